// Round 1
// baseline (2524.163 us; speedup 1.0000x reference)
//
#include <hip/hip_runtime.h>

#define NEG_SLOPE 0.2f

// ---- order-preserving float<->uint encoding for atomicMax-based segment max ----
__device__ __forceinline__ unsigned enc_f(float f) {
    unsigned u = __float_as_uint(f);
    return (u & 0x80000000u) ? ~u : (u | 0x80000000u);
}
__device__ __forceinline__ float dec_f(unsigned e) {
    unsigned u = (e & 0x80000000u) ? (e ^ 0x80000000u) : ~e;
    return __uint_as_float(u);
}

// ---- Kernel 1: h1 = x @ W1  (N x 128 @ 128 x 128), plus per-(node,head) attention logits ----
__global__ __launch_bounds__(256) void gemm1_kernel(
    const float* __restrict__ x, const float* __restrict__ W1,
    const float* __restrict__ a1s_vec, const float* __restrict__ a1d_vec,
    float* __restrict__ h1, float* __restrict__ a1s, float* __restrict__ a1d, int N)
{
    __shared__ float wsh[128 * 128];
    __shared__ float xsh[2 * 128];
    int t = threadIdx.x;
    for (int i = t; i < 128 * 128; i += 256) wsh[i] = W1[i];
    int lrow = t >> 7, col = t & 127;
    int head = (t >> 6) & 1;
    float asv = a1s_vec[col];
    float adv = a1d_vec[col];
    int base = blockIdx.x * 64;
    for (int r0 = base; r0 < base + 64; r0 += 2) {
        __syncthreads();
        int rr = r0 + lrow;
        xsh[t] = (rr < N) ? x[(size_t)rr * 128 + col] : 0.f;
        __syncthreads();
        float acc = 0.f;
        #pragma unroll 16
        for (int k = 0; k < 128; ++k) acc += xsh[lrow * 128 + k] * wsh[k * 128 + col];
        float vs = acc * asv, vd = acc * adv;
        #pragma unroll
        for (int o = 32; o; o >>= 1) { vs += __shfl_xor(vs, o); vd += __shfl_xor(vd, o); }
        if (rr < N) {
            h1[(size_t)rr * 128 + col] = acc;
            if ((t & 63) == 0) { a1s[rr * 2 + head] = vs; a1d[rr * 2 + head] = vd; }
        }
    }
}

// ---- Kernel: segment max of leaky-relu'd logits (2 heads) ----
__global__ __launch_bounds__(256) void attn_max1(
    const int* __restrict__ ei, const float* __restrict__ a1s, const float* __restrict__ a1d,
    unsigned* __restrict__ m1, int E, int Ep)
{
    int idx = blockIdx.x * 256 + threadIdx.x;
    if (idx >= Ep * 2) return;
    int e = idx >> 1, h = idx & 1;
    int src, dst;
    if (e < E) { src = ei[e]; dst = ei[E + e]; } else { src = dst = e - E; }
    float v = a1s[src * 2 + h] + a1d[dst * 2 + h];
    v = v > 0.f ? v : NEG_SLOPE * v;
    atomicMax(&m1[dst * 2 + h], enc_f(v));
}

// ---- Kernel: exp(e - max) per edge, accumulate denominator ----
__global__ __launch_bounds__(256) void attn_exp1(
    const int* __restrict__ ei, const float* __restrict__ a1s, const float* __restrict__ a1d,
    const unsigned* __restrict__ m1, float* __restrict__ d1, float* __restrict__ p1, int E, int Ep)
{
    int idx = blockIdx.x * 256 + threadIdx.x;
    if (idx >= Ep * 2) return;
    int e = idx >> 1, h = idx & 1;
    int src, dst;
    if (e < E) { src = ei[e]; dst = ei[E + e]; } else { src = dst = e - E; }
    float v = a1s[src * 2 + h] + a1d[dst * 2 + h];
    v = v > 0.f ? v : NEG_SLOPE * v;
    float m = dec_f(m1[dst * 2 + h]);
    float p = expf(v - m);
    p1[idx] = p;
    atomicAdd(&d1[dst * 2 + h], p);
}

// ---- Kernel: out1[dst] += h1[src] * alpha   (wave per edge, lane per channel) ----
__global__ __launch_bounds__(256) void aggr1(
    const int* __restrict__ ei, const float* __restrict__ h1,
    const float* __restrict__ p1, const float* __restrict__ d1,
    float* __restrict__ out1, int E, int Ep)
{
    int w = threadIdx.x >> 6, lane = threadIdx.x & 63;
    int eid = blockIdx.x * 4 + w;
    if (eid >= Ep) return;
    int src, dst;
    if (eid < E) { src = ei[eid]; dst = ei[E + eid]; } else { src = dst = eid - E; }
    #pragma unroll
    for (int h = 0; h < 2; ++h) {
        float alpha = p1[eid * 2 + h] / d1[dst * 2 + h];
        float v = h1[(size_t)src * 128 + h * 64 + lane] * alpha;
        atomicAdd(&out1[(size_t)dst * 128 + h * 64 + lane], v);
    }
}

// ---- Kernel 2nd GEMM: h2 = relu(out1 + b1) @ W2 (128 -> 64), plus attention logits ----
__global__ __launch_bounds__(256) void gemm2_kernel(
    const float* __restrict__ out1, const float* __restrict__ b1,
    const float* __restrict__ W2,
    const float* __restrict__ a2s_vec, const float* __restrict__ a2d_vec,
    float* __restrict__ h2, float* __restrict__ a2s, float* __restrict__ a2d, int N)
{
    __shared__ float wsh[128 * 64];
    __shared__ float xsh[4 * 128];
    int t = threadIdx.x;
    for (int i = t; i < 128 * 64; i += 256) wsh[i] = W2[i];
    int col = t & 63;
    int lrow = t >> 6;
    float asv = a2s_vec[col], adv = a2d_vec[col];
    int base = blockIdx.x * 64;
    for (int r0 = base; r0 < base + 64; r0 += 4) {
        __syncthreads();
        #pragma unroll
        for (int i = 0; i < 2; ++i) {
            int idx = i * 256 + t;
            int lr = idx >> 7, k = idx & 127;
            int rr = r0 + lr;
            float v = 0.f;
            if (rr < N) {
                v = out1[(size_t)rr * 128 + k] + b1[k];
                v = v > 0.f ? v : 0.f;
            }
            xsh[lr * 128 + k] = v;
        }
        __syncthreads();
        int rr = r0 + lrow;
        float acc = 0.f;
        #pragma unroll 16
        for (int k = 0; k < 128; ++k) acc += xsh[lrow * 128 + k] * wsh[k * 64 + col];
        float vs = acc * asv, vd = acc * adv;
        #pragma unroll
        for (int o = 32; o; o >>= 1) { vs += __shfl_xor(vs, o); vd += __shfl_xor(vd, o); }
        if (rr < N) {
            h2[(size_t)rr * 64 + col] = acc;
            if (col == 0) { a2s[rr] = vs; a2d[rr] = vd; }
        }
    }
}

__global__ __launch_bounds__(256) void attn_max2(
    const int* __restrict__ ei, const float* __restrict__ a2s, const float* __restrict__ a2d,
    unsigned* __restrict__ m2, int E, int Ep)
{
    int e = blockIdx.x * 256 + threadIdx.x;
    if (e >= Ep) return;
    int src, dst;
    if (e < E) { src = ei[e]; dst = ei[E + e]; } else { src = dst = e - E; }
    float v = a2s[src] + a2d[dst];
    v = v > 0.f ? v : NEG_SLOPE * v;
    atomicMax(&m2[dst], enc_f(v));
}

__global__ __launch_bounds__(256) void attn_exp2(
    const int* __restrict__ ei, const float* __restrict__ a2s, const float* __restrict__ a2d,
    const unsigned* __restrict__ m2, float* __restrict__ d2, float* __restrict__ p2, int E, int Ep)
{
    int e = blockIdx.x * 256 + threadIdx.x;
    if (e >= Ep) return;
    int src, dst;
    if (e < E) { src = ei[e]; dst = ei[E + e]; } else { src = dst = e - E; }
    float v = a2s[src] + a2d[dst];
    v = v > 0.f ? v : NEG_SLOPE * v;
    float m = dec_f(m2[dst]);
    float p = expf(v - m);
    p2[e] = p;
    atomicAdd(&d2[dst], p);
}

__global__ __launch_bounds__(256) void aggr2(
    const int* __restrict__ ei, const float* __restrict__ h2,
    const float* __restrict__ p2, const float* __restrict__ d2,
    float* __restrict__ out2, int E, int Ep)
{
    int w = threadIdx.x >> 6, lane = threadIdx.x & 63;
    int eid = blockIdx.x * 4 + w;
    if (eid >= Ep) return;
    int src, dst;
    if (eid < E) { src = ei[eid]; dst = ei[E + eid]; } else { src = dst = eid - E; }
    float alpha = p2[eid] / d2[dst];
    float v = h2[(size_t)src * 64 + lane] * alpha;
    atomicAdd(&out2[(size_t)dst * 64 + lane], v);
}

// ---- Pool: per-graph sum of relu(out2 + b2) and counts ----
__global__ __launch_bounds__(256) void pool_kernel(
    const float* __restrict__ out2, const float* __restrict__ b2,
    const int* __restrict__ batch, float* __restrict__ pool, float* __restrict__ cnt, int N)
{
    long long idx = (long long)blockIdx.x * 256 + threadIdx.x;
    if (idx >= (long long)N * 64) return;
    int n = (int)(idx >> 6), c = (int)(idx & 63);
    int g = batch[n];
    float v = out2[(size_t)n * 64 + c] + b2[c];
    v = v > 0.f ? v : 0.f;
    atomicAdd(&pool[g * 64 + c], v);
    if (c == 0) atomicAdd(&cnt[g], 1.0f);
}

// ---- Final: out[g] = dot(pool[g], Wlin)/max(cnt,1) + blin ----
__global__ void final_kernel(
    const float* __restrict__ pool, const float* __restrict__ cnt,
    const float* __restrict__ Wlin, const float* __restrict__ blin,
    float* __restrict__ out, int G)
{
    int g = threadIdx.x;
    if (g >= G) return;
    float s = 0.f;
    #pragma unroll 8
    for (int c = 0; c < 64; ++c) s += pool[g * 64 + c] * Wlin[c];
    float cn = cnt[g]; cn = cn > 1.f ? cn : 1.f;
    out[g] = s / cn + blin[0];
}

extern "C" void kernel_launch(void* const* d_in, const int* in_sizes, int n_in,
                              void* d_out, int out_size, void* d_ws, size_t ws_size,
                              hipStream_t stream) {
    const float* x     = (const float*)d_in[0];
    const int*   ei    = (const int*)d_in[1];
    const int*   batch = (const int*)d_in[2];
    const float* W1    = (const float*)d_in[3];
    const float* a1sv  = (const float*)d_in[4];
    const float* a1dv  = (const float*)d_in[5];
    const float* b1    = (const float*)d_in[6];
    const float* W2    = (const float*)d_in[7];
    const float* a2sv  = (const float*)d_in[8];
    const float* a2dv  = (const float*)d_in[9];
    const float* b2    = (const float*)d_in[10];
    const float* Wlin  = (const float*)d_in[11];
    const float* blin  = (const float*)d_in[12];

    int N  = in_sizes[2];
    int E  = in_sizes[1] / 2;
    int Ep = E + N;
    const int G = 64;

    float* ws = (float*)d_ws;
    size_t off = 0;
    float* h1   = ws + off; off += (size_t)N * 128;
    float* out1 = ws + off; off += (size_t)N * 128;
    float* h2   = ws + off; off += (size_t)N * 64;
    float* a1s  = ws + off; off += (size_t)N * 2;
    float* a1d  = ws + off; off += (size_t)N * 2;
    unsigned* m1 = (unsigned*)(ws + off); off += (size_t)N * 2;
    float* d1   = ws + off; off += (size_t)N * 2;
    float* a2s  = ws + off; off += N;
    float* a2d  = ws + off; off += N;
    unsigned* m2 = (unsigned*)(ws + off); off += N;
    float* d2   = ws + off; off += N;
    float* p1   = ws + off; off += (size_t)Ep * 2;
    float* pool = ws + off; off += G * 64;
    float* cnt  = ws + off; off += G;
    float* p2   = p1;          // alias: p1 consumed before p2 written
    float* out2 = h1;          // alias: h1 consumed before out2 accumulated

    // zero the accumulators (m1/d1 contiguous; m2/d2 contiguous; enc(-inf) < any enc(finite) so 0-init works for max)
    hipMemsetAsync(out1, 0, (size_t)N * 128 * sizeof(float), stream);
    hipMemsetAsync(m1, 0, (size_t)N * 4 * sizeof(float), stream);
    hipMemsetAsync(m2, 0, (size_t)N * 2 * sizeof(float), stream);
    hipMemsetAsync(pool, 0, (size_t)(G * 64 + G) * sizeof(float), stream);

    gemm1_kernel<<<(N + 63) / 64, 256, 0, stream>>>(x, W1, a1sv, a1dv, h1, a1s, a1d, N);
    attn_max1<<<(Ep * 2 + 255) / 256, 256, 0, stream>>>(ei, a1s, a1d, m1, E, Ep);
    attn_exp1<<<(Ep * 2 + 255) / 256, 256, 0, stream>>>(ei, a1s, a1d, m1, d1, p1, E, Ep);
    aggr1<<<(Ep + 3) / 4, 256, 0, stream>>>(ei, h1, p1, d1, out1, E, Ep);
    gemm2_kernel<<<(N + 63) / 64, 256, 0, stream>>>(out1, b1, W2, a2sv, a2dv, h2, a2s, a2d, N);
    // h1 no longer needed -> zero its alias (out2) before layer-2 aggregation
    hipMemsetAsync(out2, 0, (size_t)N * 64 * sizeof(float), stream);
    attn_max2<<<(Ep + 255) / 256, 256, 0, stream>>>(ei, a2s, a2d, m2, E, Ep);
    attn_exp2<<<(Ep + 255) / 256, 256, 0, stream>>>(ei, a2s, a2d, m2, d2, p2, E, Ep);
    aggr2<<<(Ep + 3) / 4, 256, 0, stream>>>(ei, h2, p2, d2, out2, E, Ep);
    pool_kernel<<<(int)(((long long)N * 64 + 255) / 256), 256, 0, stream>>>(out2, b2, batch, pool, cnt, N);
    final_kernel<<<1, 64, 0, stream>>>(pool, cnt, Wlin, blin, (float*)d_out, G);
}

// Round 2
// 1772.321 us; speedup vs baseline: 1.4242x; 1.4242x over previous
//
#include <hip/hip_runtime.h>

#define NEG_SLOPE 0.2f

// ---- order-preserving float<->uint encoding for atomicMax-based segment max ----
__device__ __forceinline__ unsigned enc_f(float f) {
    unsigned u = __float_as_uint(f);
    return (u & 0x80000000u) ? ~u : (u | 0x80000000u);
}
__device__ __forceinline__ float dec_f(unsigned e) {
    unsigned u = (e & 0x80000000u) ? (e ^ 0x80000000u) : ~e;
    return __uint_as_float(u);
}

// ---- Kernel 1: h1 = x @ W1  (N x 128 @ 128 x 128), plus per-(node,head) attention logits ----
__global__ __launch_bounds__(256) void gemm1_kernel(
    const float* __restrict__ x, const float* __restrict__ W1,
    const float* __restrict__ a1s_vec, const float* __restrict__ a1d_vec,
    float* __restrict__ h1, float* __restrict__ a1s, float* __restrict__ a1d, int N)
{
    __shared__ float wsh[128 * 128];
    __shared__ float xsh[2 * 128];
    int t = threadIdx.x;
    for (int i = t; i < 128 * 128; i += 256) wsh[i] = W1[i];
    int lrow = t >> 7, col = t & 127;
    int head = (t >> 6) & 1;
    float asv = a1s_vec[col];
    float adv = a1d_vec[col];
    int base = blockIdx.x * 64;
    for (int r0 = base; r0 < base + 64; r0 += 2) {
        __syncthreads();
        int rr = r0 + lrow;
        xsh[t] = (rr < N) ? x[(size_t)rr * 128 + col] : 0.f;
        __syncthreads();
        float acc = 0.f;
        #pragma unroll 16
        for (int k = 0; k < 128; ++k) acc += xsh[lrow * 128 + k] * wsh[k * 128 + col];
        float vs = acc * asv, vd = acc * adv;
        #pragma unroll
        for (int o = 32; o; o >>= 1) { vs += __shfl_xor(vs, o); vd += __shfl_xor(vd, o); }
        if (rr < N) {
            h1[(size_t)rr * 128 + col] = acc;
            if ((t & 63) == 0) { a1s[rr * 2 + head] = vs; a1d[rr * 2 + head] = vd; }
        }
    }
}

// ---- Kernel: segment max of leaky-relu'd logits (2 heads) ----
__global__ __launch_bounds__(256) void attn_max1(
    const int* __restrict__ ei, const float* __restrict__ a1s, const float* __restrict__ a1d,
    unsigned* __restrict__ m1, int E, int Ep)
{
    int idx = blockIdx.x * 256 + threadIdx.x;
    if (idx >= Ep * 2) return;
    int e = idx >> 1, h = idx & 1;
    int src, dst;
    if (e < E) { src = ei[e]; dst = ei[E + e]; } else { src = dst = e - E; }
    float v = a1s[src * 2 + h] + a1d[dst * 2 + h];
    v = v > 0.f ? v : NEG_SLOPE * v;
    atomicMax(&m1[dst * 2 + h], enc_f(v));
}

// ---- Kernel: exp(e - max) per edge, accumulate denominator ----
__global__ __launch_bounds__(256) void attn_exp1(
    const int* __restrict__ ei, const float* __restrict__ a1s, const float* __restrict__ a1d,
    const unsigned* __restrict__ m1, float* __restrict__ d1, float* __restrict__ p1, int E, int Ep)
{
    int idx = blockIdx.x * 256 + threadIdx.x;
    if (idx >= Ep * 2) return;
    int e = idx >> 1, h = idx & 1;
    int src, dst;
    if (e < E) { src = ei[e]; dst = ei[E + e]; } else { src = dst = e - E; }
    float v = a1s[src * 2 + h] + a1d[dst * 2 + h];
    v = v > 0.f ? v : NEG_SLOPE * v;
    float m = dec_f(m1[dst * 2 + h]);
    float p = expf(v - m);
    p1[idx] = p;
    atomicAdd(&d1[dst * 2 + h], p);
}

// ---- Kernel: out1[dst] += h1[src] * alpha   (wave per edge, lane per channel) ----
__global__ __launch_bounds__(256) void aggr1(
    const int* __restrict__ ei, const float* __restrict__ h1,
    const float* __restrict__ p1, const float* __restrict__ d1,
    float* __restrict__ out1, int E, int Ep)
{
    int w = threadIdx.x >> 6, lane = threadIdx.x & 63;
    int eid = blockIdx.x * 4 + w;
    if (eid >= Ep) return;
    int src, dst;
    if (eid < E) { src = ei[eid]; dst = ei[E + eid]; } else { src = dst = eid - E; }
    #pragma unroll
    for (int h = 0; h < 2; ++h) {
        float alpha = p1[eid * 2 + h] / d1[dst * 2 + h];
        float v = h1[(size_t)src * 128 + h * 64 + lane] * alpha;
        atomicAdd(&out1[(size_t)dst * 128 + h * 64 + lane], v);
    }
}

// ---- Kernel 2nd GEMM: h2 = relu(out1 + b1) @ W2 (128 -> 64), plus attention logits ----
__global__ __launch_bounds__(256) void gemm2_kernel(
    const float* __restrict__ out1, const float* __restrict__ b1,
    const float* __restrict__ W2,
    const float* __restrict__ a2s_vec, const float* __restrict__ a2d_vec,
    float* __restrict__ h2, float* __restrict__ a2s, float* __restrict__ a2d, int N)
{
    __shared__ float wsh[128 * 64];
    __shared__ float xsh[4 * 128];
    int t = threadIdx.x;
    for (int i = t; i < 128 * 64; i += 256) wsh[i] = W2[i];
    int col = t & 63;
    int lrow = t >> 6;
    float asv = a2s_vec[col], adv = a2d_vec[col];
    int base = blockIdx.x * 64;
    for (int r0 = base; r0 < base + 64; r0 += 4) {
        __syncthreads();
        #pragma unroll
        for (int i = 0; i < 2; ++i) {
            int idx = i * 256 + t;
            int lr = idx >> 7, k = idx & 127;
            int rr = r0 + lr;
            float v = 0.f;
            if (rr < N) {
                v = out1[(size_t)rr * 128 + k] + b1[k];
                v = v > 0.f ? v : 0.f;
            }
            xsh[lr * 128 + k] = v;
        }
        __syncthreads();
        int rr = r0 + lrow;
        float acc = 0.f;
        #pragma unroll 16
        for (int k = 0; k < 128; ++k) acc += xsh[lrow * 128 + k] * wsh[k * 64 + col];
        float vs = acc * asv, vd = acc * adv;
        #pragma unroll
        for (int o = 32; o; o >>= 1) { vs += __shfl_xor(vs, o); vd += __shfl_xor(vd, o); }
        if (rr < N) {
            h2[(size_t)rr * 64 + col] = acc;
            if (col == 0) { a2s[rr] = vs; a2d[rr] = vd; }
        }
    }
}

__global__ __launch_bounds__(256) void attn_max2(
    const int* __restrict__ ei, const float* __restrict__ a2s, const float* __restrict__ a2d,
    unsigned* __restrict__ m2, int E, int Ep)
{
    int e = blockIdx.x * 256 + threadIdx.x;
    if (e >= Ep) return;
    int src, dst;
    if (e < E) { src = ei[e]; dst = ei[E + e]; } else { src = dst = e - E; }
    float v = a2s[src] + a2d[dst];
    v = v > 0.f ? v : NEG_SLOPE * v;
    atomicMax(&m2[dst], enc_f(v));
}

__global__ __launch_bounds__(256) void attn_exp2(
    const int* __restrict__ ei, const float* __restrict__ a2s, const float* __restrict__ a2d,
    const unsigned* __restrict__ m2, float* __restrict__ d2, float* __restrict__ p2, int E, int Ep)
{
    int e = blockIdx.x * 256 + threadIdx.x;
    if (e >= Ep) return;
    int src, dst;
    if (e < E) { src = ei[e]; dst = ei[E + e]; } else { src = dst = e - E; }
    float v = a2s[src] + a2d[dst];
    v = v > 0.f ? v : NEG_SLOPE * v;
    float m = dec_f(m2[dst]);
    float p = expf(v - m);
    p2[e] = p;
    atomicAdd(&d2[dst], p);
}

__global__ __launch_bounds__(256) void aggr2(
    const int* __restrict__ ei, const float* __restrict__ h2,
    const float* __restrict__ p2, const float* __restrict__ d2,
    float* __restrict__ out2, int E, int Ep)
{
    int w = threadIdx.x >> 6, lane = threadIdx.x & 63;
    int eid = blockIdx.x * 4 + w;
    if (eid >= Ep) return;
    int src, dst;
    if (eid < E) { src = ei[eid]; dst = ei[E + eid]; } else { src = dst = eid - E; }
    float alpha = p2[eid] / d2[dst];
    float v = h2[(size_t)src * 64 + lane] * alpha;
    atomicAdd(&out2[(size_t)dst * 64 + lane], v);
}

// ---- Pool: hierarchical per-graph sum of relu(out2 + b2) ----
// batch is sorted, so each wave takes a contiguous node range, keeps a running
// per-graph register partial (lane = channel), and flushes one atomicAdd per
// graph boundary instead of one per element.
__global__ __launch_bounds__(256) void pool_kernel(
    const float* __restrict__ out2, const float* __restrict__ b2,
    const int* __restrict__ batch, float* __restrict__ pool, float* __restrict__ cnt, int N)
{
    int lane = threadIdx.x & 63;
    int gwave = blockIdx.x * 4 + (threadIdx.x >> 6);
    int nwaves = gridDim.x * 4;
    int per = (N + nwaves - 1) / nwaves;
    int n0 = gwave * per;
    int n1 = min(n0 + per, N);
    if (n0 >= n1) return;
    float bb = b2[lane];
    float acc = 0.f;
    int count = 0;
    int gcur = batch[n0];
    for (int n = n0; n < n1; ++n) {
        int g = batch[n];
        if (g != gcur) {
            atomicAdd(&pool[gcur * 64 + lane], acc);
            if (lane == 0) atomicAdd(&cnt[gcur], (float)count);
            acc = 0.f; count = 0; gcur = g;
        }
        float v = out2[(size_t)n * 64 + lane] + bb;
        acc += v > 0.f ? v : 0.f;
        ++count;
    }
    atomicAdd(&pool[gcur * 64 + lane], acc);
    if (lane == 0) atomicAdd(&cnt[gcur], (float)count);
}

// ---- Final: out[g] = dot(pool[g], Wlin)/max(cnt,1) + blin ----
__global__ void final_kernel(
    const float* __restrict__ pool, const float* __restrict__ cnt,
    const float* __restrict__ Wlin, const float* __restrict__ blin,
    float* __restrict__ out, int G)
{
    int g = threadIdx.x;
    if (g >= G) return;
    float s = 0.f;
    #pragma unroll 8
    for (int c = 0; c < 64; ++c) s += pool[g * 64 + c] * Wlin[c];
    float cn = cnt[g]; cn = cn > 1.f ? cn : 1.f;
    out[g] = s / cn + blin[0];
}

extern "C" void kernel_launch(void* const* d_in, const int* in_sizes, int n_in,
                              void* d_out, int out_size, void* d_ws, size_t ws_size,
                              hipStream_t stream) {
    const float* x     = (const float*)d_in[0];
    const int*   ei    = (const int*)d_in[1];
    const int*   batch = (const int*)d_in[2];
    const float* W1    = (const float*)d_in[3];
    const float* a1sv  = (const float*)d_in[4];
    const float* a1dv  = (const float*)d_in[5];
    const float* b1    = (const float*)d_in[6];
    const float* W2    = (const float*)d_in[7];
    const float* a2sv  = (const float*)d_in[8];
    const float* a2dv  = (const float*)d_in[9];
    const float* b2    = (const float*)d_in[10];
    const float* Wlin  = (const float*)d_in[11];
    const float* blin  = (const float*)d_in[12];

    int N  = in_sizes[2];
    int E  = in_sizes[1] / 2;
    int Ep = E + N;
    const int G = 64;

    float* ws = (float*)d_ws;
    size_t off = 0;
    float* h1   = ws + off; off += (size_t)N * 128;
    float* out1 = ws + off; off += (size_t)N * 128;
    float* h2   = ws + off; off += (size_t)N * 64;
    float* a1s  = ws + off; off += (size_t)N * 2;
    float* a1d  = ws + off; off += (size_t)N * 2;
    unsigned* m1 = (unsigned*)(ws + off); off += (size_t)N * 2;
    float* d1   = ws + off; off += (size_t)N * 2;
    float* a2s  = ws + off; off += N;
    float* a2d  = ws + off; off += N;
    unsigned* m2 = (unsigned*)(ws + off); off += N;
    float* d2   = ws + off; off += N;
    float* p1   = ws + off; off += (size_t)Ep * 2;
    float* pool = ws + off; off += G * 64;
    float* cnt  = ws + off; off += G;
    float* p2   = p1;          // alias: p1 consumed before p2 written
    float* out2 = h1;          // alias: h1 consumed before out2 accumulated

    hipMemsetAsync(out1, 0, (size_t)N * 128 * sizeof(float), stream);
    hipMemsetAsync(m1, 0, (size_t)N * 4 * sizeof(float), stream);
    hipMemsetAsync(m2, 0, (size_t)N * 2 * sizeof(float), stream);
    hipMemsetAsync(pool, 0, (size_t)(G * 64 + G) * sizeof(float), stream);

    gemm1_kernel<<<(N + 63) / 64, 256, 0, stream>>>(x, W1, a1sv, a1dv, h1, a1s, a1d, N);
    attn_max1<<<(Ep * 2 + 255) / 256, 256, 0, stream>>>(ei, a1s, a1d, m1, E, Ep);
    attn_exp1<<<(Ep * 2 + 255) / 256, 256, 0, stream>>>(ei, a1s, a1d, m1, d1, p1, E, Ep);
    aggr1<<<(Ep + 3) / 4, 256, 0, stream>>>(ei, h1, p1, d1, out1, E, Ep);
    gemm2_kernel<<<(N + 63) / 64, 256, 0, stream>>>(out1, b1, W2, a2sv, a2dv, h2, a2s, a2d, N);
    // h1 no longer needed -> zero its alias (out2) before layer-2 aggregation
    hipMemsetAsync(out2, 0, (size_t)N * 64 * sizeof(float), stream);
    attn_max2<<<(Ep + 255) / 256, 256, 0, stream>>>(ei, a2s, a2d, m2, E, Ep);
    attn_exp2<<<(Ep + 255) / 256, 256, 0, stream>>>(ei, a2s, a2d, m2, d2, p2, E, Ep);
    aggr2<<<(Ep + 3) / 4, 256, 0, stream>>>(ei, h2, p2, d2, out2, E, Ep);
    pool_kernel<<<256, 256, 0, stream>>>(out2, b2, batch, pool, cnt, N);
    final_kernel<<<1, 64, 0, stream>>>(pool, cnt, Wlin, blin, (float*)d_out, G);
}

// Round 3
// 995.242 us; speedup vs baseline: 2.5362x; 1.7808x over previous
//
#include <hip/hip_runtime.h>

#define NEG_SLOPE 0.2f

// ============================ GEMM 1 ============================
// h1 = x @ W1  (N x 128 @ 128 x 128), plus per-(node,head) attention logits
__global__ __launch_bounds__(256) void gemm1_kernel(
    const float* __restrict__ x, const float* __restrict__ W1,
    const float* __restrict__ a1s_vec, const float* __restrict__ a1d_vec,
    float* __restrict__ h1, float* __restrict__ a1s, float* __restrict__ a1d, int N)
{
    __shared__ float wsh[128 * 128];
    __shared__ float xsh[2 * 128];
    int t = threadIdx.x;
    for (int i = t; i < 128 * 128; i += 256) wsh[i] = W1[i];
    int lrow = t >> 7, col = t & 127;
    int head = (t >> 6) & 1;
    float asv = a1s_vec[col];
    float adv = a1d_vec[col];
    int base = blockIdx.x * 64;
    for (int r0 = base; r0 < base + 64; r0 += 2) {
        __syncthreads();
        int rr = r0 + lrow;
        xsh[t] = (rr < N) ? x[(size_t)rr * 128 + col] : 0.f;
        __syncthreads();
        float acc = 0.f;
        #pragma unroll 16
        for (int k = 0; k < 128; ++k) acc += xsh[lrow * 128 + k] * wsh[k * 128 + col];
        float vs = acc * asv, vd = acc * adv;
        #pragma unroll
        for (int o = 32; o; o >>= 1) { vs += __shfl_xor(vs, o); vd += __shfl_xor(vd, o); }
        if (rr < N) {
            h1[(size_t)rr * 128 + col] = acc;
            if ((t & 63) == 0) { a1s[rr * 2 + head] = vs; a1d[rr * 2 + head] = vd; }
        }
    }
}

// ============================ CSR build ============================
// deg histogram over destination nodes (self-loops appended)
__global__ __launch_bounds__(256) void hist_kernel(
    const int* __restrict__ ei, int* __restrict__ deg, int E, int Ep)
{
    int e = blockIdx.x * 256 + threadIdx.x;
    if (e >= Ep) return;
    int dst = (e < E) ? ei[E + e] : e - E;
    atomicAdd(&deg[dst], 1);
}

// per-block partial sums of deg (256 elements per block)
__global__ __launch_bounds__(256) void blocksum_kernel(
    const int* __restrict__ deg, int* __restrict__ bsum, int N)
{
    __shared__ int sh[4];
    int t = threadIdx.x;
    int i = blockIdx.x * 256 + t;
    int v = (i < N) ? deg[i] : 0;
    #pragma unroll
    for (int o = 32; o; o >>= 1) v += __shfl_xor(v, o);
    if ((t & 63) == 0) sh[t >> 6] = v;
    __syncthreads();
    if (t == 0) bsum[blockIdx.x] = sh[0] + sh[1] + sh[2] + sh[3];
}

// exclusive scan of block sums (single block, nb <= 512)
__global__ __launch_bounds__(512) void scan_bsum_kernel(int* __restrict__ bsum, int nb)
{
    __shared__ int sh[512];
    int t = threadIdx.x;
    int v = (t < nb) ? bsum[t] : 0;
    sh[t] = v;
    __syncthreads();
    for (int off = 1; off < 512; off <<= 1) {
        int u = (t >= off) ? sh[t - off] : 0;
        __syncthreads();
        sh[t] += u;
        __syncthreads();
    }
    if (t < nb) bsum[t] = sh[t] - v;   // exclusive
}

// final per-element exclusive scan -> rowStart, cursor
__global__ __launch_bounds__(256) void scan_final_kernel(
    const int* __restrict__ deg, const int* __restrict__ bsum,
    int* __restrict__ rowStart, int* __restrict__ cursor, int N)
{
    __shared__ int sh[256];
    int t = threadIdx.x;
    int i = blockIdx.x * 256 + t;
    int v = (i < N) ? deg[i] : 0;
    sh[t] = v;
    __syncthreads();
    for (int off = 1; off < 256; off <<= 1) {
        int u = (t >= off) ? sh[t - off] : 0;
        __syncthreads();
        sh[t] += u;
        __syncthreads();
    }
    if (i < N) {
        int exc = sh[t] - v + bsum[blockIdx.x];
        rowStart[i] = exc;
        cursor[i] = exc;
    }
}

// scatter src ids into dst-sorted order
__global__ __launch_bounds__(256) void scatter_kernel(
    const int* __restrict__ ei, int* __restrict__ cursor, int* __restrict__ srcS, int E, int Ep)
{
    int e = blockIdx.x * 256 + threadIdx.x;
    if (e >= Ep) return;
    int src, dst;
    if (e < E) { src = ei[e]; dst = ei[E + e]; } else { src = dst = e - E; }
    int pos = atomicAdd(&cursor[dst], 1);
    srcS[pos] = src;
}

// ============================ Fused softmax+aggregate, layer 1 ============================
// one wave per dst node; lane = channel (2 heads x 64); no atomics anywhere
__global__ __launch_bounds__(256) void fused_aggr1(
    const int* __restrict__ rowStart, const int* __restrict__ deg, const int* __restrict__ srcS,
    const float* __restrict__ a1s, const float* __restrict__ a1d,
    const float* __restrict__ h1, float* __restrict__ out1, int N)
{
    int lane = threadIdx.x & 63;
    int dst = blockIdx.x * 4 + (threadIdx.x >> 6);
    if (dst >= N) return;
    int base = rowStart[dst];
    int d = deg[dst];
    float ad0 = a1d[2 * dst], ad1 = a1d[2 * dst + 1];

    // pass 1: wave-parallel max over edges
    float m0 = -3.4e38f, m1 = -3.4e38f;
    for (int j = lane; j < d; j += 64) {
        int s = srcS[base + j];
        float e0 = a1s[2 * s] + ad0, e1 = a1s[2 * s + 1] + ad1;
        e0 = e0 > 0.f ? e0 : NEG_SLOPE * e0;
        e1 = e1 > 0.f ? e1 : NEG_SLOPE * e1;
        m0 = fmaxf(m0, e0); m1 = fmaxf(m1, e1);
    }
    #pragma unroll
    for (int o = 32; o; o >>= 1) { m0 = fmaxf(m0, __shfl_xor(m0, o)); m1 = fmaxf(m1, __shfl_xor(m1, o)); }

    // pass 2: wave-parallel denominator
    float s0 = 0.f, s1 = 0.f;
    for (int j = lane; j < d; j += 64) {
        int s = srcS[base + j];
        float e0 = a1s[2 * s] + ad0, e1 = a1s[2 * s + 1] + ad1;
        e0 = e0 > 0.f ? e0 : NEG_SLOPE * e0;
        e1 = e1 > 0.f ? e1 : NEG_SLOPE * e1;
        s0 += expf(e0 - m0); s1 += expf(e1 - m1);
    }
    #pragma unroll
    for (int o = 32; o; o >>= 1) { s0 += __shfl_xor(s0, o); s1 += __shfl_xor(s1, o); }
    float inv0 = 1.f / s0, inv1 = 1.f / s1;

    // pass 3: serial over edges, wave-wide coalesced gather of h1[src], register accumulate
    float acc0 = 0.f, acc1 = 0.f;
    for (int j = 0; j < d; ++j) {
        int s = srcS[base + j];
        float e0 = a1s[2 * s] + ad0, e1 = a1s[2 * s + 1] + ad1;
        e0 = e0 > 0.f ? e0 : NEG_SLOPE * e0;
        e1 = e1 > 0.f ? e1 : NEG_SLOPE * e1;
        float al0 = expf(e0 - m0) * inv0, al1 = expf(e1 - m1) * inv1;
        acc0 += h1[(size_t)s * 128 + lane] * al0;
        acc1 += h1[(size_t)s * 128 + 64 + lane] * al1;
    }
    out1[(size_t)dst * 128 + lane] = acc0;
    out1[(size_t)dst * 128 + 64 + lane] = acc1;
}

// ============================ GEMM 2 ============================
// h2 = relu(out1 + b1) @ W2 (128 -> 64), plus attention logits
__global__ __launch_bounds__(256) void gemm2_kernel(
    const float* __restrict__ out1, const float* __restrict__ b1,
    const float* __restrict__ W2,
    const float* __restrict__ a2s_vec, const float* __restrict__ a2d_vec,
    float* __restrict__ h2, float* __restrict__ a2s, float* __restrict__ a2d, int N)
{
    __shared__ float wsh[128 * 64];
    __shared__ float xsh[4 * 128];
    int t = threadIdx.x;
    for (int i = t; i < 128 * 64; i += 256) wsh[i] = W2[i];
    int col = t & 63;
    int lrow = t >> 6;
    float asv = a2s_vec[col], adv = a2d_vec[col];
    int base = blockIdx.x * 64;
    for (int r0 = base; r0 < base + 64; r0 += 4) {
        __syncthreads();
        #pragma unroll
        for (int i = 0; i < 2; ++i) {
            int idx = i * 256 + t;
            int lr = idx >> 7, k = idx & 127;
            int rr = r0 + lr;
            float v = 0.f;
            if (rr < N) {
                v = out1[(size_t)rr * 128 + k] + b1[k];
                v = v > 0.f ? v : 0.f;
            }
            xsh[lr * 128 + k] = v;
        }
        __syncthreads();
        int rr = r0 + lrow;
        float acc = 0.f;
        #pragma unroll 16
        for (int k = 0; k < 128; ++k) acc += xsh[lrow * 128 + k] * wsh[k * 64 + col];
        float vs = acc * asv, vd = acc * adv;
        #pragma unroll
        for (int o = 32; o; o >>= 1) { vs += __shfl_xor(vs, o); vd += __shfl_xor(vd, o); }
        if (rr < N) {
            h2[(size_t)rr * 64 + col] = acc;
            if (col == 0) { a2s[rr] = vs; a2d[rr] = vd; }
        }
    }
}

// ============================ Fused softmax+aggregate, layer 2 ============================
__global__ __launch_bounds__(256) void fused_aggr2(
    const int* __restrict__ rowStart, const int* __restrict__ deg, const int* __restrict__ srcS,
    const float* __restrict__ a2s, const float* __restrict__ a2d,
    const float* __restrict__ h2, float* __restrict__ out2, int N)
{
    int lane = threadIdx.x & 63;
    int dst = blockIdx.x * 4 + (threadIdx.x >> 6);
    if (dst >= N) return;
    int base = rowStart[dst];
    int d = deg[dst];
    float ad = a2d[dst];

    float m = -3.4e38f;
    for (int j = lane; j < d; j += 64) {
        float e = a2s[srcS[base + j]] + ad;
        e = e > 0.f ? e : NEG_SLOPE * e;
        m = fmaxf(m, e);
    }
    #pragma unroll
    for (int o = 32; o; o >>= 1) m = fmaxf(m, __shfl_xor(m, o));

    float sden = 0.f;
    for (int j = lane; j < d; j += 64) {
        float e = a2s[srcS[base + j]] + ad;
        e = e > 0.f ? e : NEG_SLOPE * e;
        sden += expf(e - m);
    }
    #pragma unroll
    for (int o = 32; o; o >>= 1) sden += __shfl_xor(sden, o);
    float inv = 1.f / sden;

    float acc = 0.f;
    for (int j = 0; j < d; ++j) {
        int s = srcS[base + j];
        float e = a2s[s] + ad;
        e = e > 0.f ? e : NEG_SLOPE * e;
        float al = expf(e - m) * inv;
        acc += h2[(size_t)s * 64 + lane] * al;
    }
    out2[(size_t)dst * 64 + lane] = acc;
}

// ============================ Pool ============================
// batch is sorted: wave takes contiguous node range, register partials, flush at boundaries
__global__ __launch_bounds__(256) void pool_kernel(
    const float* __restrict__ out2, const float* __restrict__ b2,
    const int* __restrict__ batch, float* __restrict__ pool, float* __restrict__ cnt, int N)
{
    int lane = threadIdx.x & 63;
    int gwave = blockIdx.x * 4 + (threadIdx.x >> 6);
    int nwaves = gridDim.x * 4;
    int per = (N + nwaves - 1) / nwaves;
    int n0 = gwave * per;
    int n1 = min(n0 + per, N);
    if (n0 >= n1) return;
    float bb = b2[lane];
    float acc = 0.f;
    int count = 0;
    int gcur = batch[n0];
    for (int n = n0; n < n1; ++n) {
        int g = batch[n];
        if (g != gcur) {
            atomicAdd(&pool[gcur * 64 + lane], acc);
            if (lane == 0) atomicAdd(&cnt[gcur], (float)count);
            acc = 0.f; count = 0; gcur = g;
        }
        float v = out2[(size_t)n * 64 + lane] + bb;
        acc += v > 0.f ? v : 0.f;
        ++count;
    }
    atomicAdd(&pool[gcur * 64 + lane], acc);
    if (lane == 0) atomicAdd(&cnt[gcur], (float)count);
}

// ============================ Final linear ============================
__global__ void final_kernel(
    const float* __restrict__ pool, const float* __restrict__ cnt,
    const float* __restrict__ Wlin, const float* __restrict__ blin,
    float* __restrict__ out, int G)
{
    int g = threadIdx.x;
    if (g >= G) return;
    float s = 0.f;
    #pragma unroll 8
    for (int c = 0; c < 64; ++c) s += pool[g * 64 + c] * Wlin[c];
    float cn = cnt[g]; cn = cn > 1.f ? cn : 1.f;
    out[g] = s / cn + blin[0];
}

extern "C" void kernel_launch(void* const* d_in, const int* in_sizes, int n_in,
                              void* d_out, int out_size, void* d_ws, size_t ws_size,
                              hipStream_t stream) {
    const float* x     = (const float*)d_in[0];
    const int*   ei    = (const int*)d_in[1];
    const int*   batch = (const int*)d_in[2];
    const float* W1    = (const float*)d_in[3];
    const float* a1sv  = (const float*)d_in[4];
    const float* a1dv  = (const float*)d_in[5];
    const float* b1    = (const float*)d_in[6];
    const float* W2    = (const float*)d_in[7];
    const float* a2sv  = (const float*)d_in[8];
    const float* a2dv  = (const float*)d_in[9];
    const float* b2    = (const float*)d_in[10];
    const float* Wlin  = (const float*)d_in[11];
    const float* blin  = (const float*)d_in[12];

    int N  = in_sizes[2];
    int E  = in_sizes[1] / 2;
    int Ep = E + N;
    const int G = 64;
    int nb = (N + 255) / 256;   // blocks for scan (must be <= 512)

    float* ws = (float*)d_ws;
    size_t off = 0;
    float* h1   = ws + off; off += (size_t)N * 128;
    float* out1 = ws + off; off += (size_t)N * 128;
    float* h2   = ws + off; off += (size_t)N * 64;
    float* a1s  = ws + off; off += (size_t)N * 2;
    float* a1d  = ws + off; off += (size_t)N * 2;
    float* a2s  = ws + off; off += N;
    float* a2d  = ws + off; off += N;
    int* degA   = (int*)(ws + off); off += N;
    int* rowStart = (int*)(ws + off); off += N;
    int* cursor = (int*)(ws + off); off += N;
    int* bsum   = (int*)(ws + off); off += 512;
    int* srcS   = (int*)(ws + off); off += Ep;
    float* pool = ws + off; off += G * 64;
    float* cnt  = ws + off; off += G;
    float* out2 = h1;   // alias: h1 dead after gemm2 reads... (h1 consumed by fused_aggr1 only)

    hipMemsetAsync(degA, 0, (size_t)N * sizeof(int), stream);
    hipMemsetAsync(pool, 0, (size_t)(G * 64 + G) * sizeof(float), stream);

    // CSR build (independent of gemm1)
    hist_kernel<<<(Ep + 255) / 256, 256, 0, stream>>>(ei, degA, E, Ep);
    blocksum_kernel<<<nb, 256, 0, stream>>>(degA, bsum, N);
    scan_bsum_kernel<<<1, 512, 0, stream>>>(bsum, nb);
    scan_final_kernel<<<nb, 256, 0, stream>>>(degA, bsum, rowStart, cursor, N);
    scatter_kernel<<<(Ep + 255) / 256, 256, 0, stream>>>(ei, cursor, srcS, E, Ep);

    gemm1_kernel<<<(N + 63) / 64, 256, 0, stream>>>(x, W1, a1sv, a1dv, h1, a1s, a1d, N);
    fused_aggr1<<<(N + 3) / 4, 256, 0, stream>>>(rowStart, degA, srcS, a1s, a1d, h1, out1, N);
    gemm2_kernel<<<(N + 63) / 64, 256, 0, stream>>>(out1, b1, W2, a2sv, a2dv, h2, a2s, a2d, N);
    fused_aggr2<<<(N + 3) / 4, 256, 0, stream>>>(rowStart, degA, srcS, a2s, a2d, h2, out2, N);
    pool_kernel<<<256, 256, 0, stream>>>(out2, b2, batch, pool, cnt, N);
    final_kernel<<<1, 64, 0, stream>>>(pool, cnt, Wlin, blin, (float*)d_out, G);
}

// Round 4
// 708.353 us; speedup vs baseline: 3.5634x; 1.4050x over previous
//
#include <hip/hip_runtime.h>

#define NEG_SLOPE 0.2f

// ============================ GEMM 1 ============================
// h1[:, head*64:+64] = x @ W1[:, head*64:+64]  (head = blockIdx.y)
// 64x64 tile per block, 4x4 micro-tile per thread; also emits per-(node,head)
// attention logits a1s/a1d via 16-lane shfl reduction.
__global__ __launch_bounds__(256) void gemm1_kernel(
    const float* __restrict__ x, const float* __restrict__ W1,
    const float* __restrict__ a1s_vec, const float* __restrict__ a1d_vec,
    float* __restrict__ h1, float* __restrict__ a1s, float* __restrict__ a1d, int N)
{
    __shared__ float wsh[128 * 64];       // [k][c]
    __shared__ float xsh[64 * 132];       // [r][k], pad 128->132
    int t = threadIdx.x;
    int head = blockIdx.y;
    int coloff = head << 6;
    int row0 = blockIdx.x << 6;

    #pragma unroll
    for (int c = 0; c < 8; ++c) {          // W tile: 128x64
        int l = c * 256 + t;
        int k = l >> 4, f = l & 15;
        *(float4*)&wsh[k * 64 + f * 4] = *(const float4*)&W1[k * 128 + coloff + f * 4];
    }
    #pragma unroll
    for (int c = 0; c < 8; ++c) {          // X tile: 64x128
        int l = c * 256 + t;
        int r = l >> 5, f = l & 31;
        int rr = row0 + r;
        float4 v = {0.f, 0.f, 0.f, 0.f};
        if (rr < N) v = *(const float4*)&x[(size_t)rr * 128 + f * 4];
        *(float4*)&xsh[r * 132 + f * 4] = v;
    }
    __syncthreads();

    int tx = t & 15, ty = t >> 4;
    float acc[4][4] = {};
    const float* xb = &xsh[(ty * 4) * 132];
    #pragma unroll 8
    for (int k = 0; k < 128; ++k) {
        float4 wv = *(const float4*)&wsh[k * 64 + tx * 4];
        float x0 = xb[k], x1 = xb[132 + k], x2 = xb[264 + k], x3 = xb[396 + k];
        acc[0][0] += x0 * wv.x; acc[0][1] += x0 * wv.y; acc[0][2] += x0 * wv.z; acc[0][3] += x0 * wv.w;
        acc[1][0] += x1 * wv.x; acc[1][1] += x1 * wv.y; acc[1][2] += x1 * wv.z; acc[1][3] += x1 * wv.w;
        acc[2][0] += x2 * wv.x; acc[2][1] += x2 * wv.y; acc[2][2] += x2 * wv.z; acc[2][3] += x2 * wv.w;
        acc[3][0] += x3 * wv.x; acc[3][1] += x3 * wv.y; acc[3][2] += x3 * wv.z; acc[3][3] += x3 * wv.w;
    }

    float avs[4], avd[4];
    #pragma unroll
    for (int c = 0; c < 4; ++c) {
        avs[c] = a1s_vec[coloff + tx * 4 + c];
        avd[c] = a1d_vec[coloff + tx * 4 + c];
    }
    #pragma unroll
    for (int r = 0; r < 4; ++r) {
        int rr = row0 + ty * 4 + r;
        float ps = acc[r][0] * avs[0] + acc[r][1] * avs[1] + acc[r][2] * avs[2] + acc[r][3] * avs[3];
        float pd = acc[r][0] * avd[0] + acc[r][1] * avd[1] + acc[r][2] * avd[2] + acc[r][3] * avd[3];
        #pragma unroll
        for (int o = 8; o; o >>= 1) { ps += __shfl_xor(ps, o); pd += __shfl_xor(pd, o); }
        if (rr < N) {
            float4 o4 = {acc[r][0], acc[r][1], acc[r][2], acc[r][3]};
            *(float4*)&h1[(size_t)rr * 128 + coloff + tx * 4] = o4;
            if (tx == 0) { a1s[rr * 2 + head] = ps; a1d[rr * 2 + head] = pd; }
        }
    }
}

// ============================ CSR build ============================
__global__ __launch_bounds__(256) void hist_kernel(
    const int* __restrict__ ei, int* __restrict__ deg, int E, int Ep)
{
    int e = blockIdx.x * 256 + threadIdx.x;
    if (e >= Ep) return;
    int dst = (e < E) ? ei[E + e] : e - E;
    atomicAdd(&deg[dst], 1);
}

__global__ __launch_bounds__(256) void blocksum_kernel(
    const int* __restrict__ deg, int* __restrict__ bsum, int N)
{
    __shared__ int sh[4];
    int t = threadIdx.x;
    int i = blockIdx.x * 256 + t;
    int v = (i < N) ? deg[i] : 0;
    #pragma unroll
    for (int o = 32; o; o >>= 1) v += __shfl_xor(v, o);
    if ((t & 63) == 0) sh[t >> 6] = v;
    __syncthreads();
    if (t == 0) bsum[blockIdx.x] = sh[0] + sh[1] + sh[2] + sh[3];
}

__global__ __launch_bounds__(512) void scan_bsum_kernel(int* __restrict__ bsum, int nb)
{
    __shared__ int sh[512];
    int t = threadIdx.x;
    int v = (t < nb) ? bsum[t] : 0;
    sh[t] = v;
    __syncthreads();
    for (int off = 1; off < 512; off <<= 1) {
        int u = (t >= off) ? sh[t - off] : 0;
        __syncthreads();
        sh[t] += u;
        __syncthreads();
    }
    if (t < nb) bsum[t] = sh[t] - v;
}

__global__ __launch_bounds__(256) void scan_final_kernel(
    const int* __restrict__ deg, const int* __restrict__ bsum,
    int* __restrict__ rowStart, int* __restrict__ cursor, int N)
{
    __shared__ int sh[256];
    int t = threadIdx.x;
    int i = blockIdx.x * 256 + t;
    int v = (i < N) ? deg[i] : 0;
    sh[t] = v;
    __syncthreads();
    for (int off = 1; off < 256; off <<= 1) {
        int u = (t >= off) ? sh[t - off] : 0;
        __syncthreads();
        sh[t] += u;
        __syncthreads();
    }
    if (i < N) {
        int exc = sh[t] - v + bsum[blockIdx.x];
        rowStart[i] = exc;
        cursor[i] = exc;
    }
}

__global__ __launch_bounds__(256) void scatter_kernel(
    const int* __restrict__ ei, int* __restrict__ cursor, int* __restrict__ srcS, int E, int Ep)
{
    int e = blockIdx.x * 256 + threadIdx.x;
    if (e >= Ep) return;
    int src, dst;
    if (e < E) { src = ei[e]; dst = ei[E + e]; } else { src = dst = e - E; }
    int pos = atomicAdd(&cursor[dst], 1);
    srcS[pos] = src;
}

// ============================ Fused softmax+aggregate, layer 1 ============================
// One wave per dst node; lane = channel. Single pass: softmax shift-invariance
// (exp(e-m)/sum == exp(e)/sum) lets us skip the max pass; logits are O(10) so
// exp cannot overflow fp32. Accumulate weighted sum and denominator together.
__global__ __launch_bounds__(256) void fused_aggr1(
    const int* __restrict__ rowStart, const int* __restrict__ deg, const int* __restrict__ srcS,
    const float* __restrict__ a1s, const float* __restrict__ a1d,
    const float* __restrict__ h1, float* __restrict__ out1, int N)
{
    int lane = threadIdx.x & 63;
    int dst = blockIdx.x * 4 + (threadIdx.x >> 6);
    if (dst >= N) return;
    int base = rowStart[dst];
    int d = deg[dst];
    float ad0 = a1d[2 * dst], ad1 = a1d[2 * dst + 1];
    float acc0 = 0.f, acc1 = 0.f, den0 = 0.f, den1 = 0.f;
    for (int j = 0; j < d; ++j) {
        int s = srcS[base + j];
        float e0 = a1s[2 * s] + ad0;
        float e1 = a1s[2 * s + 1] + ad1;
        e0 = e0 > 0.f ? e0 : NEG_SLOPE * e0;
        e1 = e1 > 0.f ? e1 : NEG_SLOPE * e1;
        float p0 = __expf(e0), p1 = __expf(e1);
        const float* hp = &h1[(size_t)s * 128];
        acc0 += p0 * hp[lane];
        acc1 += p1 * hp[64 + lane];
        den0 += p0; den1 += p1;
    }
    out1[(size_t)dst * 128 + lane] = acc0 / den0;
    out1[(size_t)dst * 128 + 64 + lane] = acc1 / den1;
}

// ============================ GEMM 2 ============================
// h2 = relu(out1 + b1) @ W2  (128 -> 64); same register-tiled structure.
__global__ __launch_bounds__(256) void gemm2_kernel(
    const float* __restrict__ out1, const float* __restrict__ b1,
    const float* __restrict__ W2,
    const float* __restrict__ a2s_vec, const float* __restrict__ a2d_vec,
    float* __restrict__ h2, float* __restrict__ a2s, float* __restrict__ a2d, int N)
{
    __shared__ float wsh[128 * 64];       // [k][c] == W2 layout
    __shared__ float xsh[64 * 132];       // [r][k]
    int t = threadIdx.x;
    int row0 = blockIdx.x << 6;

    #pragma unroll
    for (int c = 0; c < 8; ++c) {          // W2: straight copy
        int l = c * 256 + t;
        *(float4*)&wsh[l * 4] = *(const float4*)&W2[l * 4];
    }
    #pragma unroll
    for (int c = 0; c < 8; ++c) {          // X tile = relu(out1 + b1)
        int l = c * 256 + t;
        int r = l >> 5, f = l & 31;
        int rr = row0 + r;
        float4 v = {0.f, 0.f, 0.f, 0.f};
        if (rr < N) {
            v = *(const float4*)&out1[(size_t)rr * 128 + f * 4];
            float4 bv = *(const float4*)&b1[f * 4];
            v.x = fmaxf(v.x + bv.x, 0.f);
            v.y = fmaxf(v.y + bv.y, 0.f);
            v.z = fmaxf(v.z + bv.z, 0.f);
            v.w = fmaxf(v.w + bv.w, 0.f);
        }
        *(float4*)&xsh[r * 132 + f * 4] = v;
    }
    __syncthreads();

    int tx = t & 15, ty = t >> 4;
    float acc[4][4] = {};
    const float* xb = &xsh[(ty * 4) * 132];
    #pragma unroll 8
    for (int k = 0; k < 128; ++k) {
        float4 wv = *(const float4*)&wsh[k * 64 + tx * 4];
        float x0 = xb[k], x1 = xb[132 + k], x2 = xb[264 + k], x3 = xb[396 + k];
        acc[0][0] += x0 * wv.x; acc[0][1] += x0 * wv.y; acc[0][2] += x0 * wv.z; acc[0][3] += x0 * wv.w;
        acc[1][0] += x1 * wv.x; acc[1][1] += x1 * wv.y; acc[1][2] += x1 * wv.z; acc[1][3] += x1 * wv.w;
        acc[2][0] += x2 * wv.x; acc[2][1] += x2 * wv.y; acc[2][2] += x2 * wv.z; acc[2][3] += x2 * wv.w;
        acc[3][0] += x3 * wv.x; acc[3][1] += x3 * wv.y; acc[3][2] += x3 * wv.z; acc[3][3] += x3 * wv.w;
    }

    float avs[4], avd[4];
    #pragma unroll
    for (int c = 0; c < 4; ++c) {
        avs[c] = a2s_vec[tx * 4 + c];
        avd[c] = a2d_vec[tx * 4 + c];
    }
    #pragma unroll
    for (int r = 0; r < 4; ++r) {
        int rr = row0 + ty * 4 + r;
        float ps = acc[r][0] * avs[0] + acc[r][1] * avs[1] + acc[r][2] * avs[2] + acc[r][3] * avs[3];
        float pd = acc[r][0] * avd[0] + acc[r][1] * avd[1] + acc[r][2] * avd[2] + acc[r][3] * avd[3];
        #pragma unroll
        for (int o = 8; o; o >>= 1) { ps += __shfl_xor(ps, o); pd += __shfl_xor(pd, o); }
        if (rr < N) {
            float4 o4 = {acc[r][0], acc[r][1], acc[r][2], acc[r][3]};
            *(float4*)&h2[(size_t)rr * 64 + tx * 4] = o4;
            if (tx == 0) { a2s[rr] = ps; a2d[rr] = pd; }
        }
    }
}

// ============================ Fused softmax+aggregate, layer 2 ============================
__global__ __launch_bounds__(256) void fused_aggr2(
    const int* __restrict__ rowStart, const int* __restrict__ deg, const int* __restrict__ srcS,
    const float* __restrict__ a2s, const float* __restrict__ a2d,
    const float* __restrict__ h2, float* __restrict__ out2, int N)
{
    int lane = threadIdx.x & 63;
    int dst = blockIdx.x * 4 + (threadIdx.x >> 6);
    if (dst >= N) return;
    int base = rowStart[dst];
    int d = deg[dst];
    float ad = a2d[dst];
    float acc = 0.f, den = 0.f;
    for (int j = 0; j < d; ++j) {
        int s = srcS[base + j];
        float e = a2s[s] + ad;
        e = e > 0.f ? e : NEG_SLOPE * e;
        float p = __expf(e);
        acc += p * h2[(size_t)s * 64 + lane];
        den += p;
    }
    out2[(size_t)dst * 64 + lane] = acc / den;
}

// ============================ Pool ============================
__global__ __launch_bounds__(256) void pool_kernel(
    const float* __restrict__ out2, const float* __restrict__ b2,
    const int* __restrict__ batch, float* __restrict__ pool, float* __restrict__ cnt, int N)
{
    int lane = threadIdx.x & 63;
    int gwave = blockIdx.x * 4 + (threadIdx.x >> 6);
    int nwaves = gridDim.x * 4;
    int per = (N + nwaves - 1) / nwaves;
    int n0 = gwave * per;
    int n1 = min(n0 + per, N);
    if (n0 >= n1) return;
    float bb = b2[lane];
    float acc = 0.f;
    int count = 0;
    int gcur = batch[n0];
    for (int n = n0; n < n1; ++n) {
        int g = batch[n];
        if (g != gcur) {
            atomicAdd(&pool[gcur * 64 + lane], acc);
            if (lane == 0) atomicAdd(&cnt[gcur], (float)count);
            acc = 0.f; count = 0; gcur = g;
        }
        float v = out2[(size_t)n * 64 + lane] + bb;
        acc += v > 0.f ? v : 0.f;
        ++count;
    }
    atomicAdd(&pool[gcur * 64 + lane], acc);
    if (lane == 0) atomicAdd(&cnt[gcur], (float)count);
}

// ============================ Final linear ============================
__global__ void final_kernel(
    const float* __restrict__ pool, const float* __restrict__ cnt,
    const float* __restrict__ Wlin, const float* __restrict__ blin,
    float* __restrict__ out, int G)
{
    int g = threadIdx.x;
    if (g >= G) return;
    float s = 0.f;
    #pragma unroll 8
    for (int c = 0; c < 64; ++c) s += pool[g * 64 + c] * Wlin[c];
    float cn = cnt[g]; cn = cn > 1.f ? cn : 1.f;
    out[g] = s / cn + blin[0];
}

extern "C" void kernel_launch(void* const* d_in, const int* in_sizes, int n_in,
                              void* d_out, int out_size, void* d_ws, size_t ws_size,
                              hipStream_t stream) {
    const float* x     = (const float*)d_in[0];
    const int*   ei    = (const int*)d_in[1];
    const int*   batch = (const int*)d_in[2];
    const float* W1    = (const float*)d_in[3];
    const float* a1sv  = (const float*)d_in[4];
    const float* a1dv  = (const float*)d_in[5];
    const float* b1    = (const float*)d_in[6];
    const float* W2    = (const float*)d_in[7];
    const float* a2sv  = (const float*)d_in[8];
    const float* a2dv  = (const float*)d_in[9];
    const float* b2    = (const float*)d_in[10];
    const float* Wlin  = (const float*)d_in[11];
    const float* blin  = (const float*)d_in[12];

    int N  = in_sizes[2];
    int E  = in_sizes[1] / 2;
    int Ep = E + N;
    const int G = 64;
    int nb = (N + 255) / 256;   // scan blocks (<= 512)

    float* ws = (float*)d_ws;
    size_t off = 0;
    float* h1   = ws + off; off += (size_t)N * 128;
    float* out1 = ws + off; off += (size_t)N * 128;
    float* h2   = ws + off; off += (size_t)N * 64;
    float* a1s  = ws + off; off += (size_t)N * 2;
    float* a1d  = ws + off; off += (size_t)N * 2;
    float* a2s  = ws + off; off += N;
    float* a2d  = ws + off; off += N;
    int* degA   = (int*)(ws + off); off += N;
    int* rowStart = (int*)(ws + off); off += N;
    int* cursor = (int*)(ws + off); off += N;
    int* bsum   = (int*)(ws + off); off += 512;
    int* srcS   = (int*)(ws + off); off += Ep;
    float* pool = ws + off; off += G * 64;
    float* cnt  = ws + off; off += G;
    float* out2 = h1;   // alias: h1 dead after fused_aggr1

    hipMemsetAsync(degA, 0, (size_t)N * sizeof(int), stream);
    hipMemsetAsync(pool, 0, (size_t)(G * 64 + G) * sizeof(float), stream);

    // CSR build (independent of gemm1)
    hist_kernel<<<(Ep + 255) / 256, 256, 0, stream>>>(ei, degA, E, Ep);
    blocksum_kernel<<<nb, 256, 0, stream>>>(degA, bsum, N);
    scan_bsum_kernel<<<1, 512, 0, stream>>>(bsum, nb);
    scan_final_kernel<<<nb, 256, 0, stream>>>(degA, bsum, rowStart, cursor, N);
    scatter_kernel<<<(Ep + 255) / 256, 256, 0, stream>>>(ei, cursor, srcS, E, Ep);

    dim3 g1((N + 63) / 64, 2);
    gemm1_kernel<<<g1, 256, 0, stream>>>(x, W1, a1sv, a1dv, h1, a1s, a1d, N);
    fused_aggr1<<<(N + 3) / 4, 256, 0, stream>>>(rowStart, degA, srcS, a1s, a1d, h1, out1, N);
    gemm2_kernel<<<(N + 63) / 64, 256, 0, stream>>>(out1, b1, W2, a2sv, a2dv, h2, a2s, a2d, N);
    fused_aggr2<<<(N + 3) / 4, 256, 0, stream>>>(rowStart, degA, srcS, a2s, a2d, h2, out2, N);
    pool_kernel<<<256, 256, 0, stream>>>(out2, b2, batch, pool, cnt, N);
    final_kernel<<<1, 64, 0, stream>>>(pool, cnt, Wlin, blin, (float*)d_out, G);
}

// Round 5
// 595.555 us; speedup vs baseline: 4.2383x; 1.1894x over previous
//
#include <hip/hip_runtime.h>

#define NEG_SLOPE 0.2f

// ============================ GEMM 1 ============================
// h1[:, head*64:+64] = x @ W1[:, head*64:+64]  (head = blockIdx.y)
// 64x64 tile per block, 4x4 micro-tile per thread; also emits per-(node,head)
// attention logits a1s/a1d via 16-lane shfl reduction.
__global__ __launch_bounds__(256) void gemm1_kernel(
    const float* __restrict__ x, const float* __restrict__ W1,
    const float* __restrict__ a1s_vec, const float* __restrict__ a1d_vec,
    float* __restrict__ h1, float* __restrict__ a1s, float* __restrict__ a1d, int N)
{
    __shared__ float wsh[128 * 64];       // [k][c]
    __shared__ float xsh[64 * 132];       // [r][k], pad 128->132
    int t = threadIdx.x;
    int head = blockIdx.y;
    int coloff = head << 6;
    int row0 = blockIdx.x << 6;

    #pragma unroll
    for (int c = 0; c < 8; ++c) {          // W tile: 128x64
        int l = c * 256 + t;
        int k = l >> 4, f = l & 15;
        *(float4*)&wsh[k * 64 + f * 4] = *(const float4*)&W1[k * 128 + coloff + f * 4];
    }
    #pragma unroll
    for (int c = 0; c < 8; ++c) {          // X tile: 64x128
        int l = c * 256 + t;
        int r = l >> 5, f = l & 31;
        int rr = row0 + r;
        float4 v = {0.f, 0.f, 0.f, 0.f};
        if (rr < N) v = *(const float4*)&x[(size_t)rr * 128 + f * 4];
        *(float4*)&xsh[r * 132 + f * 4] = v;
    }
    __syncthreads();

    int tx = t & 15, ty = t >> 4;
    float acc[4][4] = {};
    const float* xb = &xsh[(ty * 4) * 132];
    #pragma unroll 8
    for (int k = 0; k < 128; ++k) {
        float4 wv = *(const float4*)&wsh[k * 64 + tx * 4];
        float x0 = xb[k], x1 = xb[132 + k], x2 = xb[264 + k], x3 = xb[396 + k];
        acc[0][0] += x0 * wv.x; acc[0][1] += x0 * wv.y; acc[0][2] += x0 * wv.z; acc[0][3] += x0 * wv.w;
        acc[1][0] += x1 * wv.x; acc[1][1] += x1 * wv.y; acc[1][2] += x1 * wv.z; acc[1][3] += x1 * wv.w;
        acc[2][0] += x2 * wv.x; acc[2][1] += x2 * wv.y; acc[2][2] += x2 * wv.z; acc[2][3] += x2 * wv.w;
        acc[3][0] += x3 * wv.x; acc[3][1] += x3 * wv.y; acc[3][2] += x3 * wv.z; acc[3][3] += x3 * wv.w;
    }

    float avs[4], avd[4];
    #pragma unroll
    for (int c = 0; c < 4; ++c) {
        avs[c] = a1s_vec[coloff + tx * 4 + c];
        avd[c] = a1d_vec[coloff + tx * 4 + c];
    }
    #pragma unroll
    for (int r = 0; r < 4; ++r) {
        int rr = row0 + ty * 4 + r;
        float ps = acc[r][0] * avs[0] + acc[r][1] * avs[1] + acc[r][2] * avs[2] + acc[r][3] * avs[3];
        float pd = acc[r][0] * avd[0] + acc[r][1] * avd[1] + acc[r][2] * avd[2] + acc[r][3] * avd[3];
        #pragma unroll
        for (int o = 8; o; o >>= 1) { ps += __shfl_xor(ps, o); pd += __shfl_xor(pd, o); }
        if (rr < N) {
            float4 o4 = {acc[r][0], acc[r][1], acc[r][2], acc[r][3]};
            *(float4*)&h1[(size_t)rr * 128 + coloff + tx * 4] = o4;
            if (tx == 0) { a1s[rr * 2 + head] = ps; a1d[rr * 2 + head] = pd; }
        }
    }
}

// ============================ CSR build ============================
__global__ __launch_bounds__(256) void hist_kernel(
    const int* __restrict__ ei, int* __restrict__ deg, int E, int Ep)
{
    int e = blockIdx.x * 256 + threadIdx.x;
    if (e >= Ep) return;
    int dst = (e < E) ? ei[E + e] : e - E;
    atomicAdd(&deg[dst], 1);
}

__global__ __launch_bounds__(256) void blocksum_kernel(
    const int* __restrict__ deg, int* __restrict__ bsum, int N)
{
    __shared__ int sh[4];
    int t = threadIdx.x;
    int i = blockIdx.x * 256 + t;
    int v = (i < N) ? deg[i] : 0;
    #pragma unroll
    for (int o = 32; o; o >>= 1) v += __shfl_xor(v, o);
    if ((t & 63) == 0) sh[t >> 6] = v;
    __syncthreads();
    if (t == 0) bsum[blockIdx.x] = sh[0] + sh[1] + sh[2] + sh[3];
}

__global__ __launch_bounds__(512) void scan_bsum_kernel(int* __restrict__ bsum, int nb)
{
    __shared__ int sh[512];
    int t = threadIdx.x;
    int v = (t < nb) ? bsum[t] : 0;
    sh[t] = v;
    __syncthreads();
    for (int off = 1; off < 512; off <<= 1) {
        int u = (t >= off) ? sh[t - off] : 0;
        __syncthreads();
        sh[t] += u;
        __syncthreads();
    }
    if (t < nb) bsum[t] = sh[t] - v;
}

__global__ __launch_bounds__(256) void scan_final_kernel(
    const int* __restrict__ deg, const int* __restrict__ bsum,
    int* __restrict__ rowStart, int* __restrict__ cursor, int N)
{
    __shared__ int sh[256];
    int t = threadIdx.x;
    int i = blockIdx.x * 256 + t;
    int v = (i < N) ? deg[i] : 0;
    sh[t] = v;
    __syncthreads();
    for (int off = 1; off < 256; off <<= 1) {
        int u = (t >= off) ? sh[t - off] : 0;
        __syncthreads();
        sh[t] += u;
        __syncthreads();
    }
    if (i < N) {
        int exc = sh[t] - v + bsum[blockIdx.x];
        rowStart[i] = exc;
        cursor[i] = exc;
    }
}

__global__ __launch_bounds__(256) void scatter_kernel(
    const int* __restrict__ ei, int* __restrict__ cursor, int* __restrict__ srcS, int E, int Ep)
{
    int e = blockIdx.x * 256 + threadIdx.x;
    if (e >= Ep) return;
    int src, dst;
    if (e < E) { src = ei[e]; dst = ei[E + e]; } else { src = dst = e - E; }
    int pos = atomicAdd(&cursor[dst], 1);
    srcS[pos] = src;
}

// ============================ Fused softmax+aggregate, layer 1 ============================
// One wave per dst node; lane = channel.
// Two-phase per 64-edge chunk: (a) lane-parallel weight phase -- lane j loads
// srcS/a1s for edge j and computes p (one latency chain per chunk, not per
// edge); per-lane denominator partials. (b) shfl-broadcast gather phase --
// (s_j, p_j) come from registers, so the h1 row gathers are independent
// across j and pipeline deep.
__global__ __launch_bounds__(256) void fused_aggr1(
    const int* __restrict__ rowStart, const int* __restrict__ deg, const int* __restrict__ srcS,
    const float* __restrict__ a1s, const float* __restrict__ a1d,
    const float* __restrict__ h1, float* __restrict__ out1, int N)
{
    int lane = threadIdx.x & 63;
    int dst = blockIdx.x * 4 + (threadIdx.x >> 6);
    if (dst >= N) return;
    int base = rowStart[dst];
    int d = deg[dst];
    float ad0 = a1d[2 * dst], ad1 = a1d[2 * dst + 1];
    float acc0 = 0.f, acc1 = 0.f, dpart0 = 0.f, dpart1 = 0.f;

    for (int c0 = 0; c0 < d; c0 += 64) {
        int cn = min(64, d - c0);
        int s = 0; float p0 = 0.f, p1 = 0.f;
        if (lane < cn) {
            s = srcS[base + c0 + lane];
            float2 av = *(const float2*)&a1s[2 * s];
            float e0 = av.x + ad0, e1 = av.y + ad1;
            e0 = e0 > 0.f ? e0 : NEG_SLOPE * e0;
            e1 = e1 > 0.f ? e1 : NEG_SLOPE * e1;
            p0 = __expf(e0); p1 = __expf(e1);
        }
        dpart0 += p0; dpart1 += p1;
        #pragma unroll 4
        for (int j = 0; j < cn; ++j) {
            int   sj = __shfl(s, j);
            float q0 = __shfl(p0, j);
            float q1 = __shfl(p1, j);
            const float* hp = &h1[(size_t)sj * 128];
            acc0 += q0 * hp[lane];
            acc1 += q1 * hp[64 + lane];
        }
    }
    // wave-reduce the denominators once
    #pragma unroll
    for (int o = 32; o; o >>= 1) { dpart0 += __shfl_xor(dpart0, o); dpart1 += __shfl_xor(dpart1, o); }
    out1[(size_t)dst * 128 + lane] = acc0 / dpart0;
    out1[(size_t)dst * 128 + 64 + lane] = acc1 / dpart1;
}

// ============================ GEMM 2 ============================
// h2 = relu(out1 + b1) @ W2  (128 -> 64); register-tiled.
__global__ __launch_bounds__(256) void gemm2_kernel(
    const float* __restrict__ out1, const float* __restrict__ b1,
    const float* __restrict__ W2,
    const float* __restrict__ a2s_vec, const float* __restrict__ a2d_vec,
    float* __restrict__ h2, float* __restrict__ a2s, float* __restrict__ a2d, int N)
{
    __shared__ float wsh[128 * 64];       // [k][c] == W2 layout
    __shared__ float xsh[64 * 132];       // [r][k]
    int t = threadIdx.x;
    int row0 = blockIdx.x << 6;

    #pragma unroll
    for (int c = 0; c < 8; ++c) {          // W2: straight copy
        int l = c * 256 + t;
        *(float4*)&wsh[l * 4] = *(const float4*)&W2[l * 4];
    }
    #pragma unroll
    for (int c = 0; c < 8; ++c) {          // X tile = relu(out1 + b1)
        int l = c * 256 + t;
        int r = l >> 5, f = l & 31;
        int rr = row0 + r;
        float4 v = {0.f, 0.f, 0.f, 0.f};
        if (rr < N) {
            v = *(const float4*)&out1[(size_t)rr * 128 + f * 4];
            float4 bv = *(const float4*)&b1[f * 4];
            v.x = fmaxf(v.x + bv.x, 0.f);
            v.y = fmaxf(v.y + bv.y, 0.f);
            v.z = fmaxf(v.z + bv.z, 0.f);
            v.w = fmaxf(v.w + bv.w, 0.f);
        }
        *(float4*)&xsh[r * 132 + f * 4] = v;
    }
    __syncthreads();

    int tx = t & 15, ty = t >> 4;
    float acc[4][4] = {};
    const float* xb = &xsh[(ty * 4) * 132];
    #pragma unroll 8
    for (int k = 0; k < 128; ++k) {
        float4 wv = *(const float4*)&wsh[k * 64 + tx * 4];
        float x0 = xb[k], x1 = xb[132 + k], x2 = xb[264 + k], x3 = xb[396 + k];
        acc[0][0] += x0 * wv.x; acc[0][1] += x0 * wv.y; acc[0][2] += x0 * wv.z; acc[0][3] += x0 * wv.w;
        acc[1][0] += x1 * wv.x; acc[1][1] += x1 * wv.y; acc[1][2] += x1 * wv.z; acc[1][3] += x1 * wv.w;
        acc[2][0] += x2 * wv.x; acc[2][1] += x2 * wv.y; acc[2][2] += x2 * wv.z; acc[2][3] += x2 * wv.w;
        acc[3][0] += x3 * wv.x; acc[3][1] += x3 * wv.y; acc[3][2] += x3 * wv.z; acc[3][3] += x3 * wv.w;
    }

    float avs[4], avd[4];
    #pragma unroll
    for (int c = 0; c < 4; ++c) {
        avs[c] = a2s_vec[tx * 4 + c];
        avd[c] = a2d_vec[tx * 4 + c];
    }
    #pragma unroll
    for (int r = 0; r < 4; ++r) {
        int rr = row0 + ty * 4 + r;
        float ps = acc[r][0] * avs[0] + acc[r][1] * avs[1] + acc[r][2] * avs[2] + acc[r][3] * avs[3];
        float pd = acc[r][0] * avd[0] + acc[r][1] * avd[1] + acc[r][2] * avd[2] + acc[r][3] * avd[3];
        #pragma unroll
        for (int o = 8; o; o >>= 1) { ps += __shfl_xor(ps, o); pd += __shfl_xor(pd, o); }
        if (rr < N) {
            float4 o4 = {acc[r][0], acc[r][1], acc[r][2], acc[r][3]};
            *(float4*)&h2[(size_t)rr * 64 + tx * 4] = o4;
            if (tx == 0) { a2s[rr] = ps; a2d[rr] = pd; }
        }
    }
}

// ============================ Fused softmax+aggregate, layer 2 ============================
__global__ __launch_bounds__(256) void fused_aggr2(
    const int* __restrict__ rowStart, const int* __restrict__ deg, const int* __restrict__ srcS,
    const float* __restrict__ a2s, const float* __restrict__ a2d,
    const float* __restrict__ h2, float* __restrict__ out2, int N)
{
    int lane = threadIdx.x & 63;
    int dst = blockIdx.x * 4 + (threadIdx.x >> 6);
    if (dst >= N) return;
    int base = rowStart[dst];
    int d = deg[dst];
    float ad = a2d[dst];
    float acc = 0.f, dpart = 0.f;

    for (int c0 = 0; c0 < d; c0 += 64) {
        int cn = min(64, d - c0);
        int s = 0; float p = 0.f;
        if (lane < cn) {
            s = srcS[base + c0 + lane];
            float e = a2s[s] + ad;
            e = e > 0.f ? e : NEG_SLOPE * e;
            p = __expf(e);
        }
        dpart += p;
        #pragma unroll 4
        for (int j = 0; j < cn; ++j) {
            int   sj = __shfl(s, j);
            float q  = __shfl(p, j);
            acc += q * h2[(size_t)sj * 64 + lane];
        }
    }
    #pragma unroll
    for (int o = 32; o; o >>= 1) dpart += __shfl_xor(dpart, o);
    out2[(size_t)dst * 64 + lane] = acc / dpart;
}

// ============================ Pool ============================
__global__ __launch_bounds__(256) void pool_kernel(
    const float* __restrict__ out2, const float* __restrict__ b2,
    const int* __restrict__ batch, float* __restrict__ pool, float* __restrict__ cnt, int N)
{
    int lane = threadIdx.x & 63;
    int gwave = blockIdx.x * 4 + (threadIdx.x >> 6);
    int nwaves = gridDim.x * 4;
    int per = (N + nwaves - 1) / nwaves;
    int n0 = gwave * per;
    int n1 = min(n0 + per, N);
    if (n0 >= n1) return;
    float bb = b2[lane];
    float acc = 0.f;
    int count = 0;
    int gcur = batch[n0];
    for (int n = n0; n < n1; ++n) {
        int g = batch[n];
        if (g != gcur) {
            atomicAdd(&pool[gcur * 64 + lane], acc);
            if (lane == 0) atomicAdd(&cnt[gcur], (float)count);
            acc = 0.f; count = 0; gcur = g;
        }
        float v = out2[(size_t)n * 64 + lane] + bb;
        acc += v > 0.f ? v : 0.f;
        ++count;
    }
    atomicAdd(&pool[gcur * 64 + lane], acc);
    if (lane == 0) atomicAdd(&cnt[gcur], (float)count);
}

// ============================ Final linear ============================
__global__ void final_kernel(
    const float* __restrict__ pool, const float* __restrict__ cnt,
    const float* __restrict__ Wlin, const float* __restrict__ blin,
    float* __restrict__ out, int G)
{
    int g = threadIdx.x;
    if (g >= G) return;
    float s = 0.f;
    #pragma unroll 8
    for (int c = 0; c < 64; ++c) s += pool[g * 64 + c] * Wlin[c];
    float cn = cnt[g]; cn = cn > 1.f ? cn : 1.f;
    out[g] = s / cn + blin[0];
}

extern "C" void kernel_launch(void* const* d_in, const int* in_sizes, int n_in,
                              void* d_out, int out_size, void* d_ws, size_t ws_size,
                              hipStream_t stream) {
    const float* x     = (const float*)d_in[0];
    const int*   ei    = (const int*)d_in[1];
    const int*   batch = (const int*)d_in[2];
    const float* W1    = (const float*)d_in[3];
    const float* a1sv  = (const float*)d_in[4];
    const float* a1dv  = (const float*)d_in[5];
    const float* b1    = (const float*)d_in[6];
    const float* W2    = (const float*)d_in[7];
    const float* a2sv  = (const float*)d_in[8];
    const float* a2dv  = (const float*)d_in[9];
    const float* b2    = (const float*)d_in[10];
    const float* Wlin  = (const float*)d_in[11];
    const float* blin  = (const float*)d_in[12];

    int N  = in_sizes[2];
    int E  = in_sizes[1] / 2;
    int Ep = E + N;
    const int G = 64;
    int nb = (N + 255) / 256;   // scan blocks (<= 512)

    float* ws = (float*)d_ws;
    size_t off = 0;
    float* h1   = ws + off; off += (size_t)N * 128;
    float* out1 = ws + off; off += (size_t)N * 128;
    float* h2   = ws + off; off += (size_t)N * 64;
    float* a1s  = ws + off; off += (size_t)N * 2;
    float* a1d  = ws + off; off += (size_t)N * 2;
    float* a2s  = ws + off; off += N;
    float* a2d  = ws + off; off += N;
    int* degA   = (int*)(ws + off); off += N;
    int* rowStart = (int*)(ws + off); off += N;
    int* cursor = (int*)(ws + off); off += N;
    int* bsum   = (int*)(ws + off); off += 512;
    int* srcS   = (int*)(ws + off); off += Ep;
    float* pool = ws + off; off += G * 64;
    float* cnt  = ws + off; off += G;
    float* out2 = h1;   // alias: h1 dead after fused_aggr1

    hipMemsetAsync(degA, 0, (size_t)N * sizeof(int), stream);
    hipMemsetAsync(pool, 0, (size_t)(G * 64 + G) * sizeof(float), stream);

    // CSR build (independent of gemm1)
    hist_kernel<<<(Ep + 255) / 256, 256, 0, stream>>>(ei, degA, E, Ep);
    blocksum_kernel<<<nb, 256, 0, stream>>>(degA, bsum, N);
    scan_bsum_kernel<<<1, 512, 0, stream>>>(bsum, nb);
    scan_final_kernel<<<nb, 256, 0, stream>>>(degA, bsum, rowStart, cursor, N);
    scatter_kernel<<<(Ep + 255) / 256, 256, 0, stream>>>(ei, cursor, srcS, E, Ep);

    dim3 g1((N + 63) / 64, 2);
    gemm1_kernel<<<g1, 256, 0, stream>>>(x, W1, a1sv, a1dv, h1, a1s, a1d, N);
    fused_aggr1<<<(N + 3) / 4, 256, 0, stream>>>(rowStart, degA, srcS, a1s, a1d, h1, out1, N);
    gemm2_kernel<<<(N + 63) / 64, 256, 0, stream>>>(out1, b1, W2, a2sv, a2dv, h2, a2s, a2d, N);
    fused_aggr2<<<(N + 3) / 4, 256, 0, stream>>>(rowStart, degA, srcS, a2s, a2d, h2, out2, N);
    pool_kernel<<<256, 256, 0, stream>>>(out2, b2, batch, pool, cnt, N);
    final_kernel<<<1, 64, 0, stream>>>(pool, cnt, Wlin, blin, (float*)d_out, G);
}

// Round 6
// 543.359 us; speedup vs baseline: 4.6455x; 1.0961x over previous
//
#include <hip/hip_runtime.h>

#define NEG_SLOPE 0.2f

// ============================ GEMM 1 ============================
// h1[:, head*64:+64] = x @ W1[:, head*64:+64]  (head = blockIdx.y)
__global__ __launch_bounds__(256) void gemm1_kernel(
    const float* __restrict__ x, const float* __restrict__ W1,
    const float* __restrict__ a1s_vec, const float* __restrict__ a1d_vec,
    float* __restrict__ h1, float* __restrict__ a1s, float* __restrict__ a1d, int N)
{
    __shared__ float wsh[128 * 64];       // [k][c]
    __shared__ float xsh[64 * 132];       // [r][k], pad 128->132
    int t = threadIdx.x;
    int head = blockIdx.y;
    int coloff = head << 6;
    int row0 = blockIdx.x << 6;

    #pragma unroll
    for (int c = 0; c < 8; ++c) {          // W tile: 128x64
        int l = c * 256 + t;
        int k = l >> 4, f = l & 15;
        *(float4*)&wsh[k * 64 + f * 4] = *(const float4*)&W1[k * 128 + coloff + f * 4];
    }
    #pragma unroll
    for (int c = 0; c < 8; ++c) {          // X tile: 64x128
        int l = c * 256 + t;
        int r = l >> 5, f = l & 31;
        int rr = row0 + r;
        float4 v = {0.f, 0.f, 0.f, 0.f};
        if (rr < N) v = *(const float4*)&x[(size_t)rr * 128 + f * 4];
        *(float4*)&xsh[r * 132 + f * 4] = v;
    }
    __syncthreads();

    int tx = t & 15, ty = t >> 4;
    float acc[4][4] = {};
    const float* xb = &xsh[(ty * 4) * 132];
    #pragma unroll 8
    for (int k = 0; k < 128; ++k) {
        float4 wv = *(const float4*)&wsh[k * 64 + tx * 4];
        float x0 = xb[k], x1 = xb[132 + k], x2 = xb[264 + k], x3 = xb[396 + k];
        acc[0][0] += x0 * wv.x; acc[0][1] += x0 * wv.y; acc[0][2] += x0 * wv.z; acc[0][3] += x0 * wv.w;
        acc[1][0] += x1 * wv.x; acc[1][1] += x1 * wv.y; acc[1][2] += x1 * wv.z; acc[1][3] += x1 * wv.w;
        acc[2][0] += x2 * wv.x; acc[2][1] += x2 * wv.y; acc[2][2] += x2 * wv.z; acc[2][3] += x2 * wv.w;
        acc[3][0] += x3 * wv.x; acc[3][1] += x3 * wv.y; acc[3][2] += x3 * wv.z; acc[3][3] += x3 * wv.w;
    }

    float avs[4], avd[4];
    #pragma unroll
    for (int c = 0; c < 4; ++c) {
        avs[c] = a1s_vec[coloff + tx * 4 + c];
        avd[c] = a1d_vec[coloff + tx * 4 + c];
    }
    #pragma unroll
    for (int r = 0; r < 4; ++r) {
        int rr = row0 + ty * 4 + r;
        float ps = acc[r][0] * avs[0] + acc[r][1] * avs[1] + acc[r][2] * avs[2] + acc[r][3] * avs[3];
        float pd = acc[r][0] * avd[0] + acc[r][1] * avd[1] + acc[r][2] * avd[2] + acc[r][3] * avd[3];
        #pragma unroll
        for (int o = 8; o; o >>= 1) { ps += __shfl_xor(ps, o); pd += __shfl_xor(pd, o); }
        if (rr < N) {
            float4 o4 = {acc[r][0], acc[r][1], acc[r][2], acc[r][3]};
            *(float4*)&h1[(size_t)rr * 128 + coloff + tx * 4] = o4;
            if (tx == 0) { a1s[rr * 2 + head] = ps; a1d[rr * 2 + head] = pd; }
        }
    }
}

// ============================ CSR build ============================
__global__ __launch_bounds__(256) void hist_kernel(
    const int* __restrict__ ei, int* __restrict__ deg, int E, int Ep)
{
    int e = blockIdx.x * 256 + threadIdx.x;
    if (e >= Ep) return;
    int dst = (e < E) ? ei[E + e] : e - E;
    atomicAdd(&deg[dst], 1);
}

__global__ __launch_bounds__(256) void blocksum_kernel(
    const int* __restrict__ deg, int* __restrict__ bsum, int N)
{
    __shared__ int sh[4];
    int t = threadIdx.x;
    int i = blockIdx.x * 256 + t;
    int v = (i < N) ? deg[i] : 0;
    #pragma unroll
    for (int o = 32; o; o >>= 1) v += __shfl_xor(v, o);
    if ((t & 63) == 0) sh[t >> 6] = v;
    __syncthreads();
    if (t == 0) bsum[blockIdx.x] = sh[0] + sh[1] + sh[2] + sh[3];
}

__global__ __launch_bounds__(512) void scan_bsum_kernel(int* __restrict__ bsum, int nb)
{
    __shared__ int sh[512];
    int t = threadIdx.x;
    int v = (t < nb) ? bsum[t] : 0;
    sh[t] = v;
    __syncthreads();
    for (int off = 1; off < 512; off <<= 1) {
        int u = (t >= off) ? sh[t - off] : 0;
        __syncthreads();
        sh[t] += u;
        __syncthreads();
    }
    if (t < nb) bsum[t] = sh[t] - v;
}

__global__ __launch_bounds__(256) void scan_final_kernel(
    const int* __restrict__ deg, const int* __restrict__ bsum,
    int* __restrict__ rowStart, int* __restrict__ cursor, int N)
{
    __shared__ int sh[256];
    int t = threadIdx.x;
    int i = blockIdx.x * 256 + t;
    int v = (i < N) ? deg[i] : 0;
    sh[t] = v;
    __syncthreads();
    for (int off = 1; off < 256; off <<= 1) {
        int u = (t >= off) ? sh[t - off] : 0;
        __syncthreads();
        sh[t] += u;
        __syncthreads();
    }
    if (i < N) {
        int exc = sh[t] - v + bsum[blockIdx.x];
        rowStart[i] = exc;
        cursor[i] = exc;
    }
}

__global__ __launch_bounds__(256) void scatter_kernel(
    const int* __restrict__ ei, int* __restrict__ cursor, int* __restrict__ srcS, int E, int Ep)
{
    int e = blockIdx.x * 256 + threadIdx.x;
    if (e >= Ep) return;
    int src, dst;
    if (e < E) { src = ei[e]; dst = ei[E + e]; } else { src = dst = e - E; }
    int pos = atomicAdd(&cursor[dst], 1);
    srcS[pos] = src;
}

// ============================ Fused softmax+aggregate, layer 1 ============================
// One wave per dst node. Weight phase: lane j computes p for edge j of a
// 64-edge chunk (one latency chain per chunk). Gather phase: 4 edges x 16
// lanes x float4 per iteration -- each lane issues 2x16B independent loads,
// the wave covers 4 full edge-rows (2KB) per iter. Cross-edge-subgroup
// reduction via shfl_xor(16|32) at the end.
__global__ __launch_bounds__(256) void fused_aggr1(
    const int* __restrict__ rowStart, const int* __restrict__ deg, const int* __restrict__ srcS,
    const float* __restrict__ a1s, const float* __restrict__ a1d,
    const float* __restrict__ h1, float* __restrict__ out1, int N)
{
    int lane = threadIdx.x & 63;
    int dst = blockIdx.x * 4 + (threadIdx.x >> 6);
    if (dst >= N) return;
    int base = rowStart[dst];
    int d = deg[dst];
    float ad0 = a1d[2 * dst], ad1 = a1d[2 * dst + 1];
    int tx = lane & 15, j2 = lane >> 4;
    float4 acc0 = {0.f, 0.f, 0.f, 0.f}, acc1 = {0.f, 0.f, 0.f, 0.f};
    float dpart0 = 0.f, dpart1 = 0.f;

    for (int c0 = 0; c0 < d; c0 += 64) {
        int cn = min(64, d - c0);
        int s = 0; float p0 = 0.f, p1 = 0.f;
        if (lane < cn) {
            s = srcS[base + c0 + lane];
            float2 av = *(const float2*)&a1s[2 * s];
            float e0 = av.x + ad0, e1 = av.y + ad1;
            e0 = e0 > 0.f ? e0 : NEG_SLOPE * e0;
            e1 = e1 > 0.f ? e1 : NEG_SLOPE * e1;
            p0 = __expf(e0); p1 = __expf(e1);
        }
        dpart0 += p0; dpart1 += p1;
        int niter = (cn + 3) >> 2;
        #pragma unroll 4
        for (int jj = 0; jj < niter; ++jj) {
            int esub = jj * 4 + j2;                 // this subgroup's edge in chunk
            int   sj = __shfl(s, esub);             // p==0 if esub >= cn
            float q0 = __shfl(p0, esub);
            float q1 = __shfl(p1, esub);
            const float* hp = &h1[(size_t)sj * 128 + tx * 4];
            float4 v0 = *(const float4*)hp;
            float4 v1 = *(const float4*)(hp + 64);
            acc0.x += q0 * v0.x; acc0.y += q0 * v0.y; acc0.z += q0 * v0.z; acc0.w += q0 * v0.w;
            acc1.x += q1 * v1.x; acc1.y += q1 * v1.y; acc1.z += q1 * v1.z; acc1.w += q1 * v1.w;
        }
    }
    // reduce partial sums across the 4 edge-subgroups (lanes j2*16+tx)
    #pragma unroll
    for (int o = 16; o <= 32; o <<= 1) {
        acc0.x += __shfl_xor(acc0.x, o); acc0.y += __shfl_xor(acc0.y, o);
        acc0.z += __shfl_xor(acc0.z, o); acc0.w += __shfl_xor(acc0.w, o);
        acc1.x += __shfl_xor(acc1.x, o); acc1.y += __shfl_xor(acc1.y, o);
        acc1.z += __shfl_xor(acc1.z, o); acc1.w += __shfl_xor(acc1.w, o);
    }
    #pragma unroll
    for (int o = 32; o; o >>= 1) { dpart0 += __shfl_xor(dpart0, o); dpart1 += __shfl_xor(dpart1, o); }
    if (j2 == 0) {
        float i0 = 1.f / dpart0, i1 = 1.f / dpart1;
        float4 o0 = {acc0.x * i0, acc0.y * i0, acc0.z * i0, acc0.w * i0};
        float4 o1 = {acc1.x * i1, acc1.y * i1, acc1.z * i1, acc1.w * i1};
        *(float4*)&out1[(size_t)dst * 128 + tx * 4] = o0;
        *(float4*)&out1[(size_t)dst * 128 + 64 + tx * 4] = o1;
    }
}

// ============================ GEMM 2 ============================
// h2 = relu(out1 + b1) @ W2  (128 -> 64); register-tiled.
__global__ __launch_bounds__(256) void gemm2_kernel(
    const float* __restrict__ out1, const float* __restrict__ b1,
    const float* __restrict__ W2,
    const float* __restrict__ a2s_vec, const float* __restrict__ a2d_vec,
    float* __restrict__ h2, float* __restrict__ a2s, float* __restrict__ a2d, int N)
{
    __shared__ float wsh[128 * 64];       // [k][c] == W2 layout
    __shared__ float xsh[64 * 132];       // [r][k]
    int t = threadIdx.x;
    int row0 = blockIdx.x << 6;

    #pragma unroll
    for (int c = 0; c < 8; ++c) {          // W2: straight copy
        int l = c * 256 + t;
        *(float4*)&wsh[l * 4] = *(const float4*)&W2[l * 4];
    }
    #pragma unroll
    for (int c = 0; c < 8; ++c) {          // X tile = relu(out1 + b1)
        int l = c * 256 + t;
        int r = l >> 5, f = l & 31;
        int rr = row0 + r;
        float4 v = {0.f, 0.f, 0.f, 0.f};
        if (rr < N) {
            v = *(const float4*)&out1[(size_t)rr * 128 + f * 4];
            float4 bv = *(const float4*)&b1[f * 4];
            v.x = fmaxf(v.x + bv.x, 0.f);
            v.y = fmaxf(v.y + bv.y, 0.f);
            v.z = fmaxf(v.z + bv.z, 0.f);
            v.w = fmaxf(v.w + bv.w, 0.f);
        }
        *(float4*)&xsh[r * 132 + f * 4] = v;
    }
    __syncthreads();

    int tx = t & 15, ty = t >> 4;
    float acc[4][4] = {};
    const float* xb = &xsh[(ty * 4) * 132];
    #pragma unroll 8
    for (int k = 0; k < 128; ++k) {
        float4 wv = *(const float4*)&wsh[k * 64 + tx * 4];
        float x0 = xb[k], x1 = xb[132 + k], x2 = xb[264 + k], x3 = xb[396 + k];
        acc[0][0] += x0 * wv.x; acc[0][1] += x0 * wv.y; acc[0][2] += x0 * wv.z; acc[0][3] += x0 * wv.w;
        acc[1][0] += x1 * wv.x; acc[1][1] += x1 * wv.y; acc[1][2] += x1 * wv.z; acc[1][3] += x1 * wv.w;
        acc[2][0] += x2 * wv.x; acc[2][1] += x2 * wv.y; acc[2][2] += x2 * wv.z; acc[2][3] += x2 * wv.w;
        acc[3][0] += x3 * wv.x; acc[3][1] += x3 * wv.y; acc[3][2] += x3 * wv.z; acc[3][3] += x3 * wv.w;
    }

    float avs[4], avd[4];
    #pragma unroll
    for (int c = 0; c < 4; ++c) {
        avs[c] = a2s_vec[tx * 4 + c];
        avd[c] = a2d_vec[tx * 4 + c];
    }
    #pragma unroll
    for (int r = 0; r < 4; ++r) {
        int rr = row0 + ty * 4 + r;
        float ps = acc[r][0] * avs[0] + acc[r][1] * avs[1] + acc[r][2] * avs[2] + acc[r][3] * avs[3];
        float pd = acc[r][0] * avd[0] + acc[r][1] * avd[1] + acc[r][2] * avd[2] + acc[r][3] * avd[3];
        #pragma unroll
        for (int o = 8; o; o >>= 1) { ps += __shfl_xor(ps, o); pd += __shfl_xor(pd, o); }
        if (rr < N) {
            float4 o4 = {acc[r][0], acc[r][1], acc[r][2], acc[r][3]};
            *(float4*)&h2[(size_t)rr * 64 + tx * 4] = o4;
            if (tx == 0) { a2s[rr] = ps; a2d[rr] = pd; }
        }
    }
}

// ============================ Fused softmax+aggregate, layer 2 ============================
// Same 4-edge x 16-lane x float4 structure; 64 channels.
__global__ __launch_bounds__(256) void fused_aggr2(
    const int* __restrict__ rowStart, const int* __restrict__ deg, const int* __restrict__ srcS,
    const float* __restrict__ a2s, const float* __restrict__ a2d,
    const float* __restrict__ h2, float* __restrict__ out2, int N)
{
    int lane = threadIdx.x & 63;
    int dst = blockIdx.x * 4 + (threadIdx.x >> 6);
    if (dst >= N) return;
    int base = rowStart[dst];
    int d = deg[dst];
    float ad = a2d[dst];
    int tx = lane & 15, j2 = lane >> 4;
    float4 acc = {0.f, 0.f, 0.f, 0.f};
    float dpart = 0.f;

    for (int c0 = 0; c0 < d; c0 += 64) {
        int cn = min(64, d - c0);
        int s = 0; float p = 0.f;
        if (lane < cn) {
            s = srcS[base + c0 + lane];
            float e = a2s[s] + ad;
            e = e > 0.f ? e : NEG_SLOPE * e;
            p = __expf(e);
        }
        dpart += p;
        int niter = (cn + 3) >> 2;
        #pragma unroll 4
        for (int jj = 0; jj < niter; ++jj) {
            int esub = jj * 4 + j2;
            int   sj = __shfl(s, esub);
            float q  = __shfl(p, esub);
            float4 v = *(const float4*)&h2[(size_t)sj * 64 + tx * 4];
            acc.x += q * v.x; acc.y += q * v.y; acc.z += q * v.z; acc.w += q * v.w;
        }
    }
    #pragma unroll
    for (int o = 16; o <= 32; o <<= 1) {
        acc.x += __shfl_xor(acc.x, o); acc.y += __shfl_xor(acc.y, o);
        acc.z += __shfl_xor(acc.z, o); acc.w += __shfl_xor(acc.w, o);
    }
    #pragma unroll
    for (int o = 32; o; o >>= 1) dpart += __shfl_xor(dpart, o);
    if (j2 == 0) {
        float iv = 1.f / dpart;
        float4 o4 = {acc.x * iv, acc.y * iv, acc.z * iv, acc.w * iv};
        *(float4*)&out2[(size_t)dst * 64 + tx * 4] = o4;
    }
}

// ============================ Pool ============================
__global__ __launch_bounds__(256) void pool_kernel(
    const float* __restrict__ out2, const float* __restrict__ b2,
    const int* __restrict__ batch, float* __restrict__ pool, float* __restrict__ cnt, int N)
{
    int lane = threadIdx.x & 63;
    int gwave = blockIdx.x * 4 + (threadIdx.x >> 6);
    int nwaves = gridDim.x * 4;
    int per = (N + nwaves - 1) / nwaves;
    int n0 = gwave * per;
    int n1 = min(n0 + per, N);
    if (n0 >= n1) return;
    float bb = b2[lane];
    float acc = 0.f;
    int count = 0;
    int gcur = batch[n0];
    for (int n = n0; n < n1; ++n) {
        int g = batch[n];
        if (g != gcur) {
            atomicAdd(&pool[gcur * 64 + lane], acc);
            if (lane == 0) atomicAdd(&cnt[gcur], (float)count);
            acc = 0.f; count = 0; gcur = g;
        }
        float v = out2[(size_t)n * 64 + lane] + bb;
        acc += v > 0.f ? v : 0.f;
        ++count;
    }
    atomicAdd(&pool[gcur * 64 + lane], acc);
    if (lane == 0) atomicAdd(&cnt[gcur], (float)count);
}

// ============================ Final linear ============================
__global__ void final_kernel(
    const float* __restrict__ pool, const float* __restrict__ cnt,
    const float* __restrict__ Wlin, const float* __restrict__ blin,
    float* __restrict__ out, int G)
{
    int g = threadIdx.x;
    if (g >= G) return;
    float s = 0.f;
    #pragma unroll 8
    for (int c = 0; c < 64; ++c) s += pool[g * 64 + c] * Wlin[c];
    float cn = cnt[g]; cn = cn > 1.f ? cn : 1.f;
    out[g] = s / cn + blin[0];
}

extern "C" void kernel_launch(void* const* d_in, const int* in_sizes, int n_in,
                              void* d_out, int out_size, void* d_ws, size_t ws_size,
                              hipStream_t stream) {
    const float* x     = (const float*)d_in[0];
    const int*   ei    = (const int*)d_in[1];
    const int*   batch = (const int*)d_in[2];
    const float* W1    = (const float*)d_in[3];
    const float* a1sv  = (const float*)d_in[4];
    const float* a1dv  = (const float*)d_in[5];
    const float* b1    = (const float*)d_in[6];
    const float* W2    = (const float*)d_in[7];
    const float* a2sv  = (const float*)d_in[8];
    const float* a2dv  = (const float*)d_in[9];
    const float* b2    = (const float*)d_in[10];
    const float* Wlin  = (const float*)d_in[11];
    const float* blin  = (const float*)d_in[12];

    int N  = in_sizes[2];
    int E  = in_sizes[1] / 2;
    int Ep = E + N;
    const int G = 64;
    int nb = (N + 255) / 256;   // scan blocks (<= 512)

    float* ws = (float*)d_ws;
    size_t off = 0;
    float* h1   = ws + off; off += (size_t)N * 128;
    float* out1 = ws + off; off += (size_t)N * 128;
    float* h2   = ws + off; off += (size_t)N * 64;
    float* a1s  = ws + off; off += (size_t)N * 2;
    float* a1d  = ws + off; off += (size_t)N * 2;
    float* a2s  = ws + off; off += N;
    float* a2d  = ws + off; off += N;
    int* degA   = (int*)(ws + off); off += N;
    int* rowStart = (int*)(ws + off); off += N;
    int* cursor = (int*)(ws + off); off += N;
    int* bsum   = (int*)(ws + off); off += 512;
    int* srcS   = (int*)(ws + off); off += Ep;
    float* pool = ws + off; off += G * 64;
    float* cnt  = ws + off; off += G;
    float* out2 = h1;   // alias: h1 dead after fused_aggr1

    hipMemsetAsync(degA, 0, (size_t)N * sizeof(int), stream);
    hipMemsetAsync(pool, 0, (size_t)(G * 64 + G) * sizeof(float), stream);

    // CSR build (independent of gemm1)
    hist_kernel<<<(Ep + 255) / 256, 256, 0, stream>>>(ei, degA, E, Ep);
    blocksum_kernel<<<nb, 256, 0, stream>>>(degA, bsum, N);
    scan_bsum_kernel<<<1, 512, 0, stream>>>(bsum, nb);
    scan_final_kernel<<<nb, 256, 0, stream>>>(degA, bsum, rowStart, cursor, N);
    scatter_kernel<<<(Ep + 255) / 256, 256, 0, stream>>>(ei, cursor, srcS, E, Ep);

    dim3 g1((N + 63) / 64, 2);
    gemm1_kernel<<<g1, 256, 0, stream>>>(x, W1, a1sv, a1dv, h1, a1s, a1d, N);
    fused_aggr1<<<(N + 3) / 4, 256, 0, stream>>>(rowStart, degA, srcS, a1s, a1d, h1, out1, N);
    gemm2_kernel<<<(N + 63) / 64, 256, 0, stream>>>(out1, b1, W2, a2sv, a2dv, h2, a2s, a2d, N);
    fused_aggr2<<<(N + 3) / 4, 256, 0, stream>>>(rowStart, degA, srcS, a2s, a2d, h2, out2, N);
    pool_kernel<<<256, 256, 0, stream>>>(out2, b2, batch, pool, cnt, N);
    final_kernel<<<1, 64, 0, stream>>>(pool, cnt, Wlin, blin, (float*)d_out, G);
}

// Round 7
// 471.478 us; speedup vs baseline: 5.3537x; 1.1525x over previous
//
#include <hip/hip_runtime.h>
#include <hip/hip_fp16.h>

#define NEG_SLOPE 0.2f

typedef _Float16 f16;
typedef __attribute__((ext_vector_type(8))) _Float16 half8;
typedef __attribute__((ext_vector_type(4))) _Float16 half4;

// ============================ GEMM 1 ============================
// h1h[:, head*64:+64] = fp16(x @ W1[:, head*64:+64])  (head = blockIdx.y)
// logits a1s/a1d computed in fp32 from the fp32 accumulators.
__global__ __launch_bounds__(256) void gemm1_kernel(
    const float* __restrict__ x, const float* __restrict__ W1,
    const float* __restrict__ a1s_vec, const float* __restrict__ a1d_vec,
    f16* __restrict__ h1h, float* __restrict__ a1s, float* __restrict__ a1d, int N)
{
    __shared__ float wsh[128 * 64];       // [k][c]
    __shared__ float xsh[64 * 132];       // [r][k], pad 128->132
    int t = threadIdx.x;
    int head = blockIdx.y;
    int coloff = head << 6;
    int row0 = blockIdx.x << 6;

    #pragma unroll
    for (int c = 0; c < 8; ++c) {          // W tile: 128x64
        int l = c * 256 + t;
        int k = l >> 4, f = l & 15;
        *(float4*)&wsh[k * 64 + f * 4] = *(const float4*)&W1[k * 128 + coloff + f * 4];
    }
    #pragma unroll
    for (int c = 0; c < 8; ++c) {          // X tile: 64x128
        int l = c * 256 + t;
        int r = l >> 5, f = l & 31;
        int rr = row0 + r;
        float4 v = {0.f, 0.f, 0.f, 0.f};
        if (rr < N) v = *(const float4*)&x[(size_t)rr * 128 + f * 4];
        *(float4*)&xsh[r * 132 + f * 4] = v;
    }
    __syncthreads();

    int tx = t & 15, ty = t >> 4;
    float acc[4][4] = {};
    const float* xb = &xsh[(ty * 4) * 132];
    #pragma unroll 8
    for (int k = 0; k < 128; ++k) {
        float4 wv = *(const float4*)&wsh[k * 64 + tx * 4];
        float x0 = xb[k], x1 = xb[132 + k], x2 = xb[264 + k], x3 = xb[396 + k];
        acc[0][0] += x0 * wv.x; acc[0][1] += x0 * wv.y; acc[0][2] += x0 * wv.z; acc[0][3] += x0 * wv.w;
        acc[1][0] += x1 * wv.x; acc[1][1] += x1 * wv.y; acc[1][2] += x1 * wv.z; acc[1][3] += x1 * wv.w;
        acc[2][0] += x2 * wv.x; acc[2][1] += x2 * wv.y; acc[2][2] += x2 * wv.z; acc[2][3] += x2 * wv.w;
        acc[3][0] += x3 * wv.x; acc[3][1] += x3 * wv.y; acc[3][2] += x3 * wv.z; acc[3][3] += x3 * wv.w;
    }

    float avs[4], avd[4];
    #pragma unroll
    for (int c = 0; c < 4; ++c) {
        avs[c] = a1s_vec[coloff + tx * 4 + c];
        avd[c] = a1d_vec[coloff + tx * 4 + c];
    }
    #pragma unroll
    for (int r = 0; r < 4; ++r) {
        int rr = row0 + ty * 4 + r;
        float ps = acc[r][0] * avs[0] + acc[r][1] * avs[1] + acc[r][2] * avs[2] + acc[r][3] * avs[3];
        float pd = acc[r][0] * avd[0] + acc[r][1] * avd[1] + acc[r][2] * avd[2] + acc[r][3] * avd[3];
        #pragma unroll
        for (int o = 8; o; o >>= 1) { ps += __shfl_xor(ps, o); pd += __shfl_xor(pd, o); }
        if (rr < N) {
            half4 o4 = {(f16)acc[r][0], (f16)acc[r][1], (f16)acc[r][2], (f16)acc[r][3]};
            *(half4*)&h1h[(size_t)rr * 128 + coloff + tx * 4] = o4;
            if (tx == 0) { a1s[rr * 2 + head] = ps; a1d[rr * 2 + head] = pd; }
        }
    }
}

// ============================ CSR build ============================
__global__ __launch_bounds__(256) void hist_kernel(
    const int* __restrict__ ei, int* __restrict__ deg, int E, int Ep)
{
    int e = blockIdx.x * 256 + threadIdx.x;
    if (e >= Ep) return;
    int dst = (e < E) ? ei[E + e] : e - E;
    atomicAdd(&deg[dst], 1);
}

__global__ __launch_bounds__(256) void blocksum_kernel(
    const int* __restrict__ deg, int* __restrict__ bsum, int N)
{
    __shared__ int sh[4];
    int t = threadIdx.x;
    int i = blockIdx.x * 256 + t;
    int v = (i < N) ? deg[i] : 0;
    #pragma unroll
    for (int o = 32; o; o >>= 1) v += __shfl_xor(v, o);
    if ((t & 63) == 0) sh[t >> 6] = v;
    __syncthreads();
    if (t == 0) bsum[blockIdx.x] = sh[0] + sh[1] + sh[2] + sh[3];
}

__global__ __launch_bounds__(512) void scan_bsum_kernel(int* __restrict__ bsum, int nb)
{
    __shared__ int sh[512];
    int t = threadIdx.x;
    int v = (t < nb) ? bsum[t] : 0;
    sh[t] = v;
    __syncthreads();
    for (int off = 1; off < 512; off <<= 1) {
        int u = (t >= off) ? sh[t - off] : 0;
        __syncthreads();
        sh[t] += u;
        __syncthreads();
    }
    if (t < nb) bsum[t] = sh[t] - v;
}

__global__ __launch_bounds__(256) void scan_final_kernel(
    const int* __restrict__ deg, const int* __restrict__ bsum,
    int* __restrict__ rowStart, int* __restrict__ cursor, int N)
{
    __shared__ int sh[256];
    int t = threadIdx.x;
    int i = blockIdx.x * 256 + t;
    int v = (i < N) ? deg[i] : 0;
    sh[t] = v;
    __syncthreads();
    for (int off = 1; off < 256; off <<= 1) {
        int u = (t >= off) ? sh[t - off] : 0;
        __syncthreads();
        sh[t] += u;
        __syncthreads();
    }
    if (i < N) {
        int exc = sh[t] - v + bsum[blockIdx.x];
        rowStart[i] = exc;
        cursor[i] = exc;
    }
}

__global__ __launch_bounds__(256) void scatter_kernel(
    const int* __restrict__ ei, int* __restrict__ cursor, int* __restrict__ srcS, int E, int Ep)
{
    int e = blockIdx.x * 256 + threadIdx.x;
    if (e >= Ep) return;
    int src, dst;
    if (e < E) { src = ei[e]; dst = ei[E + e]; } else { src = dst = e - E; }
    int pos = atomicAdd(&cursor[dst], 1);
    srcS[pos] = src;
}

// ============================ Fused softmax+aggregate, layer 1 ============================
// One wave per dst node. Weight phase: lane j computes p for edge j of a
// 64-edge chunk. Gather phase: 4 edges x 16 lanes x 16B(half8) per iter --
// one fp16 row (256B) per edge. Lane tx covers channels tx*8..tx*8+7
// (tx<8 -> head0 weight q0, tx>=8 -> head1 weight q1).
__global__ __launch_bounds__(256) void fused_aggr1(
    const int* __restrict__ rowStart, const int* __restrict__ deg, const int* __restrict__ srcS,
    const float* __restrict__ a1s, const float* __restrict__ a1d,
    const f16* __restrict__ h1h, float* __restrict__ out1, int N)
{
    int lane = threadIdx.x & 63;
    int dst = blockIdx.x * 4 + (threadIdx.x >> 6);
    if (dst >= N) return;
    int base = rowStart[dst];
    int d = deg[dst];
    float ad0 = a1d[2 * dst], ad1 = a1d[2 * dst + 1];
    int tx = lane & 15, j2 = lane >> 4;
    float acc[8] = {};
    float dpart0 = 0.f, dpart1 = 0.f;

    for (int c0 = 0; c0 < d; c0 += 64) {
        int cn = min(64, d - c0);
        int s = 0; float p0 = 0.f, p1 = 0.f;
        if (lane < cn) {
            s = srcS[base + c0 + lane];
            float2 av = *(const float2*)&a1s[2 * s];
            float e0 = av.x + ad0, e1 = av.y + ad1;
            e0 = e0 > 0.f ? e0 : NEG_SLOPE * e0;
            e1 = e1 > 0.f ? e1 : NEG_SLOPE * e1;
            p0 = __expf(e0); p1 = __expf(e1);
        }
        dpart0 += p0; dpart1 += p1;
        int niter = (cn + 3) >> 2;
        #pragma unroll 4
        for (int jj = 0; jj < niter; ++jj) {
            int esub = jj * 4 + j2;                 // p==0 for esub >= cn
            int   sj = __shfl(s, esub);
            float q0 = __shfl(p0, esub);
            float q1 = __shfl(p1, esub);
            float q  = (tx < 8) ? q0 : q1;
            half8 v = *(const half8*)&h1h[(size_t)sj * 128 + tx * 8];
            #pragma unroll
            for (int k = 0; k < 8; ++k) acc[k] += q * (float)v[k];
        }
    }
    // reduce partials across the 4 edge-subgroups
    #pragma unroll
    for (int k = 0; k < 8; ++k) acc[k] += __shfl_xor(acc[k], 16);
    #pragma unroll
    for (int k = 0; k < 8; ++k) acc[k] += __shfl_xor(acc[k], 32);
    #pragma unroll
    for (int o = 32; o; o >>= 1) { dpart0 += __shfl_xor(dpart0, o); dpart1 += __shfl_xor(dpart1, o); }
    if (j2 == 0) {
        float iv = (tx < 8) ? (1.f / dpart0) : (1.f / dpart1);
        float4 lo = {acc[0] * iv, acc[1] * iv, acc[2] * iv, acc[3] * iv};
        float4 hi = {acc[4] * iv, acc[5] * iv, acc[6] * iv, acc[7] * iv};
        *(float4*)&out1[(size_t)dst * 128 + tx * 8] = lo;
        *(float4*)&out1[(size_t)dst * 128 + tx * 8 + 4] = hi;
    }
}

// ============================ GEMM 2 ============================
// h2h = fp16(relu(out1 + b1) @ W2)  (128 -> 64); logits fp32.
__global__ __launch_bounds__(256) void gemm2_kernel(
    const float* __restrict__ out1, const float* __restrict__ b1,
    const float* __restrict__ W2,
    const float* __restrict__ a2s_vec, const float* __restrict__ a2d_vec,
    f16* __restrict__ h2h, float* __restrict__ a2s, float* __restrict__ a2d, int N)
{
    __shared__ float wsh[128 * 64];       // [k][c] == W2 layout
    __shared__ float xsh[64 * 132];       // [r][k]
    int t = threadIdx.x;
    int row0 = blockIdx.x << 6;

    #pragma unroll
    for (int c = 0; c < 8; ++c) {          // W2: straight copy
        int l = c * 256 + t;
        *(float4*)&wsh[l * 4] = *(const float4*)&W2[l * 4];
    }
    #pragma unroll
    for (int c = 0; c < 8; ++c) {          // X tile = relu(out1 + b1)
        int l = c * 256 + t;
        int r = l >> 5, f = l & 31;
        int rr = row0 + r;
        float4 v = {0.f, 0.f, 0.f, 0.f};
        if (rr < N) {
            v = *(const float4*)&out1[(size_t)rr * 128 + f * 4];
            float4 bv = *(const float4*)&b1[f * 4];
            v.x = fmaxf(v.x + bv.x, 0.f);
            v.y = fmaxf(v.y + bv.y, 0.f);
            v.z = fmaxf(v.z + bv.z, 0.f);
            v.w = fmaxf(v.w + bv.w, 0.f);
        }
        *(float4*)&xsh[r * 132 + f * 4] = v;
    }
    __syncthreads();

    int tx = t & 15, ty = t >> 4;
    float acc[4][4] = {};
    const float* xb = &xsh[(ty * 4) * 132];
    #pragma unroll 8
    for (int k = 0; k < 128; ++k) {
        float4 wv = *(const float4*)&wsh[k * 64 + tx * 4];
        float x0 = xb[k], x1 = xb[132 + k], x2 = xb[264 + k], x3 = xb[396 + k];
        acc[0][0] += x0 * wv.x; acc[0][1] += x0 * wv.y; acc[0][2] += x0 * wv.z; acc[0][3] += x0 * wv.w;
        acc[1][0] += x1 * wv.x; acc[1][1] += x1 * wv.y; acc[1][2] += x1 * wv.z; acc[1][3] += x1 * wv.w;
        acc[2][0] += x2 * wv.x; acc[2][1] += x2 * wv.y; acc[2][2] += x2 * wv.z; acc[2][3] += x2 * wv.w;
        acc[3][0] += x3 * wv.x; acc[3][1] += x3 * wv.y; acc[3][2] += x3 * wv.z; acc[3][3] += x3 * wv.w;
    }

    float avs[4], avd[4];
    #pragma unroll
    for (int c = 0; c < 4; ++c) {
        avs[c] = a2s_vec[tx * 4 + c];
        avd[c] = a2d_vec[tx * 4 + c];
    }
    #pragma unroll
    for (int r = 0; r < 4; ++r) {
        int rr = row0 + ty * 4 + r;
        float ps = acc[r][0] * avs[0] + acc[r][1] * avs[1] + acc[r][2] * avs[2] + acc[r][3] * avs[3];
        float pd = acc[r][0] * avd[0] + acc[r][1] * avd[1] + acc[r][2] * avd[2] + acc[r][3] * avd[3];
        #pragma unroll
        for (int o = 8; o; o >>= 1) { ps += __shfl_xor(ps, o); pd += __shfl_xor(pd, o); }
        if (rr < N) {
            half4 o4 = {(f16)acc[r][0], (f16)acc[r][1], (f16)acc[r][2], (f16)acc[r][3]};
            *(half4*)&h2h[(size_t)rr * 64 + tx * 4] = o4;
            if (tx == 0) { a2s[rr] = ps; a2d[rr] = pd; }
        }
    }
}

// ============================ Fused softmax+aggregate, layer 2 ============================
// 8 edges x 8 lanes x 16B(half8) per iteration -- one fp16 row (128B) per edge.
__global__ __launch_bounds__(256) void fused_aggr2(
    const int* __restrict__ rowStart, const int* __restrict__ deg, const int* __restrict__ srcS,
    const float* __restrict__ a2s, const float* __restrict__ a2d,
    const f16* __restrict__ h2h, float* __restrict__ out2, int N)
{
    int lane = threadIdx.x & 63;
    int dst = blockIdx.x * 4 + (threadIdx.x >> 6);
    if (dst >= N) return;
    int base = rowStart[dst];
    int d = deg[dst];
    float ad = a2d[dst];
    int tx = lane & 7, j3 = lane >> 3;
    float acc[8] = {};
    float dpart = 0.f;

    for (int c0 = 0; c0 < d; c0 += 64) {
        int cn = min(64, d - c0);
        int s = 0; float p = 0.f;
        if (lane < cn) {
            s = srcS[base + c0 + lane];
            float e = a2s[s] + ad;
            e = e > 0.f ? e : NEG_SLOPE * e;
            p = __expf(e);
        }
        dpart += p;
        int niter = (cn + 7) >> 3;
        #pragma unroll 4
        for (int jj = 0; jj < niter; ++jj) {
            int esub = jj * 8 + j3;
            int   sj = __shfl(s, esub);
            float q  = __shfl(p, esub);
            half8 v = *(const half8*)&h2h[(size_t)sj * 64 + tx * 8];
            #pragma unroll
            for (int k = 0; k < 8; ++k) acc[k] += q * (float)v[k];
        }
    }
    #pragma unroll
    for (int k = 0; k < 8; ++k) acc[k] += __shfl_xor(acc[k], 8);
    #pragma unroll
    for (int k = 0; k < 8; ++k) acc[k] += __shfl_xor(acc[k], 16);
    #pragma unroll
    for (int k = 0; k < 8; ++k) acc[k] += __shfl_xor(acc[k], 32);
    #pragma unroll
    for (int o = 32; o; o >>= 1) dpart += __shfl_xor(dpart, o);
    if (j3 == 0) {
        float iv = 1.f / dpart;
        float4 lo = {acc[0] * iv, acc[1] * iv, acc[2] * iv, acc[3] * iv};
        float4 hi = {acc[4] * iv, acc[5] * iv, acc[6] * iv, acc[7] * iv};
        *(float4*)&out2[(size_t)dst * 64 + tx * 8] = lo;
        *(float4*)&out2[(size_t)dst * 64 + tx * 8 + 4] = hi;
    }
}

// ============================ Pool ============================
__global__ __launch_bounds__(256) void pool_kernel(
    const float* __restrict__ out2, const float* __restrict__ b2,
    const int* __restrict__ batch, float* __restrict__ pool, float* __restrict__ cnt, int N)
{
    int lane = threadIdx.x & 63;
    int gwave = blockIdx.x * 4 + (threadIdx.x >> 6);
    int nwaves = gridDim.x * 4;
    int per = (N + nwaves - 1) / nwaves;
    int n0 = gwave * per;
    int n1 = min(n0 + per, N);
    if (n0 >= n1) return;
    float bb = b2[lane];
    float acc = 0.f;
    int count = 0;
    int gcur = batch[n0];
    for (int n = n0; n < n1; ++n) {
        int g = batch[n];
        if (g != gcur) {
            atomicAdd(&pool[gcur * 64 + lane], acc);
            if (lane == 0) atomicAdd(&cnt[gcur], (float)count);
            acc = 0.f; count = 0; gcur = g;
        }
        float v = out2[(size_t)n * 64 + lane] + bb;
        acc += v > 0.f ? v : 0.f;
        ++count;
    }
    atomicAdd(&pool[gcur * 64 + lane], acc);
    if (lane == 0) atomicAdd(&cnt[gcur], (float)count);
}

// ============================ Final linear ============================
__global__ void final_kernel(
    const float* __restrict__ pool, const float* __restrict__ cnt,
    const float* __restrict__ Wlin, const float* __restrict__ blin,
    float* __restrict__ out, int G)
{
    int g = threadIdx.x;
    if (g >= G) return;
    float s = 0.f;
    #pragma unroll 8
    for (int c = 0; c < 64; ++c) s += pool[g * 64 + c] * Wlin[c];
    float cn = cnt[g]; cn = cn > 1.f ? cn : 1.f;
    out[g] = s / cn + blin[0];
}

extern "C" void kernel_launch(void* const* d_in, const int* in_sizes, int n_in,
                              void* d_out, int out_size, void* d_ws, size_t ws_size,
                              hipStream_t stream) {
    const float* x     = (const float*)d_in[0];
    const int*   ei    = (const int*)d_in[1];
    const int*   batch = (const int*)d_in[2];
    const float* W1    = (const float*)d_in[3];
    const float* a1sv  = (const float*)d_in[4];
    const float* a1dv  = (const float*)d_in[5];
    const float* b1    = (const float*)d_in[6];
    const float* W2    = (const float*)d_in[7];
    const float* a2sv  = (const float*)d_in[8];
    const float* a2dv  = (const float*)d_in[9];
    const float* b2    = (const float*)d_in[10];
    const float* Wlin  = (const float*)d_in[11];
    const float* blin  = (const float*)d_in[12];

    int N  = in_sizes[2];
    int E  = in_sizes[1] / 2;
    int Ep = E + N;
    const int G = 64;
    int nb = (N + 255) / 256;   // scan blocks (<= 512)

    float* ws = (float*)d_ws;
    size_t off = 0;
    float* out1 = ws + off; off += (size_t)N * 128;
    f16*  h1h   = (f16*)(ws + off); off += (size_t)N * 64;   // N*128 halves
    f16*  h2h   = (f16*)(ws + off); off += (size_t)N * 32;   // N*64 halves
    float* a1s  = ws + off; off += (size_t)N * 2;
    float* a1d  = ws + off; off += (size_t)N * 2;
    float* a2s  = ws + off; off += N;
    float* a2d  = ws + off; off += N;
    int* degA   = (int*)(ws + off); off += N;
    int* rowStart = (int*)(ws + off); off += N;
    int* cursor = (int*)(ws + off); off += N;
    int* bsum   = (int*)(ws + off); off += 512;
    int* srcS   = (int*)(ws + off); off += Ep;
    float* pool = ws + off; off += G * 64;
    float* cnt  = ws + off; off += G;
    float* out2 = (float*)h1h;   // alias: h1h (N*128 halves == N*64 floats) dead after fused_aggr1

    hipMemsetAsync(degA, 0, (size_t)N * sizeof(int), stream);
    hipMemsetAsync(pool, 0, (size_t)(G * 64 + G) * sizeof(float), stream);

    // CSR build (independent of gemm1)
    hist_kernel<<<(Ep + 255) / 256, 256, 0, stream>>>(ei, degA, E, Ep);
    blocksum_kernel<<<nb, 256, 0, stream>>>(degA, bsum, N);
    scan_bsum_kernel<<<1, 512, 0, stream>>>(bsum, nb);
    scan_final_kernel<<<nb, 256, 0, stream>>>(degA, bsum, rowStart, cursor, N);
    scatter_kernel<<<(Ep + 255) / 256, 256, 0, stream>>>(ei, cursor, srcS, E, Ep);

    dim3 g1((N + 63) / 64, 2);
    gemm1_kernel<<<g1, 256, 0, stream>>>(x, W1, a1sv, a1dv, h1h, a1s, a1d, N);
    fused_aggr1<<<(N + 3) / 4, 256, 0, stream>>>(rowStart, degA, srcS, a1s, a1d, h1h, out1, N);
    gemm2_kernel<<<(N + 63) / 64, 256, 0, stream>>>(out1, b1, W2, a2sv, a2dv, h2h, a2s, a2d, N);
    fused_aggr2<<<(N + 3) / 4, 256, 0, stream>>>(rowStart, degA, srcS, a2s, a2d, h2h, out2, N);
    pool_kernel<<<256, 256, 0, stream>>>(out2, b2, batch, pool, cnt, N);
    final_kernel<<<1, 64, 0, stream>>>(pool, cnt, Wlin, blin, (float*)d_out, G);
}

// Round 8
// 414.662 us; speedup vs baseline: 6.0873x; 1.1370x over previous
//
#include <hip/hip_runtime.h>
#include <hip/hip_fp16.h>

#define NEG_SLOPE 0.2f
#define BSH 9                    // bucket = dst >> 9  (512 nodes / bucket)
#define NBUCK 256                // covers dst < 131072
#define NB1 256                  // pass A/C blocks
#define DCAP 12288               // pass D LDS staging capacity (uints)

typedef _Float16 f16;
typedef __attribute__((ext_vector_type(8))) _Float16 half8;
typedef __attribute__((ext_vector_type(4))) _Float16 half4;

// ============================ GEMM 1 ============================
__global__ __launch_bounds__(256) void gemm1_kernel(
    const float* __restrict__ x, const float* __restrict__ W1,
    const float* __restrict__ a1s_vec, const float* __restrict__ a1d_vec,
    f16* __restrict__ h1h, float* __restrict__ a1s, float* __restrict__ a1d, int N)
{
    __shared__ float wsh[128 * 64];       // [k][c]
    __shared__ float xsh[64 * 132];       // [r][k], pad 128->132
    int t = threadIdx.x;
    int head = blockIdx.y;
    int coloff = head << 6;
    int row0 = blockIdx.x << 6;

    #pragma unroll
    for (int c = 0; c < 8; ++c) {          // W tile: 128x64
        int l = c * 256 + t;
        int k = l >> 4, f = l & 15;
        *(float4*)&wsh[k * 64 + f * 4] = *(const float4*)&W1[k * 128 + coloff + f * 4];
    }
    #pragma unroll
    for (int c = 0; c < 8; ++c) {          // X tile: 64x128
        int l = c * 256 + t;
        int r = l >> 5, f = l & 31;
        int rr = row0 + r;
        float4 v = {0.f, 0.f, 0.f, 0.f};
        if (rr < N) v = *(const float4*)&x[(size_t)rr * 128 + f * 4];
        *(float4*)&xsh[r * 132 + f * 4] = v;
    }
    __syncthreads();

    int tx = t & 15, ty = t >> 4;
    float acc[4][4] = {};
    const float* xb = &xsh[(ty * 4) * 132];
    #pragma unroll 8
    for (int k = 0; k < 128; ++k) {
        float4 wv = *(const float4*)&wsh[k * 64 + tx * 4];
        float x0 = xb[k], x1 = xb[132 + k], x2 = xb[264 + k], x3 = xb[396 + k];
        acc[0][0] += x0 * wv.x; acc[0][1] += x0 * wv.y; acc[0][2] += x0 * wv.z; acc[0][3] += x0 * wv.w;
        acc[1][0] += x1 * wv.x; acc[1][1] += x1 * wv.y; acc[1][2] += x1 * wv.z; acc[1][3] += x1 * wv.w;
        acc[2][0] += x2 * wv.x; acc[2][1] += x2 * wv.y; acc[2][2] += x2 * wv.z; acc[2][3] += x2 * wv.w;
        acc[3][0] += x3 * wv.x; acc[3][1] += x3 * wv.y; acc[3][2] += x3 * wv.z; acc[3][3] += x3 * wv.w;
    }

    float avs[4], avd[4];
    #pragma unroll
    for (int c = 0; c < 4; ++c) {
        avs[c] = a1s_vec[coloff + tx * 4 + c];
        avd[c] = a1d_vec[coloff + tx * 4 + c];
    }
    #pragma unroll
    for (int r = 0; r < 4; ++r) {
        int rr = row0 + ty * 4 + r;
        float ps = acc[r][0] * avs[0] + acc[r][1] * avs[1] + acc[r][2] * avs[2] + acc[r][3] * avs[3];
        float pd = acc[r][0] * avd[0] + acc[r][1] * avd[1] + acc[r][2] * avd[2] + acc[r][3] * avd[3];
        #pragma unroll
        for (int o = 8; o; o >>= 1) { ps += __shfl_xor(ps, o); pd += __shfl_xor(pd, o); }
        if (rr < N) {
            half4 o4 = {(f16)acc[r][0], (f16)acc[r][1], (f16)acc[r][2], (f16)acc[r][3]};
            *(half4*)&h1h[(size_t)rr * 128 + coloff + tx * 4] = o4;
            if (tx == 0) { a1s[rr * 2 + head] = ps; a1d[rr * 2 + head] = pd; }
        }
    }
}

// ============================ CSR build: two-level bucket sort ============================
// Pass A: per-block LDS histogram over 256 coarse buckets (dst>>9).
__global__ __launch_bounds__(256) void bucket_count(
    const int* __restrict__ ei, int* __restrict__ cntg, int E, int Ep, int chunk)
{
    __shared__ int lc[NBUCK];
    int i = blockIdx.x, t = threadIdx.x;
    lc[t] = 0;
    __syncthreads();
    int e0 = i * chunk, e1 = min(e0 + chunk, Ep);
    for (int e = e0 + t; e < e1; e += 256) {
        int dst = (e < E) ? ei[E + e] : e - E;
        atomicAdd(&lc[dst >> BSH], 1);
    }
    __syncthreads();
    cntg[i * NBUCK + t] = lc[t];
}

// Pass B: offs[i][b] = bucketBase[b] + sum_{j<i} cntg[j][b]; bucketBase via LDS scan.
__global__ __launch_bounds__(256) void bucket_scan(
    int* __restrict__ cntg, int* __restrict__ offs, int* __restrict__ bucketBase, int nb)
{
    __shared__ int sh[256];
    int b = threadIdx.x;
    int run = 0;
    for (int i = 0; i < nb; ++i) {
        int c = cntg[i * NBUCK + b];
        offs[i * NBUCK + b] = run;
        run += c;
    }
    int tot = run;
    sh[b] = tot;
    __syncthreads();
    for (int off = 1; off < 256; off <<= 1) {
        int u = (b >= off) ? sh[b - off] : 0;
        __syncthreads();
        sh[b] += u;
        __syncthreads();
    }
    int base = sh[b] - tot;       // exclusive
    bucketBase[b] = base;
    if (b == 255) bucketBase[256] = sh[255];
    for (int i = 0; i < nb; ++i) offs[i * NBUCK + b] += base;
}

// Pass C: place packed (dstLocal<<17 | src) via LDS cursors (no global atomics).
__global__ __launch_bounds__(256) void bucket_place(
    const int* __restrict__ ei, const int* __restrict__ offs,
    unsigned* __restrict__ pairs, int E, int Ep, int chunk)
{
    __shared__ int cur[NBUCK];
    int i = blockIdx.x, t = threadIdx.x;
    cur[t] = offs[i * NBUCK + t];
    __syncthreads();
    int e0 = i * chunk, e1 = min(e0 + chunk, Ep);
    for (int e = e0 + t; e < e1; e += 256) {
        int src, dst;
        if (e < E) { src = ei[e]; dst = ei[E + e]; } else { src = dst = e - E; }
        int pos = atomicAdd(&cur[dst >> BSH], 1);
        pairs[pos] = ((unsigned)(dst & 511) << 17) | (unsigned)src;
    }
}

// Pass D: one block per bucket -- local degree count, LDS scan, write rowStart/deg,
// then LDS-cursor scatter of src into the bucket's contiguous srcS region.
__global__ __launch_bounds__(256) void bucket_build(
    const unsigned* __restrict__ pairs, const int* __restrict__ bucketBase,
    int* __restrict__ rowStart, int* __restrict__ deg, int* __restrict__ srcS, int N)
{
    __shared__ int ucnt[512], ustart[512], sh[256];
    __shared__ unsigned stage[DCAP];
    int b = blockIdx.x, t = threadIdx.x;
    int node0 = b << BSH;
    if (node0 >= N) return;
    int s0 = bucketBase[b], s1 = bucketBase[b + 1];
    int cnt = s1 - s0;
    ucnt[t] = 0; ucnt[t + 256] = 0;
    __syncthreads();
    bool fit = (cnt <= DCAP);
    for (int k = t; k < cnt; k += 256) {
        unsigned v = pairs[s0 + k];
        if (fit) stage[k] = v;
        atomicAdd(&ucnt[v >> 17], 1);
    }
    __syncthreads();
    // exclusive scan of ucnt[512] with 256 threads (2 elems/thread)
    int a0 = ucnt[2 * t], a1 = ucnt[2 * t + 1];
    int s2 = a0 + a1;
    sh[t] = s2;
    __syncthreads();
    for (int off = 1; off < 256; off <<= 1) {
        int u = (t >= off) ? sh[t - off] : 0;
        __syncthreads();
        sh[t] += u;
        __syncthreads();
    }
    int exc = sh[t] - s2;
    ustart[2 * t] = exc;
    ustart[2 * t + 1] = exc + a0;
    __syncthreads();
    for (int l = t; l < 512; l += 256) {
        int node = node0 + l;
        if (node < N) { rowStart[node] = s0 + ustart[l]; deg[node] = ucnt[l]; }
    }
    __syncthreads();   // rowStart writes (reading ustart) done before cursors mutate
    for (int k = t; k < cnt; k += 256) {
        unsigned v = fit ? stage[k] : pairs[s0 + k];
        int pos = atomicAdd(&ustart[v >> 17], 1);
        srcS[s0 + pos] = (int)(v & 131071u);
    }
}

// ============================ Fused softmax+aggregate, layer 1 ============================
__global__ __launch_bounds__(256) void fused_aggr1(
    const int* __restrict__ rowStart, const int* __restrict__ deg, const int* __restrict__ srcS,
    const float* __restrict__ a1s, const float* __restrict__ a1d,
    const f16* __restrict__ h1h, float* __restrict__ out1, int N)
{
    int lane = threadIdx.x & 63;
    int dst = blockIdx.x * 4 + (threadIdx.x >> 6);
    if (dst >= N) return;
    int base = rowStart[dst];
    int d = deg[dst];
    float ad0 = a1d[2 * dst], ad1 = a1d[2 * dst + 1];
    int tx = lane & 15, j2 = lane >> 4;
    float acc[8] = {};
    float dpart0 = 0.f, dpart1 = 0.f;

    for (int c0 = 0; c0 < d; c0 += 64) {
        int cn = min(64, d - c0);
        int s = 0; float p0 = 0.f, p1 = 0.f;
        if (lane < cn) {
            s = srcS[base + c0 + lane];
            float2 av = *(const float2*)&a1s[2 * s];
            float e0 = av.x + ad0, e1 = av.y + ad1;
            e0 = e0 > 0.f ? e0 : NEG_SLOPE * e0;
            e1 = e1 > 0.f ? e1 : NEG_SLOPE * e1;
            p0 = __expf(e0); p1 = __expf(e1);
        }
        dpart0 += p0; dpart1 += p1;
        int niter = (cn + 3) >> 2;
        #pragma unroll 4
        for (int jj = 0; jj < niter; ++jj) {
            int esub = jj * 4 + j2;                 // p==0 for esub >= cn
            int   sj = __shfl(s, esub);
            float q0 = __shfl(p0, esub);
            float q1 = __shfl(p1, esub);
            float q  = (tx < 8) ? q0 : q1;
            half8 v = *(const half8*)&h1h[(size_t)sj * 128 + tx * 8];
            #pragma unroll
            for (int k = 0; k < 8; ++k) acc[k] += q * (float)v[k];
        }
    }
    #pragma unroll
    for (int k = 0; k < 8; ++k) acc[k] += __shfl_xor(acc[k], 16);
    #pragma unroll
    for (int k = 0; k < 8; ++k) acc[k] += __shfl_xor(acc[k], 32);
    #pragma unroll
    for (int o = 32; o; o >>= 1) { dpart0 += __shfl_xor(dpart0, o); dpart1 += __shfl_xor(dpart1, o); }
    if (j2 == 0) {
        float iv = (tx < 8) ? (1.f / dpart0) : (1.f / dpart1);
        float4 lo = {acc[0] * iv, acc[1] * iv, acc[2] * iv, acc[3] * iv};
        float4 hi = {acc[4] * iv, acc[5] * iv, acc[6] * iv, acc[7] * iv};
        *(float4*)&out1[(size_t)dst * 128 + tx * 8] = lo;
        *(float4*)&out1[(size_t)dst * 128 + tx * 8 + 4] = hi;
    }
}

// ============================ GEMM 2 ============================
__global__ __launch_bounds__(256) void gemm2_kernel(
    const float* __restrict__ out1, const float* __restrict__ b1,
    const float* __restrict__ W2,
    const float* __restrict__ a2s_vec, const float* __restrict__ a2d_vec,
    f16* __restrict__ h2h, float* __restrict__ a2s, float* __restrict__ a2d, int N)
{
    __shared__ float wsh[128 * 64];       // [k][c] == W2 layout
    __shared__ float xsh[64 * 132];       // [r][k]
    int t = threadIdx.x;
    int row0 = blockIdx.x << 6;

    #pragma unroll
    for (int c = 0; c < 8; ++c) {          // W2: straight copy
        int l = c * 256 + t;
        *(float4*)&wsh[l * 4] = *(const float4*)&W2[l * 4];
    }
    #pragma unroll
    for (int c = 0; c < 8; ++c) {          // X tile = relu(out1 + b1)
        int l = c * 256 + t;
        int r = l >> 5, f = l & 31;
        int rr = row0 + r;
        float4 v = {0.f, 0.f, 0.f, 0.f};
        if (rr < N) {
            v = *(const float4*)&out1[(size_t)rr * 128 + f * 4];
            float4 bv = *(const float4*)&b1[f * 4];
            v.x = fmaxf(v.x + bv.x, 0.f);
            v.y = fmaxf(v.y + bv.y, 0.f);
            v.z = fmaxf(v.z + bv.z, 0.f);
            v.w = fmaxf(v.w + bv.w, 0.f);
        }
        *(float4*)&xsh[r * 132 + f * 4] = v;
    }
    __syncthreads();

    int tx = t & 15, ty = t >> 4;
    float acc[4][4] = {};
    const float* xb = &xsh[(ty * 4) * 132];
    #pragma unroll 8
    for (int k = 0; k < 128; ++k) {
        float4 wv = *(const float4*)&wsh[k * 64 + tx * 4];
        float x0 = xb[k], x1 = xb[132 + k], x2 = xb[264 + k], x3 = xb[396 + k];
        acc[0][0] += x0 * wv.x; acc[0][1] += x0 * wv.y; acc[0][2] += x0 * wv.z; acc[0][3] += x0 * wv.w;
        acc[1][0] += x1 * wv.x; acc[1][1] += x1 * wv.y; acc[1][2] += x1 * wv.z; acc[1][3] += x1 * wv.w;
        acc[2][0] += x2 * wv.x; acc[2][1] += x2 * wv.y; acc[2][2] += x2 * wv.z; acc[2][3] += x2 * wv.w;
        acc[3][0] += x3 * wv.x; acc[3][1] += x3 * wv.y; acc[3][2] += x3 * wv.z; acc[3][3] += x3 * wv.w;
    }

    float avs[4], avd[4];
    #pragma unroll
    for (int c = 0; c < 4; ++c) {
        avs[c] = a2s_vec[tx * 4 + c];
        avd[c] = a2d_vec[tx * 4 + c];
    }
    #pragma unroll
    for (int r = 0; r < 4; ++r) {
        int rr = row0 + ty * 4 + r;
        float ps = acc[r][0] * avs[0] + acc[r][1] * avs[1] + acc[r][2] * avs[2] + acc[r][3] * avs[3];
        float pd = acc[r][0] * avd[0] + acc[r][1] * avd[1] + acc[r][2] * avd[2] + acc[r][3] * avd[3];
        #pragma unroll
        for (int o = 8; o; o >>= 1) { ps += __shfl_xor(ps, o); pd += __shfl_xor(pd, o); }
        if (rr < N) {
            half4 o4 = {(f16)acc[r][0], (f16)acc[r][1], (f16)acc[r][2], (f16)acc[r][3]};
            *(half4*)&h2h[(size_t)rr * 64 + tx * 4] = o4;
            if (tx == 0) { a2s[rr] = ps; a2d[rr] = pd; }
        }
    }
}

// ============================ Fused softmax+aggregate, layer 2 ============================
__global__ __launch_bounds__(256) void fused_aggr2(
    const int* __restrict__ rowStart, const int* __restrict__ deg, const int* __restrict__ srcS,
    const float* __restrict__ a2s, const float* __restrict__ a2d,
    const f16* __restrict__ h2h, float* __restrict__ out2, int N)
{
    int lane = threadIdx.x & 63;
    int dst = blockIdx.x * 4 + (threadIdx.x >> 6);
    if (dst >= N) return;
    int base = rowStart[dst];
    int d = deg[dst];
    float ad = a2d[dst];
    int tx = lane & 7, j3 = lane >> 3;
    float acc[8] = {};
    float dpart = 0.f;

    for (int c0 = 0; c0 < d; c0 += 64) {
        int cn = min(64, d - c0);
        int s = 0; float p = 0.f;
        if (lane < cn) {
            s = srcS[base + c0 + lane];
            float e = a2s[s] + ad;
            e = e > 0.f ? e : NEG_SLOPE * e;
            p = __expf(e);
        }
        dpart += p;
        int niter = (cn + 7) >> 3;
        #pragma unroll 4
        for (int jj = 0; jj < niter; ++jj) {
            int esub = jj * 8 + j3;
            int   sj = __shfl(s, esub);
            float q  = __shfl(p, esub);
            half8 v = *(const half8*)&h2h[(size_t)sj * 64 + tx * 8];
            #pragma unroll
            for (int k = 0; k < 8; ++k) acc[k] += q * (float)v[k];
        }
    }
    #pragma unroll
    for (int k = 0; k < 8; ++k) acc[k] += __shfl_xor(acc[k], 8);
    #pragma unroll
    for (int k = 0; k < 8; ++k) acc[k] += __shfl_xor(acc[k], 16);
    #pragma unroll
    for (int k = 0; k < 8; ++k) acc[k] += __shfl_xor(acc[k], 32);
    #pragma unroll
    for (int o = 32; o; o >>= 1) dpart += __shfl_xor(dpart, o);
    if (j3 == 0) {
        float iv = 1.f / dpart;
        float4 lo = {acc[0] * iv, acc[1] * iv, acc[2] * iv, acc[3] * iv};
        float4 hi = {acc[4] * iv, acc[5] * iv, acc[6] * iv, acc[7] * iv};
        *(float4*)&out2[(size_t)dst * 64 + tx * 8] = lo;
        *(float4*)&out2[(size_t)dst * 64 + tx * 8 + 4] = hi;
    }
}

// ============================ Pool ============================
__global__ __launch_bounds__(256) void pool_kernel(
    const float* __restrict__ out2, const float* __restrict__ b2,
    const int* __restrict__ batch, float* __restrict__ pool, float* __restrict__ cnt, int N)
{
    int lane = threadIdx.x & 63;
    int gwave = blockIdx.x * 4 + (threadIdx.x >> 6);
    int nwaves = gridDim.x * 4;
    int per = (N + nwaves - 1) / nwaves;
    int n0 = gwave * per;
    int n1 = min(n0 + per, N);
    if (n0 >= n1) return;
    float bb = b2[lane];
    float acc = 0.f;
    int count = 0;
    int gcur = batch[n0];
    for (int n = n0; n < n1; ++n) {
        int g = batch[n];
        if (g != gcur) {
            atomicAdd(&pool[gcur * 64 + lane], acc);
            if (lane == 0) atomicAdd(&cnt[gcur], (float)count);
            acc = 0.f; count = 0; gcur = g;
        }
        float v = out2[(size_t)n * 64 + lane] + bb;
        acc += v > 0.f ? v : 0.f;
        ++count;
    }
    atomicAdd(&pool[gcur * 64 + lane], acc);
    if (lane == 0) atomicAdd(&cnt[gcur], (float)count);
}

// ============================ Final linear ============================
__global__ void final_kernel(
    const float* __restrict__ pool, const float* __restrict__ cnt,
    const float* __restrict__ Wlin, const float* __restrict__ blin,
    float* __restrict__ out, int G)
{
    int g = threadIdx.x;
    if (g >= G) return;
    float s = 0.f;
    #pragma unroll 8
    for (int c = 0; c < 64; ++c) s += pool[g * 64 + c] * Wlin[c];
    float cn = cnt[g]; cn = cn > 1.f ? cn : 1.f;
    out[g] = s / cn + blin[0];
}

extern "C" void kernel_launch(void* const* d_in, const int* in_sizes, int n_in,
                              void* d_out, int out_size, void* d_ws, size_t ws_size,
                              hipStream_t stream) {
    const float* x     = (const float*)d_in[0];
    const int*   ei    = (const int*)d_in[1];
    const int*   batch = (const int*)d_in[2];
    const float* W1    = (const float*)d_in[3];
    const float* a1sv  = (const float*)d_in[4];
    const float* a1dv  = (const float*)d_in[5];
    const float* b1    = (const float*)d_in[6];
    const float* W2    = (const float*)d_in[7];
    const float* a2sv  = (const float*)d_in[8];
    const float* a2dv  = (const float*)d_in[9];
    const float* b2    = (const float*)d_in[10];
    const float* Wlin  = (const float*)d_in[11];
    const float* blin  = (const float*)d_in[12];

    int N  = in_sizes[2];
    int E  = in_sizes[1] / 2;
    int Ep = E + N;
    const int G = 64;
    int chunk = (Ep + NB1 - 1) / NB1;

    float* ws = (float*)d_ws;
    size_t off = 0;
    float* out1 = ws + off; off += (size_t)N * 128;
    f16*  h1h   = (f16*)(ws + off); off += (size_t)N * 64;   // N*128 halves
    f16*  h2h   = (f16*)(ws + off); off += (size_t)N * 32;   // N*64 halves
    float* a1s  = ws + off; off += (size_t)N * 2;
    float* a1d  = ws + off; off += (size_t)N * 2;
    float* a2s  = ws + off; off += N;
    float* a2d  = ws + off; off += N;
    int* degA   = (int*)(ws + off); off += N;
    int* rowStart = (int*)(ws + off); off += N;
    int* cntg   = (int*)(ws + off); off += NB1 * NBUCK;
    int* offs   = (int*)(ws + off); off += NB1 * NBUCK;
    int* bucketBase = (int*)(ws + off); off += 257;
    unsigned* pairs = (unsigned*)(ws + off); off += Ep;
    int* srcS   = (int*)(ws + off); off += Ep;
    float* pool = ws + off; off += G * 64;
    float* cnt  = ws + off; off += G;
    float* out2 = (float*)h1h;   // alias: h1h (N*128 halves == N*64 floats) dead after fused_aggr1

    hipMemsetAsync(pool, 0, (size_t)(G * 64 + G) * sizeof(float), stream);

    // CSR build: deterministic two-level bucket sort (no global atomics)
    bucket_count<<<NB1, 256, 0, stream>>>(ei, cntg, E, Ep, chunk);
    bucket_scan<<<1, 256, 0, stream>>>(cntg, offs, bucketBase, NB1);
    bucket_place<<<NB1, 256, 0, stream>>>(ei, offs, pairs, E, Ep, chunk);
    bucket_build<<<NBUCK, 256, 0, stream>>>(pairs, bucketBase, rowStart, degA, srcS, N);

    dim3 g1((N + 63) / 64, 2);
    gemm1_kernel<<<g1, 256, 0, stream>>>(x, W1, a1sv, a1dv, h1h, a1s, a1d, N);
    fused_aggr1<<<(N + 3) / 4, 256, 0, stream>>>(rowStart, degA, srcS, a1s, a1d, h1h, out1, N);
    gemm2_kernel<<<(N + 63) / 64, 256, 0, stream>>>(out1, b1, W2, a2sv, a2dv, h2h, a2s, a2d, N);
    fused_aggr2<<<(N + 3) / 4, 256, 0, stream>>>(rowStart, degA, srcS, a2s, a2d, h2h, out2, N);
    pool_kernel<<<256, 256, 0, stream>>>(out2, b2, batch, pool, cnt, N);
    final_kernel<<<1, 64, 0, stream>>>(pool, cnt, Wlin, blin, (float*)d_out, G);
}

// Round 9
// 324.825 us; speedup vs baseline: 7.7708x; 1.2766x over previous
//
#include <hip/hip_runtime.h>
#include <hip/hip_fp16.h>

#define NEG_SLOPE 0.2f
#define BSH 9                    // bucket = dst >> 9  (512 nodes / bucket)
#define NBUCK 256                // covers dst < 131072
#define NB1 256                  // pass A/C blocks
#define DCAP 12288               // pass D LDS staging capacity (uints)

typedef _Float16 f16;
typedef __attribute__((ext_vector_type(8))) _Float16 half8;
typedef __attribute__((ext_vector_type(4))) _Float16 half4;

// ============================ GEMM 1 ============================
__global__ __launch_bounds__(256) void gemm1_kernel(
    const float* __restrict__ x, const float* __restrict__ W1,
    const float* __restrict__ a1s_vec, const float* __restrict__ a1d_vec,
    f16* __restrict__ h1h, float* __restrict__ a1s, float* __restrict__ a1d, int N)
{
    __shared__ float wsh[128 * 64];       // [k][c]
    __shared__ float xsh[64 * 132];       // [r][k], pad 128->132
    int t = threadIdx.x;
    int head = blockIdx.y;
    int coloff = head << 6;
    int row0 = blockIdx.x << 6;

    #pragma unroll
    for (int c = 0; c < 8; ++c) {          // W tile: 128x64
        int l = c * 256 + t;
        int k = l >> 4, f = l & 15;
        *(float4*)&wsh[k * 64 + f * 4] = *(const float4*)&W1[k * 128 + coloff + f * 4];
    }
    #pragma unroll
    for (int c = 0; c < 8; ++c) {          // X tile: 64x128
        int l = c * 256 + t;
        int r = l >> 5, f = l & 31;
        int rr = row0 + r;
        float4 v = {0.f, 0.f, 0.f, 0.f};
        if (rr < N) v = *(const float4*)&x[(size_t)rr * 128 + f * 4];
        *(float4*)&xsh[r * 132 + f * 4] = v;
    }
    __syncthreads();

    int tx = t & 15, ty = t >> 4;
    float acc[4][4] = {};
    const float* xb = &xsh[(ty * 4) * 132];
    #pragma unroll 8
    for (int k = 0; k < 128; ++k) {
        float4 wv = *(const float4*)&wsh[k * 64 + tx * 4];
        float x0 = xb[k], x1 = xb[132 + k], x2 = xb[264 + k], x3 = xb[396 + k];
        acc[0][0] += x0 * wv.x; acc[0][1] += x0 * wv.y; acc[0][2] += x0 * wv.z; acc[0][3] += x0 * wv.w;
        acc[1][0] += x1 * wv.x; acc[1][1] += x1 * wv.y; acc[1][2] += x1 * wv.z; acc[1][3] += x1 * wv.w;
        acc[2][0] += x2 * wv.x; acc[2][1] += x2 * wv.y; acc[2][2] += x2 * wv.z; acc[2][3] += x2 * wv.w;
        acc[3][0] += x3 * wv.x; acc[3][1] += x3 * wv.y; acc[3][2] += x3 * wv.z; acc[3][3] += x3 * wv.w;
    }

    float avs[4], avd[4];
    #pragma unroll
    for (int c = 0; c < 4; ++c) {
        avs[c] = a1s_vec[coloff + tx * 4 + c];
        avd[c] = a1d_vec[coloff + tx * 4 + c];
    }
    #pragma unroll
    for (int r = 0; r < 4; ++r) {
        int rr = row0 + ty * 4 + r;
        float ps = acc[r][0] * avs[0] + acc[r][1] * avs[1] + acc[r][2] * avs[2] + acc[r][3] * avs[3];
        float pd = acc[r][0] * avd[0] + acc[r][1] * avd[1] + acc[r][2] * avd[2] + acc[r][3] * avd[3];
        #pragma unroll
        for (int o = 8; o; o >>= 1) { ps += __shfl_xor(ps, o); pd += __shfl_xor(pd, o); }
        if (rr < N) {
            half4 o4 = {(f16)acc[r][0], (f16)acc[r][1], (f16)acc[r][2], (f16)acc[r][3]};
            *(half4*)&h1h[(size_t)rr * 128 + coloff + tx * 4] = o4;
            if (tx == 0) { a1s[rr * 2 + head] = ps; a1d[rr * 2 + head] = pd; }
        }
    }
}

// ============================ CSR build: two-level bucket sort ============================
// Pass A: per-block LDS histogram over 256 coarse buckets (dst>>9).
__global__ __launch_bounds__(256) void bucket_count(
    const int* __restrict__ ei, int* __restrict__ cntg, int E, int Ep, int chunk)
{
    __shared__ int lc[NBUCK];
    int i = blockIdx.x, t = threadIdx.x;
    lc[t] = 0;
    __syncthreads();
    int e0 = i * chunk, e1 = min(e0 + chunk, Ep);
    for (int e = e0 + t; e < e1; e += 256) {
        int dst = (e < E) ? ei[E + e] : e - E;
        atomicAdd(&lc[dst >> BSH], 1);
    }
    __syncthreads();
    cntg[i * NBUCK + t] = lc[t];
}

// Pass B1: per-bucket scan over chunk-blocks. Block b, thread i: LDS scan of
// cntg[:,b] -> offs[i][b] (exclusive, no base) and tot[b].
__global__ __launch_bounds__(256) void bucket_scan_t(
    const int* __restrict__ cntg, int* __restrict__ offs, int* __restrict__ tot)
{
    __shared__ int sh[256];
    int b = blockIdx.x, i = threadIdx.x;
    int v = cntg[i * NBUCK + b];
    sh[i] = v;
    __syncthreads();
    for (int off = 1; off < 256; off <<= 1) {
        int u = (i >= off) ? sh[i - off] : 0;
        __syncthreads();
        sh[i] += u;
        __syncthreads();
    }
    offs[i * NBUCK + b] = sh[i] - v;       // exclusive over chunk-blocks
    if (i == 255) tot[b] = sh[255];
}

// Pass B2: tiny scan of tot[256] -> bucketBase[257].
__global__ __launch_bounds__(256) void bucket_base(
    const int* __restrict__ tot, int* __restrict__ bucketBase)
{
    __shared__ int sh[256];
    int b = threadIdx.x;
    int v = tot[b];
    sh[b] = v;
    __syncthreads();
    for (int off = 1; off < 256; off <<= 1) {
        int u = (b >= off) ? sh[b - off] : 0;
        __syncthreads();
        sh[b] += u;
        __syncthreads();
    }
    bucketBase[b] = sh[b] - v;
    if (b == 255) bucketBase[256] = sh[255];
}

// Pass C: place packed (dstLocal<<17 | src) via LDS cursors (no global atomics).
__global__ __launch_bounds__(256) void bucket_place(
    const int* __restrict__ ei, const int* __restrict__ offs, const int* __restrict__ bucketBase,
    unsigned* __restrict__ pairs, int E, int Ep, int chunk)
{
    __shared__ int cur[NBUCK];
    int i = blockIdx.x, t = threadIdx.x;
    cur[t] = offs[i * NBUCK + t] + bucketBase[t];
    __syncthreads();
    int e0 = i * chunk, e1 = min(e0 + chunk, Ep);
    for (int e = e0 + t; e < e1; e += 256) {
        int src, dst;
        if (e < E) { src = ei[e]; dst = ei[E + e]; } else { src = dst = e - E; }
        int pos = atomicAdd(&cur[dst >> BSH], 1);
        pairs[pos] = ((unsigned)(dst & 511) << 17) | (unsigned)src;
    }
}

// Pass D: one block per bucket -- local degree count, LDS scan, write rowStart/deg,
// then LDS-cursor scatter of src into the bucket's contiguous srcS region.
__global__ __launch_bounds__(256) void bucket_build(
    const unsigned* __restrict__ pairs, const int* __restrict__ bucketBase,
    int* __restrict__ rowStart, int* __restrict__ deg, int* __restrict__ srcS, int N)
{
    __shared__ int ucnt[512], ustart[512], sh[256];
    __shared__ unsigned stage[DCAP];
    int b = blockIdx.x, t = threadIdx.x;
    int node0 = b << BSH;
    if (node0 >= N) return;
    int s0 = bucketBase[b], s1 = bucketBase[b + 1];
    int cnt = s1 - s0;
    ucnt[t] = 0; ucnt[t + 256] = 0;
    __syncthreads();
    bool fit = (cnt <= DCAP);
    for (int k = t; k < cnt; k += 256) {
        unsigned v = pairs[s0 + k];
        if (fit) stage[k] = v;
        atomicAdd(&ucnt[v >> 17], 1);
    }
    __syncthreads();
    // exclusive scan of ucnt[512] with 256 threads (2 elems/thread)
    int a0 = ucnt[2 * t], a1 = ucnt[2 * t + 1];
    int s2 = a0 + a1;
    sh[t] = s2;
    __syncthreads();
    for (int off = 1; off < 256; off <<= 1) {
        int u = (t >= off) ? sh[t - off] : 0;
        __syncthreads();
        sh[t] += u;
        __syncthreads();
    }
    int exc = sh[t] - s2;
    ustart[2 * t] = exc;
    ustart[2 * t + 1] = exc + a0;
    __syncthreads();
    for (int l = t; l < 512; l += 256) {
        int node = node0 + l;
        if (node < N) { rowStart[node] = s0 + ustart[l]; deg[node] = ucnt[l]; }
    }
    __syncthreads();   // rowStart writes (reading ustart) done before cursors mutate
    for (int k = t; k < cnt; k += 256) {
        unsigned v = fit ? stage[k] : pairs[s0 + k];
        int pos = atomicAdd(&ustart[v >> 17], 1);
        srcS[s0 + pos] = (int)(v & 131071u);
    }
}

// ============================ Fused softmax+aggregate, layer 1 ============================
__global__ __launch_bounds__(256) void fused_aggr1(
    const int* __restrict__ rowStart, const int* __restrict__ deg, const int* __restrict__ srcS,
    const float* __restrict__ a1s, const float* __restrict__ a1d,
    const f16* __restrict__ h1h, float* __restrict__ out1, int N)
{
    int lane = threadIdx.x & 63;
    int dst = blockIdx.x * 4 + (threadIdx.x >> 6);
    if (dst >= N) return;
    int base = rowStart[dst];
    int d = deg[dst];
    float ad0 = a1d[2 * dst], ad1 = a1d[2 * dst + 1];
    int tx = lane & 15, j2 = lane >> 4;
    float acc[8] = {};
    float dpart0 = 0.f, dpart1 = 0.f;

    for (int c0 = 0; c0 < d; c0 += 64) {
        int cn = min(64, d - c0);
        int s = 0; float p0 = 0.f, p1 = 0.f;
        if (lane < cn) {
            s = srcS[base + c0 + lane];
            float2 av = *(const float2*)&a1s[2 * s];
            float e0 = av.x + ad0, e1 = av.y + ad1;
            e0 = e0 > 0.f ? e0 : NEG_SLOPE * e0;
            e1 = e1 > 0.f ? e1 : NEG_SLOPE * e1;
            p0 = __expf(e0); p1 = __expf(e1);
        }
        dpart0 += p0; dpart1 += p1;
        int niter = (cn + 3) >> 2;
        #pragma unroll 4
        for (int jj = 0; jj < niter; ++jj) {
            int esub = jj * 4 + j2;                 // p==0 for esub >= cn
            int   sj = __shfl(s, esub);
            float q0 = __shfl(p0, esub);
            float q1 = __shfl(p1, esub);
            float q  = (tx < 8) ? q0 : q1;
            half8 v = *(const half8*)&h1h[(size_t)sj * 128 + tx * 8];
            #pragma unroll
            for (int k = 0; k < 8; ++k) acc[k] += q * (float)v[k];
        }
    }
    #pragma unroll
    for (int k = 0; k < 8; ++k) acc[k] += __shfl_xor(acc[k], 16);
    #pragma unroll
    for (int k = 0; k < 8; ++k) acc[k] += __shfl_xor(acc[k], 32);
    #pragma unroll
    for (int o = 32; o; o >>= 1) { dpart0 += __shfl_xor(dpart0, o); dpart1 += __shfl_xor(dpart1, o); }
    if (j2 == 0) {
        float iv = (tx < 8) ? (1.f / dpart0) : (1.f / dpart1);
        float4 lo = {acc[0] * iv, acc[1] * iv, acc[2] * iv, acc[3] * iv};
        float4 hi = {acc[4] * iv, acc[5] * iv, acc[6] * iv, acc[7] * iv};
        *(float4*)&out1[(size_t)dst * 128 + tx * 8] = lo;
        *(float4*)&out1[(size_t)dst * 128 + tx * 8 + 4] = hi;
    }
}

// ============================ GEMM 2 ============================
__global__ __launch_bounds__(256) void gemm2_kernel(
    const float* __restrict__ out1, const float* __restrict__ b1,
    const float* __restrict__ W2,
    const float* __restrict__ a2s_vec, const float* __restrict__ a2d_vec,
    f16* __restrict__ h2h, float* __restrict__ a2s, float* __restrict__ a2d, int N)
{
    __shared__ float wsh[128 * 64];       // [k][c] == W2 layout
    __shared__ float xsh[64 * 132];       // [r][k]
    int t = threadIdx.x;
    int row0 = blockIdx.x << 6;

    #pragma unroll
    for (int c = 0; c < 8; ++c) {          // W2: straight copy
        int l = c * 256 + t;
        *(float4*)&wsh[l * 4] = *(const float4*)&W2[l * 4];
    }
    #pragma unroll
    for (int c = 0; c < 8; ++c) {          // X tile = relu(out1 + b1)
        int l = c * 256 + t;
        int r = l >> 5, f = l & 31;
        int rr = row0 + r;
        float4 v = {0.f, 0.f, 0.f, 0.f};
        if (rr < N) {
            v = *(const float4*)&out1[(size_t)rr * 128 + f * 4];
            float4 bv = *(const float4*)&b1[f * 4];
            v.x = fmaxf(v.x + bv.x, 0.f);
            v.y = fmaxf(v.y + bv.y, 0.f);
            v.z = fmaxf(v.z + bv.z, 0.f);
            v.w = fmaxf(v.w + bv.w, 0.f);
        }
        *(float4*)&xsh[r * 132 + f * 4] = v;
    }
    __syncthreads();

    int tx = t & 15, ty = t >> 4;
    float acc[4][4] = {};
    const float* xb = &xsh[(ty * 4) * 132];
    #pragma unroll 8
    for (int k = 0; k < 128; ++k) {
        float4 wv = *(const float4*)&wsh[k * 64 + tx * 4];
        float x0 = xb[k], x1 = xb[132 + k], x2 = xb[264 + k], x3 = xb[396 + k];
        acc[0][0] += x0 * wv.x; acc[0][1] += x0 * wv.y; acc[0][2] += x0 * wv.z; acc[0][3] += x0 * wv.w;
        acc[1][0] += x1 * wv.x; acc[1][1] += x1 * wv.y; acc[1][2] += x1 * wv.z; acc[1][3] += x1 * wv.w;
        acc[2][0] += x2 * wv.x; acc[2][1] += x2 * wv.y; acc[2][2] += x2 * wv.z; acc[2][3] += x2 * wv.w;
        acc[3][0] += x3 * wv.x; acc[3][1] += x3 * wv.y; acc[3][2] += x3 * wv.z; acc[3][3] += x3 * wv.w;
    }

    float avs[4], avd[4];
    #pragma unroll
    for (int c = 0; c < 4; ++c) {
        avs[c] = a2s_vec[tx * 4 + c];
        avd[c] = a2d_vec[tx * 4 + c];
    }
    #pragma unroll
    for (int r = 0; r < 4; ++r) {
        int rr = row0 + ty * 4 + r;
        float ps = acc[r][0] * avs[0] + acc[r][1] * avs[1] + acc[r][2] * avs[2] + acc[r][3] * avs[3];
        float pd = acc[r][0] * avd[0] + acc[r][1] * avd[1] + acc[r][2] * avd[2] + acc[r][3] * avd[3];
        #pragma unroll
        for (int o = 8; o; o >>= 1) { ps += __shfl_xor(ps, o); pd += __shfl_xor(pd, o); }
        if (rr < N) {
            half4 o4 = {(f16)acc[r][0], (f16)acc[r][1], (f16)acc[r][2], (f16)acc[r][3]};
            *(half4*)&h2h[(size_t)rr * 64 + tx * 4] = o4;
            if (tx == 0) { a2s[rr] = ps; a2d[rr] = pd; }
        }
    }
}

// ============================ Fused softmax+aggregate, layer 2 ============================
__global__ __launch_bounds__(256) void fused_aggr2(
    const int* __restrict__ rowStart, const int* __restrict__ deg, const int* __restrict__ srcS,
    const float* __restrict__ a2s, const float* __restrict__ a2d,
    const f16* __restrict__ h2h, float* __restrict__ out2, int N)
{
    int lane = threadIdx.x & 63;
    int dst = blockIdx.x * 4 + (threadIdx.x >> 6);
    if (dst >= N) return;
    int base = rowStart[dst];
    int d = deg[dst];
    float ad = a2d[dst];
    int tx = lane & 7, j3 = lane >> 3;
    float acc[8] = {};
    float dpart = 0.f;

    for (int c0 = 0; c0 < d; c0 += 64) {
        int cn = min(64, d - c0);
        int s = 0; float p = 0.f;
        if (lane < cn) {
            s = srcS[base + c0 + lane];
            float e = a2s[s] + ad;
            e = e > 0.f ? e : NEG_SLOPE * e;
            p = __expf(e);
        }
        dpart += p;
        int niter = (cn + 7) >> 3;
        #pragma unroll 4
        for (int jj = 0; jj < niter; ++jj) {
            int esub = jj * 8 + j3;
            int   sj = __shfl(s, esub);
            float q  = __shfl(p, esub);
            half8 v = *(const half8*)&h2h[(size_t)sj * 64 + tx * 8];
            #pragma unroll
            for (int k = 0; k < 8; ++k) acc[k] += q * (float)v[k];
        }
    }
    #pragma unroll
    for (int k = 0; k < 8; ++k) acc[k] += __shfl_xor(acc[k], 8);
    #pragma unroll
    for (int k = 0; k < 8; ++k) acc[k] += __shfl_xor(acc[k], 16);
    #pragma unroll
    for (int k = 0; k < 8; ++k) acc[k] += __shfl_xor(acc[k], 32);
    #pragma unroll
    for (int o = 32; o; o >>= 1) dpart += __shfl_xor(dpart, o);
    if (j3 == 0) {
        float iv = 1.f / dpart;
        float4 lo = {acc[0] * iv, acc[1] * iv, acc[2] * iv, acc[3] * iv};
        float4 hi = {acc[4] * iv, acc[5] * iv, acc[6] * iv, acc[7] * iv};
        *(float4*)&out2[(size_t)dst * 64 + tx * 8] = lo;
        *(float4*)&out2[(size_t)dst * 64 + tx * 8 + 4] = hi;
    }
}

// ============================ Pool ============================
__global__ __launch_bounds__(256) void pool_kernel(
    const float* __restrict__ out2, const float* __restrict__ b2,
    const int* __restrict__ batch, float* __restrict__ pool, float* __restrict__ cnt, int N)
{
    int lane = threadIdx.x & 63;
    int gwave = blockIdx.x * 4 + (threadIdx.x >> 6);
    int nwaves = gridDim.x * 4;
    int per = (N + nwaves - 1) / nwaves;
    int n0 = gwave * per;
    int n1 = min(n0 + per, N);
    if (n0 >= n1) return;
    float bb = b2[lane];
    float acc = 0.f;
    int count = 0;
    int gcur = batch[n0];
    for (int n = n0; n < n1; ++n) {
        int g = batch[n];
        if (g != gcur) {
            atomicAdd(&pool[gcur * 64 + lane], acc);
            if (lane == 0) atomicAdd(&cnt[gcur], (float)count);
            acc = 0.f; count = 0; gcur = g;
        }
        float v = out2[(size_t)n * 64 + lane] + bb;
        acc += v > 0.f ? v : 0.f;
        ++count;
    }
    atomicAdd(&pool[gcur * 64 + lane], acc);
    if (lane == 0) atomicAdd(&cnt[gcur], (float)count);
}

// ============================ Final linear ============================
__global__ void final_kernel(
    const float* __restrict__ pool, const float* __restrict__ cnt,
    const float* __restrict__ Wlin, const float* __restrict__ blin,
    float* __restrict__ out, int G)
{
    int g = threadIdx.x;
    if (g >= G) return;
    float s = 0.f;
    #pragma unroll 8
    for (int c = 0; c < 64; ++c) s += pool[g * 64 + c] * Wlin[c];
    float cn = cnt[g]; cn = cn > 1.f ? cn : 1.f;
    out[g] = s / cn + blin[0];
}

extern "C" void kernel_launch(void* const* d_in, const int* in_sizes, int n_in,
                              void* d_out, int out_size, void* d_ws, size_t ws_size,
                              hipStream_t stream) {
    const float* x     = (const float*)d_in[0];
    const int*   ei    = (const int*)d_in[1];
    const int*   batch = (const int*)d_in[2];
    const float* W1    = (const float*)d_in[3];
    const float* a1sv  = (const float*)d_in[4];
    const float* a1dv  = (const float*)d_in[5];
    const float* b1    = (const float*)d_in[6];
    const float* W2    = (const float*)d_in[7];
    const float* a2sv  = (const float*)d_in[8];
    const float* a2dv  = (const float*)d_in[9];
    const float* b2    = (const float*)d_in[10];
    const float* Wlin  = (const float*)d_in[11];
    const float* blin  = (const float*)d_in[12];

    int N  = in_sizes[2];
    int E  = in_sizes[1] / 2;
    int Ep = E + N;
    const int G = 64;
    int chunk = (Ep + NB1 - 1) / NB1;

    float* ws = (float*)d_ws;
    size_t off = 0;
    float* out1 = ws + off; off += (size_t)N * 128;
    f16*  h1h   = (f16*)(ws + off); off += (size_t)N * 64;   // N*128 halves
    f16*  h2h   = (f16*)(ws + off); off += (size_t)N * 32;   // N*64 halves
    float* a1s  = ws + off; off += (size_t)N * 2;
    float* a1d  = ws + off; off += (size_t)N * 2;
    float* a2s  = ws + off; off += N;
    float* a2d  = ws + off; off += N;
    int* degA   = (int*)(ws + off); off += N;
    int* rowStart = (int*)(ws + off); off += N;
    int* cntg   = (int*)(ws + off); off += NB1 * NBUCK;
    int* offs   = (int*)(ws + off); off += NB1 * NBUCK;
    int* tot    = (int*)(ws + off); off += NBUCK;
    int* bucketBase = (int*)(ws + off); off += 257;
    unsigned* pairs = (unsigned*)(ws + off); off += Ep;
    int* srcS   = (int*)(ws + off); off += Ep;
    float* pool = ws + off; off += G * 64;
    float* cnt  = ws + off; off += G;
    float* out2 = (float*)h1h;   // alias: h1h (N*128 halves == N*64 floats) dead after fused_aggr1

    hipMemsetAsync(pool, 0, (size_t)(G * 64 + G) * sizeof(float), stream);

    // CSR build: deterministic two-level bucket sort (no global atomics)
    bucket_count<<<NB1, 256, 0, stream>>>(ei, cntg, E, Ep, chunk);
    bucket_scan_t<<<NBUCK, 256, 0, stream>>>(cntg, offs, tot);
    bucket_base<<<1, 256, 0, stream>>>(tot, bucketBase);
    bucket_place<<<NB1, 256, 0, stream>>>(ei, offs, bucketBase, pairs, E, Ep, chunk);
    bucket_build<<<NBUCK, 256, 0, stream>>>(pairs, bucketBase, rowStart, degA, srcS, N);

    dim3 g1((N + 63) / 64, 2);
    gemm1_kernel<<<g1, 256, 0, stream>>>(x, W1, a1sv, a1dv, h1h, a1s, a1d, N);
    fused_aggr1<<<(N + 3) / 4, 256, 0, stream>>>(rowStart, degA, srcS, a1s, a1d, h1h, out1, N);
    gemm2_kernel<<<(N + 63) / 64, 256, 0, stream>>>(out1, b1, W2, a2sv, a2dv, h2h, a2s, a2d, N);
    fused_aggr2<<<(N + 3) / 4, 256, 0, stream>>>(rowStart, degA, srcS, a2s, a2d, h2h, out2, N);
    pool_kernel<<<256, 256, 0, stream>>>(out2, b2, batch, pool, cnt, N);
    final_kernel<<<1, 64, 0, stream>>>(pool, cnt, Wlin, blin, (float*)d_out, G);
}

// Round 10
// 274.859 us; speedup vs baseline: 9.1835x; 1.1818x over previous
//
#include <hip/hip_runtime.h>
#include <hip/hip_fp16.h>

#define NEG_SLOPE 0.2f
#define BSH 9                    // bucket = dst >> 9  (512 nodes / bucket)
#define NBUCK 256                // covers dst < 131072
#define NB1 256                  // pass A/C blocks
#define DCAP 12288               // pass D LDS staging capacity (uints)

typedef _Float16 f16;
typedef __attribute__((ext_vector_type(8))) _Float16 half8;
typedef __attribute__((ext_vector_type(4))) _Float16 half4;
typedef __attribute__((ext_vector_type(4))) float f32x4;

// ============================ W transpose to fp16 [c][k] ============================
// W1 [128k][128c] -> W1t [128c][128k] fp16 ; W2 [128k][64c] -> W2t [64c][128k] fp16
__global__ __launch_bounds__(128) void prep_w(
    const float* __restrict__ W1, const float* __restrict__ W2,
    f16* __restrict__ W1t, f16* __restrict__ W2t)
{
    int b = blockIdx.x, k = threadIdx.x;
    if (b < 128) W1t[b * 128 + k] = (f16)W1[k * 128 + b];
    else { int c = b - 128; W2t[c * 128 + k] = (f16)W2[k * 64 + c]; }
}

// ============================ GEMM 1 (MFMA) ============================
// h1h = fp16(x @ W1), 64 rows x 128 cols per block, K=128.
// Wave w: rows w*16..w*16+15, all 128 cols (8 col-tiles).
// Fragment layouts (mfma_f32_16x16x32_f16): A lane=i+16*(k/8); B lane=j+16*(k/8);
// D col=lane&15, row=(lane>>4)*4+reg.
__global__ __launch_bounds__(256) void gemm1_kernel(
    const float* __restrict__ x, const f16* __restrict__ W1t,
    const float* __restrict__ a1s_vec, const float* __restrict__ a1d_vec,
    f16* __restrict__ h1h, float* __restrict__ a1s, float* __restrict__ a1d, int N)
{
    __shared__ f16 Ash[64 * 136];        // [r][k], pad 128->136
    __shared__ f16 Bsh[128 * 136];       // [c][k], pad
    int t = threadIdx.x;
    int row0 = blockIdx.x << 6;

    #pragma unroll
    for (int c = 0; c < 8; ++c) {        // A: x 64x128 fp32 -> fp16
        int l = c * 256 + t;
        int r = l >> 5, f = l & 31;
        int rr = row0 + r;
        float4 v = {0.f, 0.f, 0.f, 0.f};
        if (rr < N) v = *(const float4*)&x[(size_t)rr * 128 + f * 4];
        half4 hv = {(f16)v.x, (f16)v.y, (f16)v.z, (f16)v.w};
        *(half4*)&Ash[r * 136 + f * 4] = hv;
    }
    #pragma unroll
    for (int c = 0; c < 8; ++c) {        // B: W1t 128x128 f16 straight copy
        int l = c * 256 + t;
        int row = l >> 4, f = l & 15;
        *(half8*)&Bsh[row * 136 + f * 8] = *(const half8*)&W1t[row * 128 + f * 8];
    }
    __syncthreads();

    int lane = t & 63, w = t >> 6;
    int lr = lane & 15, kg = lane >> 4;
    f32x4 acc[8];
    #pragma unroll
    for (int ct = 0; ct < 8; ++ct) acc[ct] = (f32x4){0.f, 0.f, 0.f, 0.f};

    #pragma unroll
    for (int kt = 0; kt < 4; ++kt) {
        half8 af = *(const half8*)&Ash[(w * 16 + lr) * 136 + kt * 32 + kg * 8];
        #pragma unroll
        for (int ct = 0; ct < 8; ++ct) {
            half8 bf = *(const half8*)&Bsh[(ct * 16 + lr) * 136 + kt * 32 + kg * 8];
            acc[ct] = __builtin_amdgcn_mfma_f32_16x16x32_f16(af, bf, acc[ct], 0, 0, 0);
        }
    }

    // logits from accumulators: a1s/a1d per (row, head); reduce over 16 cols
    #pragma unroll
    for (int reg = 0; reg < 4; ++reg) {
        float ps0 = 0.f, pd0 = 0.f, ps1 = 0.f, pd1 = 0.f;
        #pragma unroll
        for (int ct = 0; ct < 4; ++ct) {
            float a = acc[ct][reg];
            ps0 += a * a1s_vec[ct * 16 + lr];
            pd0 += a * a1d_vec[ct * 16 + lr];
        }
        #pragma unroll
        for (int ct = 4; ct < 8; ++ct) {
            float a = acc[ct][reg];
            ps1 += a * a1s_vec[ct * 16 + lr];
            pd1 += a * a1d_vec[ct * 16 + lr];
        }
        #pragma unroll
        for (int o = 1; o <= 8; o <<= 1) {
            ps0 += __shfl_xor(ps0, o); pd0 += __shfl_xor(pd0, o);
            ps1 += __shfl_xor(ps1, o); pd1 += __shfl_xor(pd1, o);
        }
        if (lr == 0) {
            int rr = row0 + w * 16 + kg * 4 + reg;
            if (rr < N) {
                a1s[rr * 2] = ps0; a1d[rr * 2] = pd0;
                a1s[rr * 2 + 1] = ps1; a1d[rr * 2 + 1] = pd1;
            }
        }
    }

    // stage C through LDS (reuse Ash) for coalesced fp16 writes
    __syncthreads();
    #pragma unroll
    for (int ct = 0; ct < 8; ++ct)
        #pragma unroll
        for (int reg = 0; reg < 4; ++reg)
            Ash[(w * 16 + kg * 4 + reg) * 136 + ct * 16 + lr] = (f16)acc[ct][reg];
    __syncthreads();
    #pragma unroll
    for (int c = 0; c < 4; ++c) {
        int l = c * 256 + t;
        int r = l >> 4, f = l & 15;
        int rr = row0 + r;
        if (rr < N) *(half8*)&h1h[(size_t)rr * 128 + f * 8] = *(const half8*)&Ash[r * 136 + f * 8];
    }
}

// ============================ CSR build: two-level bucket sort ============================
__global__ __launch_bounds__(256) void bucket_count(
    const int* __restrict__ ei, int* __restrict__ cntg, int E, int Ep, int chunk)
{
    __shared__ int lc[NBUCK];
    int i = blockIdx.x, t = threadIdx.x;
    lc[t] = 0;
    __syncthreads();
    int e0 = i * chunk, e1 = min(e0 + chunk, Ep);
    for (int e = e0 + t; e < e1; e += 256) {
        int dst = (e < E) ? ei[E + e] : e - E;
        atomicAdd(&lc[dst >> BSH], 1);
    }
    __syncthreads();
    cntg[i * NBUCK + t] = lc[t];
}

__global__ __launch_bounds__(256) void bucket_scan_t(
    const int* __restrict__ cntg, int* __restrict__ offs, int* __restrict__ tot)
{
    __shared__ int sh[256];
    int b = blockIdx.x, i = threadIdx.x;
    int v = cntg[i * NBUCK + b];
    sh[i] = v;
    __syncthreads();
    for (int off = 1; off < 256; off <<= 1) {
        int u = (i >= off) ? sh[i - off] : 0;
        __syncthreads();
        sh[i] += u;
        __syncthreads();
    }
    offs[i * NBUCK + b] = sh[i] - v;
    if (i == 255) tot[b] = sh[255];
}

__global__ __launch_bounds__(256) void bucket_base(
    const int* __restrict__ tot, int* __restrict__ bucketBase)
{
    __shared__ int sh[256];
    int b = threadIdx.x;
    int v = tot[b];
    sh[b] = v;
    __syncthreads();
    for (int off = 1; off < 256; off <<= 1) {
        int u = (b >= off) ? sh[b - off] : 0;
        __syncthreads();
        sh[b] += u;
        __syncthreads();
    }
    bucketBase[b] = sh[b] - v;
    if (b == 255) bucketBase[256] = sh[255];
}

__global__ __launch_bounds__(256) void bucket_place(
    const int* __restrict__ ei, const int* __restrict__ offs, const int* __restrict__ bucketBase,
    unsigned* __restrict__ pairs, int E, int Ep, int chunk)
{
    __shared__ int cur[NBUCK];
    int i = blockIdx.x, t = threadIdx.x;
    cur[t] = offs[i * NBUCK + t] + bucketBase[t];
    __syncthreads();
    int e0 = i * chunk, e1 = min(e0 + chunk, Ep);
    for (int e = e0 + t; e < e1; e += 256) {
        int src, dst;
        if (e < E) { src = ei[e]; dst = ei[E + e]; } else { src = dst = e - E; }
        int pos = atomicAdd(&cur[dst >> BSH], 1);
        pairs[pos] = ((unsigned)(dst & 511) << 17) | (unsigned)src;
    }
}

__global__ __launch_bounds__(256) void bucket_build(
    const unsigned* __restrict__ pairs, const int* __restrict__ bucketBase,
    int* __restrict__ rowStart, int* __restrict__ deg, int* __restrict__ srcS, int N)
{
    __shared__ int ucnt[512], ustart[512], sh[256];
    __shared__ unsigned stage[DCAP];
    int b = blockIdx.x, t = threadIdx.x;
    int node0 = b << BSH;
    if (node0 >= N) return;
    int s0 = bucketBase[b], s1 = bucketBase[b + 1];
    int cnt = s1 - s0;
    ucnt[t] = 0; ucnt[t + 256] = 0;
    __syncthreads();
    bool fit = (cnt <= DCAP);
    for (int k = t; k < cnt; k += 256) {
        unsigned v = pairs[s0 + k];
        if (fit) stage[k] = v;
        atomicAdd(&ucnt[v >> 17], 1);
    }
    __syncthreads();
    int a0 = ucnt[2 * t], a1 = ucnt[2 * t + 1];
    int s2 = a0 + a1;
    sh[t] = s2;
    __syncthreads();
    for (int off = 1; off < 256; off <<= 1) {
        int u = (t >= off) ? sh[t - off] : 0;
        __syncthreads();
        sh[t] += u;
        __syncthreads();
    }
    int exc = sh[t] - s2;
    ustart[2 * t] = exc;
    ustart[2 * t + 1] = exc + a0;
    __syncthreads();
    for (int l = t; l < 512; l += 256) {
        int node = node0 + l;
        if (node < N) { rowStart[node] = s0 + ustart[l]; deg[node] = ucnt[l]; }
    }
    __syncthreads();
    for (int k = t; k < cnt; k += 256) {
        unsigned v = fit ? stage[k] : pairs[s0 + k];
        int pos = atomicAdd(&ustart[v >> 17], 1);
        srcS[s0 + pos] = (int)(v & 131071u);
    }
}

// ============================ Fused softmax+aggregate, layer 1 ============================
__global__ __launch_bounds__(256) void fused_aggr1(
    const int* __restrict__ rowStart, const int* __restrict__ deg, const int* __restrict__ srcS,
    const float* __restrict__ a1s, const float* __restrict__ a1d,
    const f16* __restrict__ h1h, float* __restrict__ out1, int N)
{
    int lane = threadIdx.x & 63;
    int dst = blockIdx.x * 4 + (threadIdx.x >> 6);
    if (dst >= N) return;
    int base = rowStart[dst];
    int d = deg[dst];
    float ad0 = a1d[2 * dst], ad1 = a1d[2 * dst + 1];
    int tx = lane & 15, j2 = lane >> 4;
    float acc[8] = {};
    float dpart0 = 0.f, dpart1 = 0.f;

    for (int c0 = 0; c0 < d; c0 += 64) {
        int cn = min(64, d - c0);
        int s = 0; float p0 = 0.f, p1 = 0.f;
        if (lane < cn) {
            s = srcS[base + c0 + lane];
            float2 av = *(const float2*)&a1s[2 * s];
            float e0 = av.x + ad0, e1 = av.y + ad1;
            e0 = e0 > 0.f ? e0 : NEG_SLOPE * e0;
            e1 = e1 > 0.f ? e1 : NEG_SLOPE * e1;
            p0 = __expf(e0); p1 = __expf(e1);
        }
        dpart0 += p0; dpart1 += p1;
        int niter = (cn + 3) >> 2;
        #pragma unroll 4
        for (int jj = 0; jj < niter; ++jj) {
            int esub = jj * 4 + j2;
            int   sj = __shfl(s, esub);
            float q0 = __shfl(p0, esub);
            float q1 = __shfl(p1, esub);
            float q  = (tx < 8) ? q0 : q1;
            half8 v = *(const half8*)&h1h[(size_t)sj * 128 + tx * 8];
            #pragma unroll
            for (int k = 0; k < 8; ++k) acc[k] += q * (float)v[k];
        }
    }
    #pragma unroll
    for (int k = 0; k < 8; ++k) acc[k] += __shfl_xor(acc[k], 16);
    #pragma unroll
    for (int k = 0; k < 8; ++k) acc[k] += __shfl_xor(acc[k], 32);
    #pragma unroll
    for (int o = 32; o; o >>= 1) { dpart0 += __shfl_xor(dpart0, o); dpart1 += __shfl_xor(dpart1, o); }
    if (j2 == 0) {
        float iv = (tx < 8) ? (1.f / dpart0) : (1.f / dpart1);
        float4 lo = {acc[0] * iv, acc[1] * iv, acc[2] * iv, acc[3] * iv};
        float4 hi = {acc[4] * iv, acc[5] * iv, acc[6] * iv, acc[7] * iv};
        *(float4*)&out1[(size_t)dst * 128 + tx * 8] = lo;
        *(float4*)&out1[(size_t)dst * 128 + tx * 8 + 4] = hi;
    }
}

// ============================ GEMM 2 (MFMA) ============================
// h2h = fp16(relu(out1 + b1) @ W2), 64 rows x 64 cols per block, K=128.
__global__ __launch_bounds__(256) void gemm2_kernel(
    const float* __restrict__ out1, const float* __restrict__ b1,
    const f16* __restrict__ W2t,
    const float* __restrict__ a2s_vec, const float* __restrict__ a2d_vec,
    f16* __restrict__ h2h, float* __restrict__ a2s, float* __restrict__ a2d, int N)
{
    __shared__ f16 Ash[64 * 136];        // [r][k]
    __shared__ f16 Bsh[64 * 136];        // [c][k]
    int t = threadIdx.x;
    int row0 = blockIdx.x << 6;

    #pragma unroll
    for (int c = 0; c < 8; ++c) {        // A: relu(out1 + b1) -> fp16
        int l = c * 256 + t;
        int r = l >> 5, f = l & 31;
        int rr = row0 + r;
        float4 v = {0.f, 0.f, 0.f, 0.f};
        if (rr < N) {
            v = *(const float4*)&out1[(size_t)rr * 128 + f * 4];
            float4 bv = *(const float4*)&b1[f * 4];
            v.x = fmaxf(v.x + bv.x, 0.f);
            v.y = fmaxf(v.y + bv.y, 0.f);
            v.z = fmaxf(v.z + bv.z, 0.f);
            v.w = fmaxf(v.w + bv.w, 0.f);
        }
        half4 hv = {(f16)v.x, (f16)v.y, (f16)v.z, (f16)v.w};
        *(half4*)&Ash[r * 136 + f * 4] = hv;
    }
    #pragma unroll
    for (int c = 0; c < 4; ++c) {        // B: W2t 64x128 f16 copy
        int l = c * 256 + t;
        int row = l >> 4, f = l & 15;
        *(half8*)&Bsh[row * 136 + f * 8] = *(const half8*)&W2t[row * 128 + f * 8];
    }
    __syncthreads();

    int lane = t & 63, w = t >> 6;
    int lr = lane & 15, kg = lane >> 4;
    f32x4 acc[4];
    #pragma unroll
    for (int ct = 0; ct < 4; ++ct) acc[ct] = (f32x4){0.f, 0.f, 0.f, 0.f};

    #pragma unroll
    for (int kt = 0; kt < 4; ++kt) {
        half8 af = *(const half8*)&Ash[(w * 16 + lr) * 136 + kt * 32 + kg * 8];
        #pragma unroll
        for (int ct = 0; ct < 4; ++ct) {
            half8 bf = *(const half8*)&Bsh[(ct * 16 + lr) * 136 + kt * 32 + kg * 8];
            acc[ct] = __builtin_amdgcn_mfma_f32_16x16x32_f16(af, bf, acc[ct], 0, 0, 0);
        }
    }

    #pragma unroll
    for (int reg = 0; reg < 4; ++reg) {
        float ps = 0.f, pd = 0.f;
        #pragma unroll
        for (int ct = 0; ct < 4; ++ct) {
            float a = acc[ct][reg];
            ps += a * a2s_vec[ct * 16 + lr];
            pd += a * a2d_vec[ct * 16 + lr];
        }
        #pragma unroll
        for (int o = 1; o <= 8; o <<= 1) { ps += __shfl_xor(ps, o); pd += __shfl_xor(pd, o); }
        if (lr == 0) {
            int rr = row0 + w * 16 + kg * 4 + reg;
            if (rr < N) { a2s[rr] = ps; a2d[rr] = pd; }
        }
    }

    __syncthreads();
    #pragma unroll
    for (int ct = 0; ct < 4; ++ct)
        #pragma unroll
        for (int reg = 0; reg < 4; ++reg)
            Ash[(w * 16 + kg * 4 + reg) * 136 + ct * 16 + lr] = (f16)acc[ct][reg];
    __syncthreads();
    #pragma unroll
    for (int c = 0; c < 2; ++c) {
        int l = c * 256 + t;
        int r = l >> 3, f = l & 7;
        int rr = row0 + r;
        if (rr < N) *(half8*)&h2h[(size_t)rr * 64 + f * 8] = *(const half8*)&Ash[r * 136 + f * 8];
    }
}

// ============================ Fused softmax+aggregate, layer 2 ============================
__global__ __launch_bounds__(256) void fused_aggr2(
    const int* __restrict__ rowStart, const int* __restrict__ deg, const int* __restrict__ srcS,
    const float* __restrict__ a2s, const float* __restrict__ a2d,
    const f16* __restrict__ h2h, float* __restrict__ out2, int N)
{
    int lane = threadIdx.x & 63;
    int dst = blockIdx.x * 4 + (threadIdx.x >> 6);
    if (dst >= N) return;
    int base = rowStart[dst];
    int d = deg[dst];
    float ad = a2d[dst];
    int tx = lane & 7, j3 = lane >> 3;
    float acc[8] = {};
    float dpart = 0.f;

    for (int c0 = 0; c0 < d; c0 += 64) {
        int cn = min(64, d - c0);
        int s = 0; float p = 0.f;
        if (lane < cn) {
            s = srcS[base + c0 + lane];
            float e = a2s[s] + ad;
            e = e > 0.f ? e : NEG_SLOPE * e;
            p = __expf(e);
        }
        dpart += p;
        int niter = (cn + 7) >> 3;
        #pragma unroll 4
        for (int jj = 0; jj < niter; ++jj) {
            int esub = jj * 8 + j3;
            int   sj = __shfl(s, esub);
            float q  = __shfl(p, esub);
            half8 v = *(const half8*)&h2h[(size_t)sj * 64 + tx * 8];
            #pragma unroll
            for (int k = 0; k < 8; ++k) acc[k] += q * (float)v[k];
        }
    }
    #pragma unroll
    for (int k = 0; k < 8; ++k) acc[k] += __shfl_xor(acc[k], 8);
    #pragma unroll
    for (int k = 0; k < 8; ++k) acc[k] += __shfl_xor(acc[k], 16);
    #pragma unroll
    for (int k = 0; k < 8; ++k) acc[k] += __shfl_xor(acc[k], 32);
    #pragma unroll
    for (int o = 32; o; o >>= 1) dpart += __shfl_xor(dpart, o);
    if (j3 == 0) {
        float iv = 1.f / dpart;
        float4 lo = {acc[0] * iv, acc[1] * iv, acc[2] * iv, acc[3] * iv};
        float4 hi = {acc[4] * iv, acc[5] * iv, acc[6] * iv, acc[7] * iv};
        *(float4*)&out2[(size_t)dst * 64 + tx * 8] = lo;
        *(float4*)&out2[(size_t)dst * 64 + tx * 8 + 4] = hi;
    }
}

// ============================ Pool ============================
__global__ __launch_bounds__(256) void pool_kernel(
    const float* __restrict__ out2, const float* __restrict__ b2,
    const int* __restrict__ batch, float* __restrict__ pool, float* __restrict__ cnt, int N)
{
    int lane = threadIdx.x & 63;
    int gwave = blockIdx.x * 4 + (threadIdx.x >> 6);
    int nwaves = gridDim.x * 4;
    int per = (N + nwaves - 1) / nwaves;
    int n0 = gwave * per;
    int n1 = min(n0 + per, N);
    if (n0 >= n1) return;
    float bb = b2[lane];
    float acc = 0.f;
    int count = 0;
    int gcur = batch[n0];
    for (int n = n0; n < n1; ++n) {
        int g = batch[n];
        if (g != gcur) {
            atomicAdd(&pool[gcur * 64 + lane], acc);
            if (lane == 0) atomicAdd(&cnt[gcur], (float)count);
            acc = 0.f; count = 0; gcur = g;
        }
        float v = out2[(size_t)n * 64 + lane] + bb;
        acc += v > 0.f ? v : 0.f;
        ++count;
    }
    atomicAdd(&pool[gcur * 64 + lane], acc);
    if (lane == 0) atomicAdd(&cnt[gcur], (float)count);
}

// ============================ Final linear ============================
__global__ void final_kernel(
    const float* __restrict__ pool, const float* __restrict__ cnt,
    const float* __restrict__ Wlin, const float* __restrict__ blin,
    float* __restrict__ out, int G)
{
    int g = threadIdx.x;
    if (g >= G) return;
    float s = 0.f;
    #pragma unroll 8
    for (int c = 0; c < 64; ++c) s += pool[g * 64 + c] * Wlin[c];
    float cn = cnt[g]; cn = cn > 1.f ? cn : 1.f;
    out[g] = s / cn + blin[0];
}

extern "C" void kernel_launch(void* const* d_in, const int* in_sizes, int n_in,
                              void* d_out, int out_size, void* d_ws, size_t ws_size,
                              hipStream_t stream) {
    const float* x     = (const float*)d_in[0];
    const int*   ei    = (const int*)d_in[1];
    const int*   batch = (const int*)d_in[2];
    const float* W1    = (const float*)d_in[3];
    const float* a1sv  = (const float*)d_in[4];
    const float* a1dv  = (const float*)d_in[5];
    const float* b1    = (const float*)d_in[6];
    const float* W2    = (const float*)d_in[7];
    const float* a2sv  = (const float*)d_in[8];
    const float* a2dv  = (const float*)d_in[9];
    const float* b2    = (const float*)d_in[10];
    const float* Wlin  = (const float*)d_in[11];
    const float* blin  = (const float*)d_in[12];

    int N  = in_sizes[2];
    int E  = in_sizes[1] / 2;
    int Ep = E + N;
    const int G = 64;
    int chunk = (Ep + NB1 - 1) / NB1;

    float* ws = (float*)d_ws;
    size_t off = 0;
    float* out1 = ws + off; off += (size_t)N * 128;
    f16*  h1h   = (f16*)(ws + off); off += (size_t)N * 64;   // N*128 halves
    f16*  h2h   = (f16*)(ws + off); off += (size_t)N * 32;   // N*64 halves
    float* a1s  = ws + off; off += (size_t)N * 2;
    float* a1d  = ws + off; off += (size_t)N * 2;
    float* a2s  = ws + off; off += N;
    float* a2d  = ws + off; off += N;
    int* degA   = (int*)(ws + off); off += N;
    int* rowStart = (int*)(ws + off); off += N;
    int* cntg   = (int*)(ws + off); off += NB1 * NBUCK;
    int* offs   = (int*)(ws + off); off += NB1 * NBUCK;
    int* tot    = (int*)(ws + off); off += NBUCK;
    int* bucketBase = (int*)(ws + off); off += 257;
    unsigned* pairs = (unsigned*)(ws + off); off += Ep;
    int* srcS   = (int*)(ws + off); off += Ep;
    float* pool = ws + off; off += G * 64;
    float* cnt  = ws + off; off += G;
    f16* W1t    = (f16*)(ws + off); off += 128 * 64;         // 128*128 halves
    f16* W2t    = (f16*)(ws + off); off += 64 * 64;          // 64*128 halves
    float* out2 = (float*)h1h;   // alias: h1h dead after fused_aggr1

    hipMemsetAsync(pool, 0, (size_t)(G * 64 + G) * sizeof(float), stream);

    prep_w<<<192, 128, 0, stream>>>(W1, W2, W1t, W2t);

    // CSR build: deterministic two-level bucket sort (no global atomics)
    bucket_count<<<NB1, 256, 0, stream>>>(ei, cntg, E, Ep, chunk);
    bucket_scan_t<<<NBUCK, 256, 0, stream>>>(cntg, offs, tot);
    bucket_base<<<1, 256, 0, stream>>>(tot, bucketBase);
    bucket_place<<<NB1, 256, 0, stream>>>(ei, offs, bucketBase, pairs, E, Ep, chunk);
    bucket_build<<<NBUCK, 256, 0, stream>>>(pairs, bucketBase, rowStart, degA, srcS, N);

    gemm1_kernel<<<(N + 63) / 64, 256, 0, stream>>>(x, W1t, a1sv, a1dv, h1h, a1s, a1d, N);
    fused_aggr1<<<(N + 3) / 4, 256, 0, stream>>>(rowStart, degA, srcS, a1s, a1d, h1h, out1, N);
    gemm2_kernel<<<(N + 63) / 64, 256, 0, stream>>>(out1, b1, W2t, a2sv, a2dv, h2h, a2s, a2d, N);
    fused_aggr2<<<(N + 3) / 4, 256, 0, stream>>>(rowStart, degA, srcS, a2s, a2d, h2h, out2, N);
    pool_kernel<<<256, 256, 0, stream>>>(out2, b2, batch, pool, cnt, N);
    final_kernel<<<1, 64, 0, stream>>>(pool, cnt, Wlin, blin, (float*)d_out, G);
}

// Round 11
// 264.591 us; speedup vs baseline: 9.5399x; 1.0388x over previous
//
#include <hip/hip_runtime.h>
#include <hip/hip_fp16.h>

#define NEG_SLOPE 0.2f
#define BSH 9                    // bucket = dst >> 9  (512 nodes / bucket)
#define NBUCK 256                // covers dst < 131072
#define NB1 256                  // pass A/C blocks
#define DCAP 12288               // pass D LDS staging capacity (uints)

typedef _Float16 f16;
typedef __attribute__((ext_vector_type(8))) _Float16 half8;
typedef __attribute__((ext_vector_type(4))) _Float16 half4;
typedef __attribute__((ext_vector_type(4))) float f32x4;

// ============================ W transpose to fp16 [c][k] ============================
__global__ __launch_bounds__(128) void prep_w(
    const float* __restrict__ W1, const float* __restrict__ W2,
    f16* __restrict__ W1t, f16* __restrict__ W2t)
{
    int b = blockIdx.x, k = threadIdx.x;
    if (b < 128) W1t[b * 128 + k] = (f16)W1[k * 128 + b];
    else { int c = b - 128; W2t[c * 128 + k] = (f16)W2[k * 64 + c]; }
}

// ============================ GEMM 1 (MFMA) ============================
// h1h = fp16(x @ W1), 64 rows x 128 cols per block, K=128.
__global__ __launch_bounds__(256) void gemm1_kernel(
    const float* __restrict__ x, const f16* __restrict__ W1t,
    const float* __restrict__ a1s_vec, const float* __restrict__ a1d_vec,
    f16* __restrict__ h1h, float* __restrict__ a1s, float* __restrict__ a1d, int N)
{
    __shared__ f16 Ash[64 * 136];        // [r][k], pad 128->136
    __shared__ f16 Bsh[128 * 136];       // [c][k], pad
    int t = threadIdx.x;
    int row0 = blockIdx.x << 6;

    #pragma unroll
    for (int c = 0; c < 8; ++c) {        // A: x 64x128 fp32 -> fp16
        int l = c * 256 + t;
        int r = l >> 5, f = l & 31;
        int rr = row0 + r;
        float4 v = {0.f, 0.f, 0.f, 0.f};
        if (rr < N) v = *(const float4*)&x[(size_t)rr * 128 + f * 4];
        half4 hv = {(f16)v.x, (f16)v.y, (f16)v.z, (f16)v.w};
        *(half4*)&Ash[r * 136 + f * 4] = hv;
    }
    #pragma unroll
    for (int c = 0; c < 8; ++c) {        // B: W1t 128x128 f16 straight copy
        int l = c * 256 + t;
        int row = l >> 4, f = l & 15;
        *(half8*)&Bsh[row * 136 + f * 8] = *(const half8*)&W1t[row * 128 + f * 8];
    }
    __syncthreads();

    int lane = t & 63, w = t >> 6;
    int lr = lane & 15, kg = lane >> 4;
    f32x4 acc[8];
    #pragma unroll
    for (int ct = 0; ct < 8; ++ct) acc[ct] = (f32x4){0.f, 0.f, 0.f, 0.f};

    #pragma unroll
    for (int kt = 0; kt < 4; ++kt) {
        half8 af = *(const half8*)&Ash[(w * 16 + lr) * 136 + kt * 32 + kg * 8];
        #pragma unroll
        for (int ct = 0; ct < 8; ++ct) {
            half8 bf = *(const half8*)&Bsh[(ct * 16 + lr) * 136 + kt * 32 + kg * 8];
            acc[ct] = __builtin_amdgcn_mfma_f32_16x16x32_f16(af, bf, acc[ct], 0, 0, 0);
        }
    }

    #pragma unroll
    for (int reg = 0; reg < 4; ++reg) {
        float ps0 = 0.f, pd0 = 0.f, ps1 = 0.f, pd1 = 0.f;
        #pragma unroll
        for (int ct = 0; ct < 4; ++ct) {
            float a = acc[ct][reg];
            ps0 += a * a1s_vec[ct * 16 + lr];
            pd0 += a * a1d_vec[ct * 16 + lr];
        }
        #pragma unroll
        for (int ct = 4; ct < 8; ++ct) {
            float a = acc[ct][reg];
            ps1 += a * a1s_vec[ct * 16 + lr];
            pd1 += a * a1d_vec[ct * 16 + lr];
        }
        #pragma unroll
        for (int o = 1; o <= 8; o <<= 1) {
            ps0 += __shfl_xor(ps0, o); pd0 += __shfl_xor(pd0, o);
            ps1 += __shfl_xor(ps1, o); pd1 += __shfl_xor(pd1, o);
        }
        if (lr == 0) {
            int rr = row0 + w * 16 + kg * 4 + reg;
            if (rr < N) {
                a1s[rr * 2] = ps0; a1d[rr * 2] = pd0;
                a1s[rr * 2 + 1] = ps1; a1d[rr * 2 + 1] = pd1;
            }
        }
    }

    __syncthreads();
    #pragma unroll
    for (int ct = 0; ct < 8; ++ct)
        #pragma unroll
        for (int reg = 0; reg < 4; ++reg)
            Ash[(w * 16 + kg * 4 + reg) * 136 + ct * 16 + lr] = (f16)acc[ct][reg];
    __syncthreads();
    #pragma unroll
    for (int c = 0; c < 4; ++c) {
        int l = c * 256 + t;
        int r = l >> 4, f = l & 15;
        int rr = row0 + r;
        if (rr < N) *(half8*)&h1h[(size_t)rr * 128 + f * 8] = *(const half8*)&Ash[r * 136 + f * 8];
    }
}

// ============================ CSR build: two-level bucket sort ============================
// Pass A: per-block LDS histogram; block 0 also zeroes pool/cnt accumulators.
__global__ __launch_bounds__(256) void bucket_count(
    const int* __restrict__ ei, int* __restrict__ cntg,
    float* __restrict__ poolz, int nz, int E, int Ep, int chunk)
{
    __shared__ int lc[NBUCK];
    int i = blockIdx.x, t = threadIdx.x;
    if (i == 0) for (int z = t; z < nz; z += 256) poolz[z] = 0.f;
    lc[t] = 0;
    __syncthreads();
    int e0 = i * chunk, e1 = min(e0 + chunk, Ep);
    for (int e = e0 + t; e < e1; e += 256) {
        int dst = (e < E) ? ei[E + e] : e - E;
        atomicAdd(&lc[dst >> BSH], 1);
    }
    __syncthreads();
    cntg[i * NBUCK + t] = lc[t];
}

__global__ __launch_bounds__(256) void bucket_scan_t(
    const int* __restrict__ cntg, int* __restrict__ offs, int* __restrict__ tot)
{
    __shared__ int sh[256];
    int b = blockIdx.x, i = threadIdx.x;
    int v = cntg[i * NBUCK + b];
    sh[i] = v;
    __syncthreads();
    for (int off = 1; off < 256; off <<= 1) {
        int u = (i >= off) ? sh[i - off] : 0;
        __syncthreads();
        sh[i] += u;
        __syncthreads();
    }
    offs[i * NBUCK + b] = sh[i] - v;
    if (i == 255) tot[b] = sh[255];
}

// Pass C: each block re-derives bucketBase from tot via LDS scan, then places
// packed (dstLocal<<17 | src) through LDS cursors.
__global__ __launch_bounds__(256) void bucket_place(
    const int* __restrict__ ei, const int* __restrict__ offs, const int* __restrict__ tot,
    unsigned* __restrict__ pairs, int E, int Ep, int chunk)
{
    __shared__ int cur[NBUCK];
    __shared__ int sh[256];
    int i = blockIdx.x, t = threadIdx.x;
    int v = tot[t];
    sh[t] = v;
    __syncthreads();
    for (int off = 1; off < 256; off <<= 1) {
        int u = (t >= off) ? sh[t - off] : 0;
        __syncthreads();
        sh[t] += u;
        __syncthreads();
    }
    cur[t] = offs[i * NBUCK + t] + sh[t] - v;   // + exclusive bucket base
    __syncthreads();
    int e0 = i * chunk, e1 = min(e0 + chunk, Ep);
    for (int e = e0 + t; e < e1; e += 256) {
        int src, dst;
        if (e < E) { src = ei[e]; dst = ei[E + e]; } else { src = dst = e - E; }
        int pos = atomicAdd(&cur[dst >> BSH], 1);
        pairs[pos] = ((unsigned)(dst & 511) << 17) | (unsigned)src;
    }
}

// Pass D: re-derives its bucket range from tot scan; degree count, LDS scan,
// rowStart/deg write, LDS-cursor scatter into contiguous srcS region.
__global__ __launch_bounds__(256) void bucket_build(
    const unsigned* __restrict__ pairs, const int* __restrict__ tot,
    int* __restrict__ rowStart, int* __restrict__ deg, int* __restrict__ srcS, int N)
{
    __shared__ int ucnt[512], ustart[512], sh[256];
    __shared__ unsigned stage[DCAP];
    int b = blockIdx.x, t = threadIdx.x;
    int node0 = b << BSH;
    if (node0 >= N) return;
    ucnt[t] = 0; ucnt[t + 256] = 0;
    int v = tot[t];
    sh[t] = v;
    __syncthreads();
    for (int off = 1; off < 256; off <<= 1) {
        int u = (t >= off) ? sh[t - off] : 0;
        __syncthreads();
        sh[t] += u;
        __syncthreads();
    }
    int s0 = (b == 0) ? 0 : sh[b - 1];
    int s1 = sh[b];
    int cnt = s1 - s0;
    __syncthreads();
    bool fit = (cnt <= DCAP);
    for (int k = t; k < cnt; k += 256) {
        unsigned pv = pairs[s0 + k];
        if (fit) stage[k] = pv;
        atomicAdd(&ucnt[pv >> 17], 1);
    }
    __syncthreads();
    int a0 = ucnt[2 * t], a1 = ucnt[2 * t + 1];
    int s2 = a0 + a1;
    sh[t] = s2;
    __syncthreads();
    for (int off = 1; off < 256; off <<= 1) {
        int u = (t >= off) ? sh[t - off] : 0;
        __syncthreads();
        sh[t] += u;
        __syncthreads();
    }
    int exc = sh[t] - s2;
    ustart[2 * t] = exc;
    ustart[2 * t + 1] = exc + a0;
    __syncthreads();
    for (int l = t; l < 512; l += 256) {
        int node = node0 + l;
        if (node < N) { rowStart[node] = s0 + ustart[l]; deg[node] = ucnt[l]; }
    }
    __syncthreads();
    for (int k = t; k < cnt; k += 256) {
        unsigned pv = fit ? stage[k] : pairs[s0 + k];
        int pos = atomicAdd(&ustart[pv >> 17], 1);
        srcS[s0 + pos] = (int)(pv & 131071u);
    }
}

// ============================ Fused softmax+aggregate, layer 1 ============================
// Epilogue applies bias+relu and stores fp16 (out1h) -- identical arithmetic to
// the old gemm2 A-staging, one pass earlier.
__global__ __launch_bounds__(256) void fused_aggr1(
    const int* __restrict__ rowStart, const int* __restrict__ deg, const int* __restrict__ srcS,
    const float* __restrict__ a1s, const float* __restrict__ a1d, const float* __restrict__ b1,
    const f16* __restrict__ h1h, f16* __restrict__ out1h, int N)
{
    int lane = threadIdx.x & 63;
    int dst = blockIdx.x * 4 + (threadIdx.x >> 6);
    if (dst >= N) return;
    int base = rowStart[dst];
    int d = deg[dst];
    float ad0 = a1d[2 * dst], ad1 = a1d[2 * dst + 1];
    int tx = lane & 15, j2 = lane >> 4;
    float acc[8] = {};
    float dpart0 = 0.f, dpart1 = 0.f;

    for (int c0 = 0; c0 < d; c0 += 64) {
        int cn = min(64, d - c0);
        int s = 0; float p0 = 0.f, p1 = 0.f;
        if (lane < cn) {
            s = srcS[base + c0 + lane];
            float2 av = *(const float2*)&a1s[2 * s];
            float e0 = av.x + ad0, e1 = av.y + ad1;
            e0 = e0 > 0.f ? e0 : NEG_SLOPE * e0;
            e1 = e1 > 0.f ? e1 : NEG_SLOPE * e1;
            p0 = __expf(e0); p1 = __expf(e1);
        }
        dpart0 += p0; dpart1 += p1;
        int niter = (cn + 3) >> 2;
        #pragma unroll 4
        for (int jj = 0; jj < niter; ++jj) {
            int esub = jj * 4 + j2;
            int   sj = __shfl(s, esub);
            float q0 = __shfl(p0, esub);
            float q1 = __shfl(p1, esub);
            float q  = (tx < 8) ? q0 : q1;
            half8 v = *(const half8*)&h1h[(size_t)sj * 128 + tx * 8];
            #pragma unroll
            for (int k = 0; k < 8; ++k) acc[k] += q * (float)v[k];
        }
    }
    #pragma unroll
    for (int k = 0; k < 8; ++k) acc[k] += __shfl_xor(acc[k], 16);
    #pragma unroll
    for (int k = 0; k < 8; ++k) acc[k] += __shfl_xor(acc[k], 32);
    #pragma unroll
    for (int o = 32; o; o >>= 1) { dpart0 += __shfl_xor(dpart0, o); dpart1 += __shfl_xor(dpart1, o); }
    if (j2 == 0) {
        float iv = (tx < 8) ? (1.f / dpart0) : (1.f / dpart1);
        float4 blo = *(const float4*)&b1[tx * 8];
        float4 bhi = *(const float4*)&b1[tx * 8 + 4];
        float o0 = fmaxf(acc[0] * iv + blo.x, 0.f);
        float o1 = fmaxf(acc[1] * iv + blo.y, 0.f);
        float o2 = fmaxf(acc[2] * iv + blo.z, 0.f);
        float o3 = fmaxf(acc[3] * iv + blo.w, 0.f);
        float o4 = fmaxf(acc[4] * iv + bhi.x, 0.f);
        float o5 = fmaxf(acc[5] * iv + bhi.y, 0.f);
        float o6 = fmaxf(acc[6] * iv + bhi.z, 0.f);
        float o7 = fmaxf(acc[7] * iv + bhi.w, 0.f);
        half8 hv = {(f16)o0, (f16)o1, (f16)o2, (f16)o3, (f16)o4, (f16)o5, (f16)o6, (f16)o7};
        *(half8*)&out1h[(size_t)dst * 128 + tx * 8] = hv;
    }
}

// ============================ GEMM 2 (MFMA) ============================
// h2h = fp16(out1h @ W2): A is pre-activated fp16, straight copy to LDS.
__global__ __launch_bounds__(256) void gemm2_kernel(
    const f16* __restrict__ out1h, const f16* __restrict__ W2t,
    const float* __restrict__ a2s_vec, const float* __restrict__ a2d_vec,
    f16* __restrict__ h2h, float* __restrict__ a2s, float* __restrict__ a2d, int N)
{
    __shared__ f16 Ash[64 * 136];        // [r][k]
    __shared__ f16 Bsh[64 * 136];        // [c][k]
    int t = threadIdx.x;
    int row0 = blockIdx.x << 6;

    #pragma unroll
    for (int c = 0; c < 4; ++c) {        // A: out1h 64x128 f16 copy
        int l = c * 256 + t;
        int r = l >> 4, f = l & 15;
        int rr = row0 + r;
        half8 hv = {0, 0, 0, 0, 0, 0, 0, 0};
        if (rr < N) hv = *(const half8*)&out1h[(size_t)rr * 128 + f * 8];
        *(half8*)&Ash[r * 136 + f * 8] = hv;
    }
    #pragma unroll
    for (int c = 0; c < 4; ++c) {        // B: W2t 64x128 f16 copy
        int l = c * 256 + t;
        int row = l >> 4, f = l & 15;
        *(half8*)&Bsh[row * 136 + f * 8] = *(const half8*)&W2t[row * 128 + f * 8];
    }
    __syncthreads();

    int lane = t & 63, w = t >> 6;
    int lr = lane & 15, kg = lane >> 4;
    f32x4 acc[4];
    #pragma unroll
    for (int ct = 0; ct < 4; ++ct) acc[ct] = (f32x4){0.f, 0.f, 0.f, 0.f};

    #pragma unroll
    for (int kt = 0; kt < 4; ++kt) {
        half8 af = *(const half8*)&Ash[(w * 16 + lr) * 136 + kt * 32 + kg * 8];
        #pragma unroll
        for (int ct = 0; ct < 4; ++ct) {
            half8 bf = *(const half8*)&Bsh[(ct * 16 + lr) * 136 + kt * 32 + kg * 8];
            acc[ct] = __builtin_amdgcn_mfma_f32_16x16x32_f16(af, bf, acc[ct], 0, 0, 0);
        }
    }

    #pragma unroll
    for (int reg = 0; reg < 4; ++reg) {
        float ps = 0.f, pd = 0.f;
        #pragma unroll
        for (int ct = 0; ct < 4; ++ct) {
            float a = acc[ct][reg];
            ps += a * a2s_vec[ct * 16 + lr];
            pd += a * a2d_vec[ct * 16 + lr];
        }
        #pragma unroll
        for (int o = 1; o <= 8; o <<= 1) { ps += __shfl_xor(ps, o); pd += __shfl_xor(pd, o); }
        if (lr == 0) {
            int rr = row0 + w * 16 + kg * 4 + reg;
            if (rr < N) { a2s[rr] = ps; a2d[rr] = pd; }
        }
    }

    __syncthreads();
    #pragma unroll
    for (int ct = 0; ct < 4; ++ct)
        #pragma unroll
        for (int reg = 0; reg < 4; ++reg)
            Ash[(w * 16 + kg * 4 + reg) * 136 + ct * 16 + lr] = (f16)acc[ct][reg];
    __syncthreads();
    #pragma unroll
    for (int c = 0; c < 2; ++c) {
        int l = c * 256 + t;
        int r = l >> 3, f = l & 7;
        int rr = row0 + r;
        if (rr < N) *(half8*)&h2h[(size_t)rr * 64 + f * 8] = *(const half8*)&Ash[r * 136 + f * 8];
    }
}

// ============================ Fused softmax+aggregate, layer 2 ============================
// Epilogue applies b2+relu, stores fp16 (out2h) -- pool becomes a pure sum.
__global__ __launch_bounds__(256) void fused_aggr2(
    const int* __restrict__ rowStart, const int* __restrict__ deg, const int* __restrict__ srcS,
    const float* __restrict__ a2s, const float* __restrict__ a2d, const float* __restrict__ b2,
    const f16* __restrict__ h2h, f16* __restrict__ out2h, int N)
{
    int lane = threadIdx.x & 63;
    int dst = blockIdx.x * 4 + (threadIdx.x >> 6);
    if (dst >= N) return;
    int base = rowStart[dst];
    int d = deg[dst];
    float ad = a2d[dst];
    int tx = lane & 7, j3 = lane >> 3;
    float acc[8] = {};
    float dpart = 0.f;

    for (int c0 = 0; c0 < d; c0 += 64) {
        int cn = min(64, d - c0);
        int s = 0; float p = 0.f;
        if (lane < cn) {
            s = srcS[base + c0 + lane];
            float e = a2s[s] + ad;
            e = e > 0.f ? e : NEG_SLOPE * e;
            p = __expf(e);
        }
        dpart += p;
        int niter = (cn + 7) >> 3;
        #pragma unroll 4
        for (int jj = 0; jj < niter; ++jj) {
            int esub = jj * 8 + j3;
            int   sj = __shfl(s, esub);
            float q  = __shfl(p, esub);
            half8 v = *(const half8*)&h2h[(size_t)sj * 64 + tx * 8];
            #pragma unroll
            for (int k = 0; k < 8; ++k) acc[k] += q * (float)v[k];
        }
    }
    #pragma unroll
    for (int k = 0; k < 8; ++k) acc[k] += __shfl_xor(acc[k], 8);
    #pragma unroll
    for (int k = 0; k < 8; ++k) acc[k] += __shfl_xor(acc[k], 16);
    #pragma unroll
    for (int k = 0; k < 8; ++k) acc[k] += __shfl_xor(acc[k], 32);
    #pragma unroll
    for (int o = 32; o; o >>= 1) dpart += __shfl_xor(dpart, o);
    if (j3 == 0) {
        float iv = 1.f / dpart;
        float4 blo = *(const float4*)&b2[tx * 8];
        float4 bhi = *(const float4*)&b2[tx * 8 + 4];
        float o0 = fmaxf(acc[0] * iv + blo.x, 0.f);
        float o1 = fmaxf(acc[1] * iv + blo.y, 0.f);
        float o2 = fmaxf(acc[2] * iv + blo.z, 0.f);
        float o3 = fmaxf(acc[3] * iv + blo.w, 0.f);
        float o4 = fmaxf(acc[4] * iv + bhi.x, 0.f);
        float o5 = fmaxf(acc[5] * iv + bhi.y, 0.f);
        float o6 = fmaxf(acc[6] * iv + bhi.z, 0.f);
        float o7 = fmaxf(acc[7] * iv + bhi.w, 0.f);
        half8 hv = {(f16)o0, (f16)o1, (f16)o2, (f16)o3, (f16)o4, (f16)o5, (f16)o6, (f16)o7};
        *(half8*)&out2h[(size_t)dst * 64 + tx * 8] = hv;
    }
}

// ============================ Pool ============================
// out2h already holds relu(out2 + b2); pure sum per graph.
__global__ __launch_bounds__(256) void pool_kernel(
    const f16* __restrict__ out2h, const int* __restrict__ batch,
    float* __restrict__ pool, float* __restrict__ cnt, int N)
{
    int lane = threadIdx.x & 63;
    int gwave = blockIdx.x * 4 + (threadIdx.x >> 6);
    int nwaves = gridDim.x * 4;
    int per = (N + nwaves - 1) / nwaves;
    int n0 = gwave * per;
    int n1 = min(n0 + per, N);
    if (n0 >= n1) return;
    float acc = 0.f;
    int count = 0;
    int gcur = batch[n0];
    for (int n = n0; n < n1; ++n) {
        int g = batch[n];
        if (g != gcur) {
            atomicAdd(&pool[gcur * 64 + lane], acc);
            if (lane == 0) atomicAdd(&cnt[gcur], (float)count);
            acc = 0.f; count = 0; gcur = g;
        }
        acc += (float)out2h[(size_t)n * 64 + lane];
        ++count;
    }
    atomicAdd(&pool[gcur * 64 + lane], acc);
    if (lane == 0) atomicAdd(&cnt[gcur], (float)count);
}

// ============================ Final linear ============================
__global__ void final_kernel(
    const float* __restrict__ pool, const float* __restrict__ cnt,
    const float* __restrict__ Wlin, const float* __restrict__ blin,
    float* __restrict__ out, int G)
{
    int g = threadIdx.x;
    if (g >= G) return;
    float s = 0.f;
    #pragma unroll 8
    for (int c = 0; c < 64; ++c) s += pool[g * 64 + c] * Wlin[c];
    float cn = cnt[g]; cn = cn > 1.f ? cn : 1.f;
    out[g] = s / cn + blin[0];
}

extern "C" void kernel_launch(void* const* d_in, const int* in_sizes, int n_in,
                              void* d_out, int out_size, void* d_ws, size_t ws_size,
                              hipStream_t stream) {
    const float* x     = (const float*)d_in[0];
    const int*   ei    = (const int*)d_in[1];
    const int*   batch = (const int*)d_in[2];
    const float* W1    = (const float*)d_in[3];
    const float* a1sv  = (const float*)d_in[4];
    const float* a1dv  = (const float*)d_in[5];
    const float* b1    = (const float*)d_in[6];
    const float* W2    = (const float*)d_in[7];
    const float* a2sv  = (const float*)d_in[8];
    const float* a2dv  = (const float*)d_in[9];
    const float* b2    = (const float*)d_in[10];
    const float* Wlin  = (const float*)d_in[11];
    const float* blin  = (const float*)d_in[12];

    int N  = in_sizes[2];
    int E  = in_sizes[1] / 2;
    int Ep = E + N;
    const int G = 64;
    int chunk = (Ep + NB1 - 1) / NB1;

    float* ws = (float*)d_ws;
    size_t off = 0;
    f16*  out1h = (f16*)(ws + off); off += (size_t)N * 64;   // N*128 halves
    f16*  h1h   = (f16*)(ws + off); off += (size_t)N * 64;   // N*128 halves
    f16*  h2h   = (f16*)(ws + off); off += (size_t)N * 32;   // N*64 halves
    float* a1s  = ws + off; off += (size_t)N * 2;
    float* a1d  = ws + off; off += (size_t)N * 2;
    float* a2s  = ws + off; off += N;
    float* a2d  = ws + off; off += N;
    int* degA   = (int*)(ws + off); off += N;
    int* rowStart = (int*)(ws + off); off += N;
    int* cntg   = (int*)(ws + off); off += NB1 * NBUCK;
    int* offs   = (int*)(ws + off); off += NB1 * NBUCK;
    int* tot    = (int*)(ws + off); off += NBUCK;
    unsigned* pairs = (unsigned*)(ws + off); off += Ep;
    int* srcS   = (int*)(ws + off); off += Ep;
    float* pool = ws + off; off += G * 64;
    float* cnt  = ws + off; off += G;
    f16* W1t    = (f16*)(ws + off); off += 128 * 64;         // 128*128 halves
    f16* W2t    = (f16*)(ws + off); off += 64 * 64;          // 64*128 halves
    f16* out2h  = h1h;   // alias: h1h dead after fused_aggr1

    prep_w<<<192, 128, 0, stream>>>(W1, W2, W1t, W2t);

    // CSR build: deterministic two-level bucket sort (no global atomics)
    bucket_count<<<NB1, 256, 0, stream>>>(ei, cntg, pool, G * 64 + G, E, Ep, chunk);
    bucket_scan_t<<<NBUCK, 256, 0, stream>>>(cntg, offs, tot);
    bucket_place<<<NB1, 256, 0, stream>>>(ei, offs, tot, pairs, E, Ep, chunk);
    bucket_build<<<NBUCK, 256, 0, stream>>>(pairs, tot, rowStart, degA, srcS, N);

    gemm1_kernel<<<(N + 63) / 64, 256, 0, stream>>>(x, W1t, a1sv, a1dv, h1h, a1s, a1d, N);
    fused_aggr1<<<(N + 3) / 4, 256, 0, stream>>>(rowStart, degA, srcS, a1s, a1d, b1, h1h, out1h, N);
    gemm2_kernel<<<(N + 63) / 64, 256, 0, stream>>>(out1h, W2t, a2sv, a2dv, h2h, a2s, a2d, N);
    fused_aggr2<<<(N + 3) / 4, 256, 0, stream>>>(rowStart, degA, srcS, a2s, a2d, b2, h2h, out2h, N);
    pool_kernel<<<256, 256, 0, stream>>>(out2h, batch, pool, cnt, N);
    final_kernel<<<1, 64, 0, stream>>>(pool, cnt, Wlin, blin, (float*)d_out, G);
}